// Round 1
// baseline (4819.387 us; speedup 1.0000x reference)
//
#include <hip/hip_runtime.h>
#include <hip/hip_bf16.h>

// ---------------------------------------------------------------------------
// MolecularGNN: atom proj -> 6x (GATConv + BN + ReLU) -> mean pool -> MLP
// Round 1: correctness-first fp32 implementation.
// ---------------------------------------------------------------------------

#define N_NODES 50000
#define N_EDGES 150000
#define N_GRAPHS 2000
#define ATOM_DIM 100
#define HID 512
#define HEADS 8
#define HEAD_DIM 64
#define LAYERS 6
#define TARGETS 13

__device__ __forceinline__ float lrelu(float v) { return v > 0.f ? v : 0.2f * v; }

// ---------------- GEMM: C[N,M] = A[N,K] @ B[K,M] (+bias) -------------------
// 64x64 tile, BK=16, 256 threads, 4x4 micro-tile per thread.
template <int VEC>
__launch_bounds__(256)
__global__ void gemm_kernel(const float* __restrict__ A, const float* __restrict__ B,
                            const float* __restrict__ bias, float* __restrict__ C,
                            int N, int K, int M) {
    __shared__ __align__(16) float As[16][68];
    __shared__ __align__(16) float Bs[16][64];
    const int tid = threadIdx.x;
    const int row0 = blockIdx.x * 64;
    const int col0 = blockIdx.y * 64;
    const int tx = tid & 15, ty = tid >> 4;
    float acc[4][4] = {};

    for (int k0 = 0; k0 < K; k0 += 16) {
        if (VEC) {
            // K % 16 == 0 path: float4 loads
            int r = tid >> 2;
            int kq = (tid & 3) << 2;
            int row = row0 + r;
            float4 a4 = make_float4(0.f, 0.f, 0.f, 0.f);
            if (row < N) a4 = *reinterpret_cast<const float4*>(A + (size_t)row * K + k0 + kq);
            As[kq + 0][r] = a4.x; As[kq + 1][r] = a4.y;
            As[kq + 2][r] = a4.z; As[kq + 3][r] = a4.w;
            int kk = tid >> 4;
            int c4 = (tid & 15) << 2;
            float4 b4 = *reinterpret_cast<const float4*>(B + (size_t)(k0 + kk) * M + col0 + c4);
            *reinterpret_cast<float4*>(&Bs[kk][c4]) = b4;
        } else {
#pragma unroll
            for (int i = 0; i < 4; ++i) {
                int idx = i * 256 + tid;
                int r = idx >> 4, kk = idx & 15;
                int row = row0 + r;
                As[kk][r] = (row < N && (k0 + kk) < K) ? A[(size_t)row * K + k0 + kk] : 0.f;
                int kb = idx >> 6, c = idx & 63;
                Bs[kb][c] = ((k0 + kb) < K) ? B[(size_t)(k0 + kb) * M + col0 + c] : 0.f;
            }
        }
        __syncthreads();
#pragma unroll
        for (int kk = 0; kk < 16; ++kk) {
            float4 a4 = *reinterpret_cast<const float4*>(&As[kk][ty << 2]);
            float4 b4 = *reinterpret_cast<const float4*>(&Bs[kk][tx << 2]);
            float a[4] = {a4.x, a4.y, a4.z, a4.w};
            float b[4] = {b4.x, b4.y, b4.z, b4.w};
#pragma unroll
            for (int i = 0; i < 4; ++i)
#pragma unroll
                for (int j = 0; j < 4; ++j)
                    acc[i][j] += a[i] * b[j];
        }
        __syncthreads();
    }

#pragma unroll
    for (int i = 0; i < 4; ++i) {
        int row = row0 + (ty << 2) + i;
        if (row >= N) continue;
        int col = col0 + (tx << 2);
        float4 o = make_float4(acc[i][0], acc[i][1], acc[i][2], acc[i][3]);
        if (bias) {
            o.x += bias[col + 0]; o.y += bias[col + 1];
            o.z += bias[col + 2]; o.w += bias[col + 3];
        }
        *reinterpret_cast<float4*>(C + (size_t)row * M + col) = o;
    }
}

// ---------------- per-node attention coefficients --------------------------
// block = 512 threads (8 waves), one node per block; wave w = head w.
__global__ void alpha_kernel(const float* __restrict__ h, const float* __restrict__ att_s,
                             const float* __restrict__ att_d, float* __restrict__ as_out,
                             float* __restrict__ ad_out, int n) {
    int i = blockIdx.x;
    int hd = threadIdx.x >> 6;
    int lane = threadIdx.x & 63;
    float hv = h[(size_t)i * HID + (hd << 6) + lane];
    float vs = hv * att_s[(hd << 6) + lane];
    float vd = hv * att_d[(hd << 6) + lane];
#pragma unroll
    for (int off = 32; off > 0; off >>= 1) {
        vs += __shfl_xor(vs, off);
        vd += __shfl_xor(vd, off);
    }
    if (lane == 0) {
        as_out[i * HEADS + hd] = vs;
        ad_out[i * HEADS + hd] = vd;
    }
}

// ---------------- CSR build ------------------------------------------------
__global__ void count_kernel(const int* __restrict__ ei, int* __restrict__ counts) {
    int e = blockIdx.x * blockDim.x + threadIdx.x;
    int tot = N_EDGES + N_NODES;
    if (e >= tot) return;
    int dst = e < N_EDGES ? ei[N_EDGES + e] : e - N_EDGES;
    atomicAdd(&counts[dst], 1);
}

__global__ void scan1_kernel(const int* __restrict__ counts, int* __restrict__ offsets,
                             int* __restrict__ bsums, int n) {
    __shared__ int tmp[1024];
    int tid = threadIdx.x;
    int gid = blockIdx.x * 1024 + tid;
    tmp[tid] = gid < n ? counts[gid] : 0;
    __syncthreads();
    for (int off = 1; off < 1024; off <<= 1) {
        int t = tid >= off ? tmp[tid - off] : 0;
        __syncthreads();
        tmp[tid] += t;
        __syncthreads();
    }
    if (gid < n) offsets[gid + 1] = tmp[tid];
    if (tid == 1023) bsums[blockIdx.x] = tmp[1023];
}

__global__ void scan2_kernel(int* bsums, int nb) {
    if (threadIdx.x == 0) {
        int s = 0;
        for (int i = 0; i < nb; ++i) { s += bsums[i]; bsums[i] = s; }
    }
}

__global__ void scan3_kernel(const int* __restrict__ counts, int* __restrict__ offsets,
                             const int* __restrict__ bsums, int* __restrict__ wp, int n) {
    int tid = threadIdx.x;
    int gid = blockIdx.x * 1024 + tid;
    if (gid == 0) offsets[0] = 0;
    if (gid >= n) return;
    int add = blockIdx.x > 0 ? bsums[blockIdx.x - 1] : 0;
    int v = offsets[gid + 1] + add;
    offsets[gid + 1] = v;
    wp[gid] = v - counts[gid];
}

__global__ void scatter_kernel(const int* __restrict__ ei, int* __restrict__ wp,
                               int* __restrict__ eids) {
    int e = blockIdx.x * blockDim.x + threadIdx.x;
    int tot = N_EDGES + N_NODES;
    if (e >= tot) return;
    int dst = e < N_EDGES ? ei[N_EDGES + e] : e - N_EDGES;
    int pos = atomicAdd(&wp[dst], 1);
    eids[pos] = e;
}

// ---------------- softmax-attention aggregation ----------------------------
// block = 512 threads, one dst node per block. 3 passes over incident edges:
// max, denom (online softmax), then weighted accumulation of h[src] rows.
__global__ void agg_kernel(const float* __restrict__ h, const float* __restrict__ as,
                           const float* __restrict__ ad, const int* __restrict__ offsets,
                           const int* __restrict__ eids, const int* __restrict__ esrc,
                           const float* __restrict__ bias, float* __restrict__ out) {
    int i = blockIdx.x;
    int tid = threadIdx.x;
    int hd = tid >> 6, lane = tid & 63;
    int beg = offsets[i], end = offsets[i + 1];
    int deg = end - beg;
    __shared__ float m_sh[HEADS], d_sh[HEADS];
    float adv = ad[i * HEADS + hd];

    // pass 1: max logit per head
    float lm = -1e30f;
    for (int e = lane; e < deg; e += 64) {
        int eid = eids[beg + e];
        int s = eid < N_EDGES ? esrc[eid] : eid - N_EDGES;
        lm = fmaxf(lm, lrelu(as[s * HEADS + hd] + adv));
    }
#pragma unroll
    for (int off = 32; off > 0; off >>= 1) lm = fmaxf(lm, __shfl_xor(lm, off));
    if (lane == 0) m_sh[hd] = lm;
    __syncthreads();
    float m = m_sh[hd];

    // pass 2: denominator
    float ls = 0.f;
    for (int e = lane; e < deg; e += 64) {
        int eid = eids[beg + e];
        int s = eid < N_EDGES ? esrc[eid] : eid - N_EDGES;
        ls += __expf(lrelu(as[s * HEADS + hd] + adv) - m);
    }
#pragma unroll
    for (int off = 32; off > 0; off >>= 1) ls += __shfl_xor(ls, off);
    if (lane == 0) d_sh[hd] = ls;
    __syncthreads();
    float inv_d = 1.f / d_sh[hd];

    // pass 3: weighted accumulation; thread tid owns channel tid.
    float acc = 0.f;
    for (int e = 0; e < deg; ++e) {
        int eid = eids[beg + e];
        int s = eid < N_EDGES ? esrc[eid] : eid - N_EDGES;
        float w = __expf(lrelu(as[s * HEADS + hd] + adv) - m);
        acc += w * h[(size_t)s * HID + tid];
    }
    out[(size_t)i * HID + tid] = acc * inv_d + bias[tid];
}

// ---------------- batchnorm ------------------------------------------------
__global__ void bn_stats_kernel(const float* __restrict__ x, float* __restrict__ sum,
                                float* __restrict__ sumsq, int n) {
    int tid = threadIdx.x; // 256
    int rows_per_block = (n + gridDim.x - 1) / gridDim.x;
    int r0 = blockIdx.x * rows_per_block;
    int r1 = min(n, r0 + rows_per_block);
    float s0 = 0.f, q0 = 0.f, s1 = 0.f, q1 = 0.f;
    for (int r = r0; r < r1; ++r) {
        float v0 = x[(size_t)r * HID + tid];
        float v1 = x[(size_t)r * HID + tid + 256];
        s0 += v0; q0 += v0 * v0;
        s1 += v1; q1 += v1 * v1;
    }
    atomicAdd(&sum[tid], s0);       atomicAdd(&sumsq[tid], q0);
    atomicAdd(&sum[tid + 256], s1); atomicAdd(&sumsq[tid + 256], q1);
}

__global__ void bn_apply_kernel(float* __restrict__ x, const float* __restrict__ sum,
                                const float* __restrict__ sumsq, const float* __restrict__ gamma,
                                const float* __restrict__ beta, int n) {
    size_t idx = (size_t)blockIdx.x * blockDim.x + threadIdx.x;
    size_t total = (size_t)n * HID;
    if (idx >= total) return;
    int c = idx & (HID - 1);
    float inv_n = 1.f / (float)n;
    float mu = sum[c] * inv_n;
    float var = sumsq[c] * inv_n - mu * mu;
    float sc = rsqrtf(var + 1e-5f) * gamma[c];
    float v = (x[idx] - mu) * sc + beta[c];
    x[idx] = v > 0.f ? v : 0.f;
}

// ---------------- pooling + output MLP -------------------------------------
__global__ void pool_kernel(const float* __restrict__ x, const int* __restrict__ batch,
                            float* __restrict__ pooled, int* __restrict__ gcnt) {
    int i = blockIdx.x;
    int g = batch[i];
    for (int c = threadIdx.x; c < HID; c += 256)
        atomicAdd(&pooled[(size_t)g * HID + c], x[(size_t)i * HID + c]);
    if (threadIdx.x == 0) atomicAdd(&gcnt[g], 1);
}

__global__ void mlp1_kernel(const float* __restrict__ pooled, const int* __restrict__ gcnt,
                            const float* __restrict__ w1, const float* __restrict__ b1,
                            float* __restrict__ h1) {
    __shared__ float row[HID];
    int g = blockIdx.x;
    int tid = threadIdx.x; // 256
    row[tid] = pooled[(size_t)g * HID + tid];
    row[tid + 256] = pooled[(size_t)g * HID + tid + 256];
    __syncthreads();
    float inv = 1.f / fmaxf((float)gcnt[g], 1.f);
    float acc = 0.f;
    for (int c = 0; c < HID; ++c) acc += row[c] * w1[c * 256 + tid];
    float v = acc * inv + b1[tid];
    h1[g * 256 + tid] = v > 0.f ? v : 0.f;
}

__global__ void mlp2_kernel(const float* __restrict__ h1, const float* __restrict__ w2,
                            const float* __restrict__ b2, float* __restrict__ out) {
    __shared__ float row[256];
    int g = blockIdx.x;
    int tid = threadIdx.x; // 64
    for (int j = tid; j < 256; j += 64) row[j] = h1[g * 256 + j];
    __syncthreads();
    if (tid < TARGETS) {
        float acc = 0.f;
        for (int j = 0; j < 256; ++j) acc += row[j] * w2[j * TARGETS + tid];
        out[g * TARGETS + tid] = acc + b2[tid];
    }
}

// ---------------------------------------------------------------------------
extern "C" void kernel_launch(void* const* d_in, const int* in_sizes, int n_in,
                              void* d_out, int out_size, void* d_ws, size_t ws_size,
                              hipStream_t stream) {
    const float* atom   = (const float*)d_in[0];
    // d_in[1] = bond_features: unused by the reference
    const int*   ei     = (const int*)d_in[2];   // [2, N_EDGES]
    const int*   batch  = (const int*)d_in[3];
    const float* atom_w = (const float*)d_in[4];
    const float* atom_b = (const float*)d_in[5];
    const float* gat_w  = (const float*)d_in[6];
    const float* att_s  = (const float*)d_in[7];
    const float* att_d  = (const float*)d_in[8];
    const float* gat_b  = (const float*)d_in[9];
    const float* bn_g   = (const float*)d_in[10];
    const float* bn_b   = (const float*)d_in[11];
    const float* w1     = (const float*)d_in[12];
    const float* b1     = (const float*)d_in[13];
    const float* w2     = (const float*)d_in[14];
    const float* b2     = (const float*)d_in[15];
    float* out = (float*)d_out;

    const int ETOT = N_EDGES + N_NODES;

    char* ws = (char*)d_ws;
    size_t off = 0;
    auto alloc = [&](size_t bytes) {
        void* p = ws + off;
        off += (bytes + 255) & ~(size_t)255;
        return p;
    };
    float* x      = (float*)alloc((size_t)N_NODES * HID * 4);
    float* h      = (float*)alloc((size_t)N_NODES * HID * 4);
    float* as_    = (float*)alloc((size_t)N_NODES * HEADS * 4);
    float* ad_    = (float*)alloc((size_t)N_NODES * HEADS * 4);
    int* counts   = (int*)alloc(N_NODES * 4);
    int* offsets  = (int*)alloc((N_NODES + 1) * 4);
    int* wp       = (int*)alloc(N_NODES * 4);
    int* eids     = (int*)alloc(ETOT * 4);
    int* bsums    = (int*)alloc(64 * 4);
    float* bn_sum = (float*)alloc(HID * 4);
    float* bn_sq  = (float*)alloc(HID * 4);
    float* pooled = (float*)alloc((size_t)N_GRAPHS * HID * 4);
    int* gcnt     = (int*)alloc(N_GRAPHS * 4);
    float* h1     = (float*)alloc((size_t)N_GRAPHS * 256 * 4);

    // ---- CSR build (by dst, with self-loops appended as eid >= N_EDGES) ----
    hipMemsetAsync(counts, 0, N_NODES * 4, stream);
    count_kernel<<<(ETOT + 255) / 256, 256, 0, stream>>>(ei, counts);
    int nb = (N_NODES + 1023) / 1024;
    scan1_kernel<<<nb, 1024, 0, stream>>>(counts, offsets, bsums, N_NODES);
    scan2_kernel<<<1, 64, 0, stream>>>(bsums, nb);
    scan3_kernel<<<nb, 1024, 0, stream>>>(counts, offsets, bsums, wp, N_NODES);
    scatter_kernel<<<(ETOT + 255) / 256, 256, 0, stream>>>(ei, wp, eids);

    // ---- atom projection: x = atom @ atom_w + atom_b ----
    gemm_kernel<0><<<dim3((N_NODES + 63) / 64, HID / 64), 256, 0, stream>>>(
        atom, atom_w, atom_b, x, N_NODES, ATOM_DIM, HID);

    // ---- 6 GAT layers ----
    for (int l = 0; l < LAYERS; ++l) {
        const float* W = gat_w + (size_t)l * HID * HID;
        gemm_kernel<1><<<dim3((N_NODES + 63) / 64, HID / 64), 256, 0, stream>>>(
            x, W, nullptr, h, N_NODES, HID, HID);
        alpha_kernel<<<N_NODES, 512, 0, stream>>>(h, att_s + l * HID, att_d + l * HID, as_, ad_, N_NODES);
        agg_kernel<<<N_NODES, 512, 0, stream>>>(h, as_, ad_, offsets, eids, ei, gat_b + l * HID, x);
        hipMemsetAsync(bn_sum, 0, HID * 4, stream);
        hipMemsetAsync(bn_sq, 0, HID * 4, stream);
        bn_stats_kernel<<<256, 256, 0, stream>>>(x, bn_sum, bn_sq, N_NODES);
        bn_apply_kernel<<<(int)(((size_t)N_NODES * HID + 255) / 256), 256, 0, stream>>>(
            x, bn_sum, bn_sq, bn_g + l * HID, bn_b + l * HID, N_NODES);
    }

    // ---- global mean pool + MLP head ----
    hipMemsetAsync(pooled, 0, (size_t)N_GRAPHS * HID * 4, stream);
    hipMemsetAsync(gcnt, 0, N_GRAPHS * 4, stream);
    pool_kernel<<<N_NODES, 256, 0, stream>>>(x, batch, pooled, gcnt);
    mlp1_kernel<<<N_GRAPHS, 256, 0, stream>>>(pooled, gcnt, w1, b1, h1);
    mlp2_kernel<<<N_GRAPHS, 64, 0, stream>>>(h1, w2, b2, out);
}

// Round 3
// 3170.070 us; speedup vs baseline: 1.5203x; 1.5203x over previous
//
#include <hip/hip_runtime.h>
#include <hip/hip_bf16.h>

// ---------------------------------------------------------------------------
// MolecularGNN: atom proj -> 6x (GATConv + BN + ReLU) -> mean pool -> MLP
// Round 3: bf16 MFMA layer GEMMs with fp32->bf16 convert-on-stage (no xb
// buffer: round-2 crashed on workspace overflow at ~270MB; ws is ~256MiB).
// Workspace budget: x(102.4) + h(102.4) + Wt(3.1) + misc(11) = ~219 MB.
// ---------------------------------------------------------------------------

#define N_NODES 50000
#define N_EDGES 150000
#define N_GRAPHS 2000
#define ATOM_DIM 100
#define HID 512
#define HEADS 8
#define HEAD_DIM 64
#define LAYERS 6
#define TARGETS 13

typedef __attribute__((ext_vector_type(8))) short bf16x8;
typedef __attribute__((ext_vector_type(4))) float f32x4;

__device__ __forceinline__ float lrelu(float v) { return v > 0.f ? v : 0.2f * v; }

__device__ __forceinline__ unsigned short f2bf(float v) {
    __hip_bfloat16 b = __float2bfloat16(v);
    return *reinterpret_cast<unsigned short*>(&b);
}

// ---------------- fp32 GEMM (atom projection only, K=100) ------------------
__launch_bounds__(256)
__global__ void gemm_f32_kernel(const float* __restrict__ A, const float* __restrict__ B,
                                const float* __restrict__ bias, float* __restrict__ C,
                                int N, int K, int M) {
    __shared__ __align__(16) float As[16][68];
    __shared__ __align__(16) float Bs[16][64];
    const int tid = threadIdx.x;
    const int row0 = blockIdx.x * 64;
    const int col0 = blockIdx.y * 64;
    const int tx = tid & 15, ty = tid >> 4;
    float acc[4][4] = {};

    for (int k0 = 0; k0 < K; k0 += 16) {
#pragma unroll
        for (int i = 0; i < 4; ++i) {
            int idx = i * 256 + tid;
            int r = idx >> 4, kk = idx & 15;
            int row = row0 + r;
            As[kk][r] = (row < N && (k0 + kk) < K) ? A[(size_t)row * K + k0 + kk] : 0.f;
            int kb = idx >> 6, c = idx & 63;
            Bs[kb][c] = ((k0 + kb) < K) ? B[(size_t)(k0 + kb) * M + col0 + c] : 0.f;
        }
        __syncthreads();
#pragma unroll
        for (int kk = 0; kk < 16; ++kk) {
            float4 a4 = *reinterpret_cast<const float4*>(&As[kk][ty << 2]);
            float4 b4 = *reinterpret_cast<const float4*>(&Bs[kk][tx << 2]);
            float a[4] = {a4.x, a4.y, a4.z, a4.w};
            float b[4] = {b4.x, b4.y, b4.z, b4.w};
#pragma unroll
            for (int i = 0; i < 4; ++i)
#pragma unroll
                for (int j = 0; j < 4; ++j)
                    acc[i][j] += a[i] * b[j];
        }
        __syncthreads();
    }

#pragma unroll
    for (int i = 0; i < 4; ++i) {
        int row = row0 + (ty << 2) + i;
        if (row >= N) continue;
        int col = col0 + (tx << 2);
        float4 o = make_float4(acc[i][0] + bias[col + 0], acc[i][1] + bias[col + 1],
                               acc[i][2] + bias[col + 2], acc[i][3] + bias[col + 3]);
        *reinterpret_cast<float4*>(C + (size_t)row * M + col) = o;
    }
}

// ---------------- weight transpose + bf16 convert --------------------------
// Wt[l][m][k] = bf16(W[l][k][m]); all 6 layers in one launch.
__global__ void wtrans_kernel(const float* __restrict__ W, __hip_bfloat16* __restrict__ Wt) {
    __shared__ float t[32][33];
    int l = blockIdx.z;
    int k0 = blockIdx.x * 32, m0 = blockIdx.y * 32;
    const float* Wl = W + (size_t)l * HID * HID;
    __hip_bfloat16* Wtl = Wt + (size_t)l * HID * HID;
#pragma unroll
    for (int i = 0; i < 32; i += 8)
        t[threadIdx.y + i][threadIdx.x] = Wl[(size_t)(k0 + threadIdx.y + i) * HID + m0 + threadIdx.x];
    __syncthreads();
#pragma unroll
    for (int i = 0; i < 32; i += 8)
        Wtl[(size_t)(m0 + threadIdx.y + i) * HID + k0 + threadIdx.x] =
            __float2bfloat16(t[threadIdx.x][threadIdx.y + i]);
}

// ---------------- bf16 MFMA GEMM: C[N,512] = bf16(A[N,512]) @ Bt[512,512]^T
// A is fp32 in global; converted to bf16 while staging to LDS.
// 128x128 tile, BK=32, 256 threads = 4 waves, each wave 64x64 (4x4 MFMA).
__launch_bounds__(256)
__global__ void gemm_mfma_kernel(const float* __restrict__ A,
                                 const __hip_bfloat16* __restrict__ Bt,
                                 float* __restrict__ C, int N) {
    constexpr int K = HID;
    constexpr int LDA = 40; // shorts; 80B row stride
    __shared__ __align__(16) short As[128 * LDA];
    __shared__ __align__(16) short Bs[128 * LDA];
    const int tid = threadIdx.x;
    const int wave = tid >> 6, lane = tid & 63;
    const int row0 = blockIdx.x * 128, col0 = blockIdx.y * 128;
    const int wr = (wave >> 1) * 64, wc = (wave & 1) * 64;
    const int q = lane >> 4, r16 = lane & 15;
    f32x4 acc[4][4] = {};

    for (int k0 = 0; k0 < K; k0 += 32) {
#pragma unroll
        for (int c = tid; c < 512; c += 256) {
            int rrow = c >> 2, koff = (c & 3) << 3;
            int grow = row0 + rrow;
            // A: 8 fp32 -> 8 bf16
            float4 v0 = make_float4(0.f, 0.f, 0.f, 0.f), v1 = v0;
            if (grow < N) {
                const float* ap = A + (size_t)grow * K + k0 + koff;
                v0 = *reinterpret_cast<const float4*>(ap);
                v1 = *reinterpret_cast<const float4*>(ap + 4);
            }
            ushort4 p0, p1;
            p0.x = f2bf(v0.x); p0.y = f2bf(v0.y); p0.z = f2bf(v0.z); p0.w = f2bf(v0.w);
            p1.x = f2bf(v1.x); p1.y = f2bf(v1.y); p1.z = f2bf(v1.z); p1.w = f2bf(v1.w);
            *reinterpret_cast<ushort4*>(&As[rrow * LDA + koff]) = p0;
            *reinterpret_cast<ushort4*>(&As[rrow * LDA + koff + 4]) = p1;
            // B: already bf16, 16B copy
            float4 w = *reinterpret_cast<const float4*>(Bt + (size_t)(col0 + rrow) * K + k0 + koff);
            *reinterpret_cast<float4*>(&Bs[rrow * LDA + koff]) = w;
        }
        __syncthreads();
        bf16x8 a[4], b[4];
#pragma unroll
        for (int i = 0; i < 4; ++i)
            a[i] = *reinterpret_cast<const bf16x8*>(&As[(wr + i * 16 + r16) * LDA + q * 8]);
#pragma unroll
        for (int j = 0; j < 4; ++j)
            b[j] = *reinterpret_cast<const bf16x8*>(&Bs[(wc + j * 16 + r16) * LDA + q * 8]);
#pragma unroll
        for (int i = 0; i < 4; ++i)
#pragma unroll
            for (int j = 0; j < 4; ++j)
                acc[i][j] = __builtin_amdgcn_mfma_f32_16x16x32_bf16(a[i], b[j], acc[i][j], 0, 0, 0);
        __syncthreads();
    }

    // C/D layout: col = lane&15, row = (lane>>4)*4 + reg
#pragma unroll
    for (int i = 0; i < 4; ++i) {
#pragma unroll
        for (int rr = 0; rr < 4; ++rr) {
            int grow = row0 + wr + i * 16 + q * 4 + rr;
            if (grow >= N) continue;
#pragma unroll
            for (int j = 0; j < 4; ++j)
                C[(size_t)grow * HID + col0 + wc + j * 16 + r16] = acc[i][j][rr];
        }
    }
}

// ---------------- per-node attention coefficients --------------------------
__global__ void alpha_kernel(const float* __restrict__ h, const float* __restrict__ att_s,
                             const float* __restrict__ att_d, float* __restrict__ as_out,
                             float* __restrict__ ad_out, int n) {
    int i = blockIdx.x;
    int hd = threadIdx.x >> 6;
    int lane = threadIdx.x & 63;
    float hv = h[(size_t)i * HID + (hd << 6) + lane];
    float vs = hv * att_s[(hd << 6) + lane];
    float vd = hv * att_d[(hd << 6) + lane];
#pragma unroll
    for (int off = 32; off > 0; off >>= 1) {
        vs += __shfl_xor(vs, off);
        vd += __shfl_xor(vd, off);
    }
    if (lane == 0) {
        as_out[i * HEADS + hd] = vs;
        ad_out[i * HEADS + hd] = vd;
    }
}

// ---------------- CSR build ------------------------------------------------
__global__ void count_kernel(const int* __restrict__ ei, int* __restrict__ counts) {
    int e = blockIdx.x * blockDim.x + threadIdx.x;
    int tot = N_EDGES + N_NODES;
    if (e >= tot) return;
    int dst = e < N_EDGES ? ei[N_EDGES + e] : e - N_EDGES;
    atomicAdd(&counts[dst], 1);
}

__global__ void scan1_kernel(const int* __restrict__ counts, int* __restrict__ offsets,
                             int* __restrict__ bsums, int n) {
    __shared__ int tmp[1024];
    int tid = threadIdx.x;
    int gid = blockIdx.x * 1024 + tid;
    tmp[tid] = gid < n ? counts[gid] : 0;
    __syncthreads();
    for (int off = 1; off < 1024; off <<= 1) {
        int t = tid >= off ? tmp[tid - off] : 0;
        __syncthreads();
        tmp[tid] += t;
        __syncthreads();
    }
    if (gid < n) offsets[gid + 1] = tmp[tid];
    if (tid == 1023) bsums[blockIdx.x] = tmp[1023];
}

__global__ void scan2_kernel(int* bsums, int nb) {
    if (threadIdx.x == 0) {
        int s = 0;
        for (int i = 0; i < nb; ++i) { s += bsums[i]; bsums[i] = s; }
    }
}

__global__ void scan3_kernel(const int* __restrict__ counts, int* __restrict__ offsets,
                             const int* __restrict__ bsums, int* __restrict__ wp, int n) {
    int tid = threadIdx.x;
    int gid = blockIdx.x * 1024 + tid;
    if (gid == 0) offsets[0] = 0;
    if (gid >= n) return;
    int add = blockIdx.x > 0 ? bsums[blockIdx.x - 1] : 0;
    int v = offsets[gid + 1] + add;
    offsets[gid + 1] = v;
    wp[gid] = v - counts[gid];
}

__global__ void scatter_kernel(const int* __restrict__ ei, int* __restrict__ wp,
                               int* __restrict__ eids) {
    int e = blockIdx.x * blockDim.x + threadIdx.x;
    int tot = N_EDGES + N_NODES;
    if (e >= tot) return;
    int dst = e < N_EDGES ? ei[N_EDGES + e] : e - N_EDGES;
    int pos = atomicAdd(&wp[dst], 1);
    eids[pos] = e;
}

// ---------------- softmax-attention aggregation ----------------------------
__global__ void agg_kernel(const float* __restrict__ h, const float* __restrict__ as,
                           const float* __restrict__ ad, const int* __restrict__ offsets,
                           const int* __restrict__ eids, const int* __restrict__ esrc,
                           const float* __restrict__ bias, float* __restrict__ out) {
    int i = blockIdx.x;
    int tid = threadIdx.x;
    int hd = tid >> 6, lane = tid & 63;
    int beg = offsets[i], end = offsets[i + 1];
    int deg = end - beg;
    __shared__ float m_sh[HEADS], d_sh[HEADS];
    float adv = ad[i * HEADS + hd];

    float lm = -1e30f;
    for (int e = lane; e < deg; e += 64) {
        int eid = eids[beg + e];
        int s = eid < N_EDGES ? esrc[eid] : eid - N_EDGES;
        lm = fmaxf(lm, lrelu(as[s * HEADS + hd] + adv));
    }
#pragma unroll
    for (int off = 32; off > 0; off >>= 1) lm = fmaxf(lm, __shfl_xor(lm, off));
    if (lane == 0) m_sh[hd] = lm;
    __syncthreads();
    float m = m_sh[hd];

    float ls = 0.f;
    for (int e = lane; e < deg; e += 64) {
        int eid = eids[beg + e];
        int s = eid < N_EDGES ? esrc[eid] : eid - N_EDGES;
        ls += __expf(lrelu(as[s * HEADS + hd] + adv) - m);
    }
#pragma unroll
    for (int off = 32; off > 0; off >>= 1) ls += __shfl_xor(ls, off);
    if (lane == 0) d_sh[hd] = ls;
    __syncthreads();
    float inv_d = 1.f / d_sh[hd];

    float acc = 0.f;
    for (int e = 0; e < deg; ++e) {
        int eid = eids[beg + e];
        int s = eid < N_EDGES ? esrc[eid] : eid - N_EDGES;
        float w = __expf(lrelu(as[s * HEADS + hd] + adv) - m);
        acc += w * h[(size_t)s * HID + tid];
    }
    out[(size_t)i * HID + tid] = acc * inv_d + bias[tid];
}

// ---------------- batchnorm ------------------------------------------------
__global__ void bn_stats_kernel(const float* __restrict__ x, float* __restrict__ sum,
                                float* __restrict__ sumsq, int n) {
    int tid = threadIdx.x; // 256
    int rows_per_block = (n + gridDim.x - 1) / gridDim.x;
    int r0 = blockIdx.x * rows_per_block;
    int r1 = min(n, r0 + rows_per_block);
    float s0 = 0.f, q0 = 0.f, s1 = 0.f, q1 = 0.f;
    for (int r = r0; r < r1; ++r) {
        float v0 = x[(size_t)r * HID + tid];
        float v1 = x[(size_t)r * HID + tid + 256];
        s0 += v0; q0 += v0 * v0;
        s1 += v1; q1 += v1 * v1;
    }
    atomicAdd(&sum[tid], s0);       atomicAdd(&sumsq[tid], q0);
    atomicAdd(&sum[tid + 256], s1); atomicAdd(&sumsq[tid + 256], q1);
}

__global__ void bn_apply_kernel(float* __restrict__ x, const float* __restrict__ sum,
                                const float* __restrict__ sumsq, const float* __restrict__ gamma,
                                const float* __restrict__ beta, int n) {
    size_t idx4 = (size_t)blockIdx.x * blockDim.x + threadIdx.x;
    size_t total4 = (size_t)n * HID / 4;
    if (idx4 >= total4) return;
    size_t idx = idx4 * 4;
    int c = (int)(idx & (HID - 1));
    float inv_n = 1.f / (float)n;
    float4 v = *reinterpret_cast<const float4*>(x + idx);
    float* vv = reinterpret_cast<float*>(&v);
    float o[4];
#pragma unroll
    for (int t = 0; t < 4; ++t) {
        float mu = sum[c + t] * inv_n;
        float var = sumsq[c + t] * inv_n - mu * mu;
        float sc = rsqrtf(var + 1e-5f) * gamma[c + t];
        float val = (vv[t] - mu) * sc + beta[c + t];
        o[t] = val > 0.f ? val : 0.f;
    }
    *reinterpret_cast<float4*>(x + idx) = make_float4(o[0], o[1], o[2], o[3]);
}

// ---------------- pooling + output MLP -------------------------------------
__global__ void pool_kernel(const float* __restrict__ x, const int* __restrict__ batch,
                            float* __restrict__ pooled, int* __restrict__ gcnt) {
    int i = blockIdx.x;
    int g = batch[i];
    for (int c = threadIdx.x; c < HID; c += 256)
        atomicAdd(&pooled[(size_t)g * HID + c], x[(size_t)i * HID + c]);
    if (threadIdx.x == 0) atomicAdd(&gcnt[g], 1);
}

__global__ void mlp1_kernel(const float* __restrict__ pooled, const int* __restrict__ gcnt,
                            const float* __restrict__ w1, const float* __restrict__ b1,
                            float* __restrict__ h1) {
    __shared__ float row[HID];
    int g = blockIdx.x;
    int tid = threadIdx.x; // 256
    row[tid] = pooled[(size_t)g * HID + tid];
    row[tid + 256] = pooled[(size_t)g * HID + tid + 256];
    __syncthreads();
    float inv = 1.f / fmaxf((float)gcnt[g], 1.f);
    float acc = 0.f;
    for (int c = 0; c < HID; ++c) acc += row[c] * w1[c * 256 + tid];
    float v = acc * inv + b1[tid];
    h1[g * 256 + tid] = v > 0.f ? v : 0.f;
}

__global__ void mlp2_kernel(const float* __restrict__ h1, const float* __restrict__ w2,
                            const float* __restrict__ b2, float* __restrict__ out) {
    __shared__ float row[256];
    int g = blockIdx.x;
    int tid = threadIdx.x; // 64
    for (int j = tid; j < 256; j += 64) row[j] = h1[g * 256 + j];
    __syncthreads();
    if (tid < TARGETS) {
        float acc = 0.f;
        for (int j = 0; j < 256; ++j) acc += row[j] * w2[j * TARGETS + tid];
        out[g * TARGETS + tid] = acc + b2[tid];
    }
}

// ---------------------------------------------------------------------------
extern "C" void kernel_launch(void* const* d_in, const int* in_sizes, int n_in,
                              void* d_out, int out_size, void* d_ws, size_t ws_size,
                              hipStream_t stream) {
    const float* atom   = (const float*)d_in[0];
    const int*   ei     = (const int*)d_in[2];   // [2, N_EDGES]
    const int*   batch  = (const int*)d_in[3];
    const float* atom_w = (const float*)d_in[4];
    const float* atom_b = (const float*)d_in[5];
    const float* gat_w  = (const float*)d_in[6];
    const float* att_s  = (const float*)d_in[7];
    const float* att_d  = (const float*)d_in[8];
    const float* gat_b  = (const float*)d_in[9];
    const float* bn_g   = (const float*)d_in[10];
    const float* bn_b   = (const float*)d_in[11];
    const float* w1     = (const float*)d_in[12];
    const float* b1     = (const float*)d_in[13];
    const float* w2     = (const float*)d_in[14];
    const float* b2     = (const float*)d_in[15];
    float* out = (float*)d_out;

    const int ETOT = N_EDGES + N_NODES;

    char* ws = (char*)d_ws;
    size_t off = 0;
    auto alloc = [&](size_t bytes) {
        void* p = ws + off;
        off += (bytes + 255) & ~(size_t)255;
        return p;
    };
    float* x      = (float*)alloc((size_t)N_NODES * HID * 4);   // 102.4 MB
    float* h      = (float*)alloc((size_t)N_NODES * HID * 4);   // 102.4 MB
    __hip_bfloat16* Wt = (__hip_bfloat16*)alloc((size_t)LAYERS * HID * HID * 2); // 3.1 MB
    float* as_    = (float*)alloc((size_t)N_NODES * HEADS * 4);
    float* ad_    = (float*)alloc((size_t)N_NODES * HEADS * 4);
    int* counts   = (int*)alloc(N_NODES * 4);
    int* offsets  = (int*)alloc((N_NODES + 1) * 4);
    int* wp       = (int*)alloc(N_NODES * 4);
    int* eids     = (int*)alloc(ETOT * 4);
    int* bsums    = (int*)alloc(64 * 4);
    float* bn_sum = (float*)alloc(HID * 4);
    float* bn_sq  = (float*)alloc(HID * 4);
    float* pooled = (float*)alloc((size_t)N_GRAPHS * HID * 4);
    int* gcnt     = (int*)alloc(N_GRAPHS * 4);
    float* h1     = (float*)alloc((size_t)N_GRAPHS * 256 * 4);

    // ---- CSR build (by dst, self-loops appended as eid >= N_EDGES) ----
    hipMemsetAsync(counts, 0, N_NODES * 4, stream);
    count_kernel<<<(ETOT + 255) / 256, 256, 0, stream>>>(ei, counts);
    int nb = (N_NODES + 1023) / 1024;
    scan1_kernel<<<nb, 1024, 0, stream>>>(counts, offsets, bsums, N_NODES);
    scan2_kernel<<<1, 64, 0, stream>>>(bsums, nb);
    scan3_kernel<<<nb, 1024, 0, stream>>>(counts, offsets, bsums, wp, N_NODES);
    scatter_kernel<<<(ETOT + 255) / 256, 256, 0, stream>>>(ei, wp, eids);

    // ---- weights: transpose + bf16 convert (all 6 layers) ----
    wtrans_kernel<<<dim3(HID / 32, HID / 32, LAYERS), dim3(32, 8), 0, stream>>>(gat_w, Wt);

    // ---- atom projection -> x (fp32) ----
    gemm_f32_kernel<<<dim3((N_NODES + 63) / 64, HID / 64), 256, 0, stream>>>(
        atom, atom_w, atom_b, x, N_NODES, ATOM_DIM, HID);

    // ---- 6 GAT layers ----
    for (int l = 0; l < LAYERS; ++l) {
        gemm_mfma_kernel<<<dim3((N_NODES + 127) / 128, HID / 128), 256, 0, stream>>>(
            x, Wt + (size_t)l * HID * HID, h, N_NODES);
        alpha_kernel<<<N_NODES, 512, 0, stream>>>(h, att_s + l * HID, att_d + l * HID, as_, ad_, N_NODES);
        agg_kernel<<<N_NODES, 512, 0, stream>>>(h, as_, ad_, offsets, eids, ei, gat_b + l * HID, x);
        hipMemsetAsync(bn_sum, 0, HID * 4, stream);
        hipMemsetAsync(bn_sq, 0, HID * 4, stream);
        bn_stats_kernel<<<256, 256, 0, stream>>>(x, bn_sum, bn_sq, N_NODES);
        bn_apply_kernel<<<(int)(((size_t)N_NODES * HID / 4 + 255) / 256), 256, 0, stream>>>(
            x, bn_sum, bn_sq, bn_g + l * HID, bn_b + l * HID, N_NODES);
    }

    // ---- global mean pool + MLP head ----
    hipMemsetAsync(pooled, 0, (size_t)N_GRAPHS * HID * 4, stream);
    hipMemsetAsync(gcnt, 0, N_GRAPHS * 4, stream);
    pool_kernel<<<N_NODES, 256, 0, stream>>>(x, batch, pooled, gcnt);
    mlp1_kernel<<<N_GRAPHS, 256, 0, stream>>>(pooled, gcnt, w1, b1, h1);
    mlp2_kernel<<<N_GRAPHS, 64, 0, stream>>>(h1, w2, b2, out);
}

// Round 4
// 2654.308 us; speedup vs baseline: 1.8157x; 1.1943x over previous
//
#include <hip/hip_runtime.h>
#include <hip/hip_bf16.h>

// ---------------------------------------------------------------------------
// MolecularGNN: atom proj -> 6x (GATConv + BN + ReLU) -> mean pool -> MLP
// Round 4: agg_kernel restructured — CSR stores src directly (one less
// dependent load), single fused pass (no max-subtract; num+den together),
// per-edge weights precomputed into LDS so h-row gathers are independent.
// Workspace budget unchanged (~219 MB < 256 MiB).
// ---------------------------------------------------------------------------

#define N_NODES 50000
#define N_EDGES 150000
#define N_GRAPHS 2000
#define ATOM_DIM 100
#define HID 512
#define HEADS 8
#define HEAD_DIM 64
#define LAYERS 6
#define TARGETS 13
#define AGG_CHUNK 64

typedef __attribute__((ext_vector_type(8))) short bf16x8;
typedef __attribute__((ext_vector_type(4))) float f32x4;

__device__ __forceinline__ float lrelu(float v) { return v > 0.f ? v : 0.2f * v; }

__device__ __forceinline__ unsigned short f2bf(float v) {
    __hip_bfloat16 b = __float2bfloat16(v);
    return *reinterpret_cast<unsigned short*>(&b);
}

// ---------------- fp32 GEMM (atom projection only, K=100) ------------------
__launch_bounds__(256)
__global__ void gemm_f32_kernel(const float* __restrict__ A, const float* __restrict__ B,
                                const float* __restrict__ bias, float* __restrict__ C,
                                int N, int K, int M) {
    __shared__ __align__(16) float As[16][68];
    __shared__ __align__(16) float Bs[16][64];
    const int tid = threadIdx.x;
    const int row0 = blockIdx.x * 64;
    const int col0 = blockIdx.y * 64;
    const int tx = tid & 15, ty = tid >> 4;
    float acc[4][4] = {};

    for (int k0 = 0; k0 < K; k0 += 16) {
#pragma unroll
        for (int i = 0; i < 4; ++i) {
            int idx = i * 256 + tid;
            int r = idx >> 4, kk = idx & 15;
            int row = row0 + r;
            As[kk][r] = (row < N && (k0 + kk) < K) ? A[(size_t)row * K + k0 + kk] : 0.f;
            int kb = idx >> 6, c = idx & 63;
            Bs[kb][c] = ((k0 + kb) < K) ? B[(size_t)(k0 + kb) * M + col0 + c] : 0.f;
        }
        __syncthreads();
#pragma unroll
        for (int kk = 0; kk < 16; ++kk) {
            float4 a4 = *reinterpret_cast<const float4*>(&As[kk][ty << 2]);
            float4 b4 = *reinterpret_cast<const float4*>(&Bs[kk][tx << 2]);
            float a[4] = {a4.x, a4.y, a4.z, a4.w};
            float b[4] = {b4.x, b4.y, b4.z, b4.w};
#pragma unroll
            for (int i = 0; i < 4; ++i)
#pragma unroll
                for (int j = 0; j < 4; ++j)
                    acc[i][j] += a[i] * b[j];
        }
        __syncthreads();
    }

#pragma unroll
    for (int i = 0; i < 4; ++i) {
        int row = row0 + (ty << 2) + i;
        if (row >= N) continue;
        int col = col0 + (tx << 2);
        float4 o = make_float4(acc[i][0] + bias[col + 0], acc[i][1] + bias[col + 1],
                               acc[i][2] + bias[col + 2], acc[i][3] + bias[col + 3]);
        *reinterpret_cast<float4*>(C + (size_t)row * M + col) = o;
    }
}

// ---------------- weight transpose + bf16 convert --------------------------
__global__ void wtrans_kernel(const float* __restrict__ W, __hip_bfloat16* __restrict__ Wt) {
    __shared__ float t[32][33];
    int l = blockIdx.z;
    int k0 = blockIdx.x * 32, m0 = blockIdx.y * 32;
    const float* Wl = W + (size_t)l * HID * HID;
    __hip_bfloat16* Wtl = Wt + (size_t)l * HID * HID;
#pragma unroll
    for (int i = 0; i < 32; i += 8)
        t[threadIdx.y + i][threadIdx.x] = Wl[(size_t)(k0 + threadIdx.y + i) * HID + m0 + threadIdx.x];
    __syncthreads();
#pragma unroll
    for (int i = 0; i < 32; i += 8)
        Wtl[(size_t)(m0 + threadIdx.y + i) * HID + k0 + threadIdx.x] =
            __float2bfloat16(t[threadIdx.x][threadIdx.y + i]);
}

// ---------------- bf16 MFMA GEMM: C[N,512] = bf16(A[N,512]) @ Bt[512,512]^T
__launch_bounds__(256)
__global__ void gemm_mfma_kernel(const float* __restrict__ A,
                                 const __hip_bfloat16* __restrict__ Bt,
                                 float* __restrict__ C, int N) {
    constexpr int K = HID;
    constexpr int LDA = 40; // shorts; 80B row stride
    __shared__ __align__(16) short As[128 * LDA];
    __shared__ __align__(16) short Bs[128 * LDA];
    const int tid = threadIdx.x;
    const int wave = tid >> 6, lane = tid & 63;
    const int row0 = blockIdx.x * 128, col0 = blockIdx.y * 128;
    const int wr = (wave >> 1) * 64, wc = (wave & 1) * 64;
    const int q = lane >> 4, r16 = lane & 15;
    f32x4 acc[4][4] = {};

    for (int k0 = 0; k0 < K; k0 += 32) {
#pragma unroll
        for (int c = tid; c < 512; c += 256) {
            int rrow = c >> 2, koff = (c & 3) << 3;
            int grow = row0 + rrow;
            float4 v0 = make_float4(0.f, 0.f, 0.f, 0.f), v1 = v0;
            if (grow < N) {
                const float* ap = A + (size_t)grow * K + k0 + koff;
                v0 = *reinterpret_cast<const float4*>(ap);
                v1 = *reinterpret_cast<const float4*>(ap + 4);
            }
            ushort4 p0, p1;
            p0.x = f2bf(v0.x); p0.y = f2bf(v0.y); p0.z = f2bf(v0.z); p0.w = f2bf(v0.w);
            p1.x = f2bf(v1.x); p1.y = f2bf(v1.y); p1.z = f2bf(v1.z); p1.w = f2bf(v1.w);
            *reinterpret_cast<ushort4*>(&As[rrow * LDA + koff]) = p0;
            *reinterpret_cast<ushort4*>(&As[rrow * LDA + koff + 4]) = p1;
            float4 w = *reinterpret_cast<const float4*>(Bt + (size_t)(col0 + rrow) * K + k0 + koff);
            *reinterpret_cast<float4*>(&Bs[rrow * LDA + koff]) = w;
        }
        __syncthreads();
        bf16x8 a[4], b[4];
#pragma unroll
        for (int i = 0; i < 4; ++i)
            a[i] = *reinterpret_cast<const bf16x8*>(&As[(wr + i * 16 + r16) * LDA + q * 8]);
#pragma unroll
        for (int j = 0; j < 4; ++j)
            b[j] = *reinterpret_cast<const bf16x8*>(&Bs[(wc + j * 16 + r16) * LDA + q * 8]);
#pragma unroll
        for (int i = 0; i < 4; ++i)
#pragma unroll
            for (int j = 0; j < 4; ++j)
                acc[i][j] = __builtin_amdgcn_mfma_f32_16x16x32_bf16(a[i], b[j], acc[i][j], 0, 0, 0);
        __syncthreads();
    }

    // C/D layout: col = lane&15, row = (lane>>4)*4 + reg
#pragma unroll
    for (int i = 0; i < 4; ++i) {
#pragma unroll
        for (int rr = 0; rr < 4; ++rr) {
            int grow = row0 + wr + i * 16 + q * 4 + rr;
            if (grow >= N) continue;
#pragma unroll
            for (int j = 0; j < 4; ++j)
                C[(size_t)grow * HID + col0 + wc + j * 16 + r16] = acc[i][j][rr];
        }
    }
}

// ---------------- per-node attention coefficients --------------------------
__global__ void alpha_kernel(const float* __restrict__ h, const float* __restrict__ att_s,
                             const float* __restrict__ att_d, float* __restrict__ as_out,
                             float* __restrict__ ad_out, int n) {
    int i = blockIdx.x;
    int hd = threadIdx.x >> 6;
    int lane = threadIdx.x & 63;
    float hv = h[(size_t)i * HID + (hd << 6) + lane];
    float vs = hv * att_s[(hd << 6) + lane];
    float vd = hv * att_d[(hd << 6) + lane];
#pragma unroll
    for (int off = 32; off > 0; off >>= 1) {
        vs += __shfl_xor(vs, off);
        vd += __shfl_xor(vd, off);
    }
    if (lane == 0) {
        as_out[i * HEADS + hd] = vs;
        ad_out[i * HEADS + hd] = vd;
    }
}

// ---------------- CSR build ------------------------------------------------
__global__ void count_kernel(const int* __restrict__ ei, int* __restrict__ counts) {
    int e = blockIdx.x * blockDim.x + threadIdx.x;
    int tot = N_EDGES + N_NODES;
    if (e >= tot) return;
    int dst = e < N_EDGES ? ei[N_EDGES + e] : e - N_EDGES;
    atomicAdd(&counts[dst], 1);
}

__global__ void scan1_kernel(const int* __restrict__ counts, int* __restrict__ offsets,
                             int* __restrict__ bsums, int n) {
    __shared__ int tmp[1024];
    int tid = threadIdx.x;
    int gid = blockIdx.x * 1024 + tid;
    tmp[tid] = gid < n ? counts[gid] : 0;
    __syncthreads();
    for (int off = 1; off < 1024; off <<= 1) {
        int t = tid >= off ? tmp[tid - off] : 0;
        __syncthreads();
        tmp[tid] += t;
        __syncthreads();
    }
    if (gid < n) offsets[gid + 1] = tmp[tid];
    if (tid == 1023) bsums[blockIdx.x] = tmp[1023];
}

__global__ void scan2_kernel(int* bsums, int nb) {
    if (threadIdx.x == 0) {
        int s = 0;
        for (int i = 0; i < nb; ++i) { s += bsums[i]; bsums[i] = s; }
    }
}

__global__ void scan3_kernel(const int* __restrict__ counts, int* __restrict__ offsets,
                             const int* __restrict__ bsums, int* __restrict__ wp, int n) {
    int tid = threadIdx.x;
    int gid = blockIdx.x * 1024 + tid;
    if (gid == 0) offsets[0] = 0;
    if (gid >= n) return;
    int add = blockIdx.x > 0 ? bsums[blockIdx.x - 1] : 0;
    int v = offsets[gid + 1] + add;
    offsets[gid + 1] = v;
    wp[gid] = v - counts[gid];
}

// stores the edge's SOURCE node directly in CSR order (no eid indirection)
__global__ void scatter_kernel(const int* __restrict__ ei, int* __restrict__ wp,
                               int* __restrict__ csrc) {
    int e = blockIdx.x * blockDim.x + threadIdx.x;
    int tot = N_EDGES + N_NODES;
    if (e >= tot) return;
    int src = e < N_EDGES ? ei[e] : e - N_EDGES;
    int dst = e < N_EDGES ? ei[N_EDGES + e] : e - N_EDGES;
    int pos = atomicAdd(&wp[dst], 1);
    csrc[pos] = src;
}

// ---------------- softmax-attention aggregation (single fused pass) --------
// block = 512 threads, one dst node per block; thread tid owns channel tid.
// No max-subtraction: logits are O(+-2), exp is safe; ratio identical.
// Per chunk: lanes 0..cnt-1 precompute src + 8 head-weights into LDS, then
// all threads stream independent h rows (multiple loads in flight).
__launch_bounds__(512)
__global__ void agg_kernel(const float* __restrict__ h, const float* __restrict__ as,
                           const float* __restrict__ ad, const int* __restrict__ offsets,
                           const int* __restrict__ csrc, const float* __restrict__ bias,
                           float* __restrict__ out) {
    int i = blockIdx.x;
    int tid = threadIdx.x;
    int hd = tid >> 6;
    int beg = offsets[i];
    int deg = offsets[i + 1] - beg;
    __shared__ int s_sh[AGG_CHUNK];
    __shared__ float w_sh[AGG_CHUNK][HEADS];

    float acc = 0.f, den = 0.f;
    for (int c0 = 0; c0 < deg; c0 += AGG_CHUNK) {
        int cnt = min(AGG_CHUNK, deg - c0);
        __syncthreads(); // protect LDS from previous chunk's readers
        if (tid < cnt) {
            int s = csrc[beg + c0 + tid];
            s_sh[tid] = s;
            const float4* ap = reinterpret_cast<const float4*>(as + (size_t)s * HEADS);
            const float4* dp = reinterpret_cast<const float4*>(ad + (size_t)i * HEADS);
            float4 a0 = ap[0], a1 = ap[1];
            float4 d0 = dp[0], d1 = dp[1];
            w_sh[tid][0] = __expf(lrelu(a0.x + d0.x));
            w_sh[tid][1] = __expf(lrelu(a0.y + d0.y));
            w_sh[tid][2] = __expf(lrelu(a0.z + d0.z));
            w_sh[tid][3] = __expf(lrelu(a0.w + d0.w));
            w_sh[tid][4] = __expf(lrelu(a1.x + d1.x));
            w_sh[tid][5] = __expf(lrelu(a1.y + d1.y));
            w_sh[tid][6] = __expf(lrelu(a1.z + d1.z));
            w_sh[tid][7] = __expf(lrelu(a1.w + d1.w));
        }
        __syncthreads();
        for (int e = 0; e < cnt; ++e) {
            float w = w_sh[e][hd];                       // LDS broadcast
            acc += w * h[(size_t)s_sh[e] * HID + tid];   // independent 2KB row loads
            den += w;
        }
    }
    out[(size_t)i * HID + tid] = acc / den + bias[tid];
}

// ---------------- batchnorm ------------------------------------------------
__global__ void bn_stats_kernel(const float* __restrict__ x, float* __restrict__ sum,
                                float* __restrict__ sumsq, int n) {
    int tid = threadIdx.x; // 256
    int rows_per_block = (n + gridDim.x - 1) / gridDim.x;
    int r0 = blockIdx.x * rows_per_block;
    int r1 = min(n, r0 + rows_per_block);
    float s0 = 0.f, q0 = 0.f, s1 = 0.f, q1 = 0.f;
    for (int r = r0; r < r1; ++r) {
        float v0 = x[(size_t)r * HID + tid];
        float v1 = x[(size_t)r * HID + tid + 256];
        s0 += v0; q0 += v0 * v0;
        s1 += v1; q1 += v1 * v1;
    }
    atomicAdd(&sum[tid], s0);       atomicAdd(&sumsq[tid], q0);
    atomicAdd(&sum[tid + 256], s1); atomicAdd(&sumsq[tid + 256], q1);
}

__global__ void bn_apply_kernel(float* __restrict__ x, const float* __restrict__ sum,
                                const float* __restrict__ sumsq, const float* __restrict__ gamma,
                                const float* __restrict__ beta, int n) {
    size_t idx4 = (size_t)blockIdx.x * blockDim.x + threadIdx.x;
    size_t total4 = (size_t)n * HID / 4;
    if (idx4 >= total4) return;
    size_t idx = idx4 * 4;
    int c = (int)(idx & (HID - 1));
    float inv_n = 1.f / (float)n;
    float4 v = *reinterpret_cast<const float4*>(x + idx);
    float* vv = reinterpret_cast<float*>(&v);
    float o[4];
#pragma unroll
    for (int t = 0; t < 4; ++t) {
        float mu = sum[c + t] * inv_n;
        float var = sumsq[c + t] * inv_n - mu * mu;
        float sc = rsqrtf(var + 1e-5f) * gamma[c + t];
        float val = (vv[t] - mu) * sc + beta[c + t];
        o[t] = val > 0.f ? val : 0.f;
    }
    *reinterpret_cast<float4*>(x + idx) = make_float4(o[0], o[1], o[2], o[3]);
}

// ---------------- pooling + output MLP -------------------------------------
__global__ void pool_kernel(const float* __restrict__ x, const int* __restrict__ batch,
                            float* __restrict__ pooled, int* __restrict__ gcnt) {
    int i = blockIdx.x;
    int g = batch[i];
    for (int c = threadIdx.x; c < HID; c += 256)
        atomicAdd(&pooled[(size_t)g * HID + c], x[(size_t)i * HID + c]);
    if (threadIdx.x == 0) atomicAdd(&gcnt[g], 1);
}

__global__ void mlp1_kernel(const float* __restrict__ pooled, const int* __restrict__ gcnt,
                            const float* __restrict__ w1, const float* __restrict__ b1,
                            float* __restrict__ h1) {
    __shared__ float row[HID];
    int g = blockIdx.x;
    int tid = threadIdx.x; // 256
    row[tid] = pooled[(size_t)g * HID + tid];
    row[tid + 256] = pooled[(size_t)g * HID + tid + 256];
    __syncthreads();
    float inv = 1.f / fmaxf((float)gcnt[g], 1.f);
    float acc = 0.f;
    for (int c = 0; c < HID; ++c) acc += row[c] * w1[c * 256 + tid];
    float v = acc * inv + b1[tid];
    h1[g * 256 + tid] = v > 0.f ? v : 0.f;
}

__global__ void mlp2_kernel(const float* __restrict__ h1, const float* __restrict__ w2,
                            const float* __restrict__ b2, float* __restrict__ out) {
    __shared__ float row[256];
    int g = blockIdx.x;
    int tid = threadIdx.x; // 64
    for (int j = tid; j < 256; j += 64) row[j] = h1[g * 256 + j];
    __syncthreads();
    if (tid < TARGETS) {
        float acc = 0.f;
        for (int j = 0; j < 256; ++j) acc += row[j] * w2[j * TARGETS + tid];
        out[g * TARGETS + tid] = acc + b2[tid];
    }
}

// ---------------------------------------------------------------------------
extern "C" void kernel_launch(void* const* d_in, const int* in_sizes, int n_in,
                              void* d_out, int out_size, void* d_ws, size_t ws_size,
                              hipStream_t stream) {
    const float* atom   = (const float*)d_in[0];
    const int*   ei     = (const int*)d_in[2];   // [2, N_EDGES]
    const int*   batch  = (const int*)d_in[3];
    const float* atom_w = (const float*)d_in[4];
    const float* atom_b = (const float*)d_in[5];
    const float* gat_w  = (const float*)d_in[6];
    const float* att_s  = (const float*)d_in[7];
    const float* att_d  = (const float*)d_in[8];
    const float* gat_b  = (const float*)d_in[9];
    const float* bn_g   = (const float*)d_in[10];
    const float* bn_b   = (const float*)d_in[11];
    const float* w1     = (const float*)d_in[12];
    const float* b1     = (const float*)d_in[13];
    const float* w2     = (const float*)d_in[14];
    const float* b2     = (const float*)d_in[15];
    float* out = (float*)d_out;

    const int ETOT = N_EDGES + N_NODES;

    char* ws = (char*)d_ws;
    size_t off = 0;
    auto alloc = [&](size_t bytes) {
        void* p = ws + off;
        off += (bytes + 255) & ~(size_t)255;
        return p;
    };
    float* x      = (float*)alloc((size_t)N_NODES * HID * 4);   // 102.4 MB
    float* h      = (float*)alloc((size_t)N_NODES * HID * 4);   // 102.4 MB
    __hip_bfloat16* Wt = (__hip_bfloat16*)alloc((size_t)LAYERS * HID * HID * 2); // 3.1 MB
    float* as_    = (float*)alloc((size_t)N_NODES * HEADS * 4);
    float* ad_    = (float*)alloc((size_t)N_NODES * HEADS * 4);
    int* counts   = (int*)alloc(N_NODES * 4);
    int* offsets  = (int*)alloc((N_NODES + 1) * 4);
    int* wp       = (int*)alloc(N_NODES * 4);
    int* csrc     = (int*)alloc(ETOT * 4);
    int* bsums    = (int*)alloc(64 * 4);
    float* bn_sum = (float*)alloc(HID * 4);
    float* bn_sq  = (float*)alloc(HID * 4);
    float* pooled = (float*)alloc((size_t)N_GRAPHS * HID * 4);
    int* gcnt     = (int*)alloc(N_GRAPHS * 4);
    float* h1     = (float*)alloc((size_t)N_GRAPHS * 256 * 4);

    // ---- CSR build (by dst; self-loops appended; stores src per slot) ----
    hipMemsetAsync(counts, 0, N_NODES * 4, stream);
    count_kernel<<<(ETOT + 255) / 256, 256, 0, stream>>>(ei, counts);
    int nb = (N_NODES + 1023) / 1024;
    scan1_kernel<<<nb, 1024, 0, stream>>>(counts, offsets, bsums, N_NODES);
    scan2_kernel<<<1, 64, 0, stream>>>(bsums, nb);
    scan3_kernel<<<nb, 1024, 0, stream>>>(counts, offsets, bsums, wp, N_NODES);
    scatter_kernel<<<(ETOT + 255) / 256, 256, 0, stream>>>(ei, wp, csrc);

    // ---- weights: transpose + bf16 convert (all 6 layers) ----
    wtrans_kernel<<<dim3(HID / 32, HID / 32, LAYERS), dim3(32, 8), 0, stream>>>(gat_w, Wt);

    // ---- atom projection -> x (fp32) ----
    gemm_f32_kernel<<<dim3((N_NODES + 63) / 64, HID / 64), 256, 0, stream>>>(
        atom, atom_w, atom_b, x, N_NODES, ATOM_DIM, HID);

    // ---- 6 GAT layers ----
    for (int l = 0; l < LAYERS; ++l) {
        gemm_mfma_kernel<<<dim3((N_NODES + 127) / 128, HID / 128), 256, 0, stream>>>(
            x, Wt + (size_t)l * HID * HID, h, N_NODES);
        alpha_kernel<<<N_NODES, 512, 0, stream>>>(h, att_s + l * HID, att_d + l * HID, as_, ad_, N_NODES);
        agg_kernel<<<N_NODES, 512, 0, stream>>>(h, as_, ad_, offsets, csrc, gat_b + l * HID, x);
        hipMemsetAsync(bn_sum, 0, HID * 4, stream);
        hipMemsetAsync(bn_sq, 0, HID * 4, stream);
        bn_stats_kernel<<<256, 256, 0, stream>>>(x, bn_sum, bn_sq, N_NODES);
        bn_apply_kernel<<<(int)(((size_t)N_NODES * HID / 4 + 255) / 256), 256, 0, stream>>>(
            x, bn_sum, bn_sq, bn_g + l * HID, bn_b + l * HID, N_NODES);
    }

    // ---- global mean pool + MLP head ----
    hipMemsetAsync(pooled, 0, (size_t)N_GRAPHS * HID * 4, stream);
    hipMemsetAsync(gcnt, 0, N_GRAPHS * 4, stream);
    pool_kernel<<<N_NODES, 256, 0, stream>>>(x, batch, pooled, gcnt);
    mlp1_kernel<<<N_GRAPHS, 256, 0, stream>>>(pooled, gcnt, w1, b1, h1);
    mlp2_kernel<<<N_GRAPHS, 64, 0, stream>>>(h1, w2, b2, out);
}

// Round 5
// 2002.179 us; speedup vs baseline: 2.4071x; 1.3257x over previous
//
#include <hip/hip_runtime.h>
#include <hip/hip_bf16.h>

// ---------------------------------------------------------------------------
// MolecularGNN: atom proj -> 6x (GATConv + BN + ReLU) -> mean pool -> MLP
// Round 5: (a) agg -> wave-per-node (deg~4; 512-thread blocks were
// latency-bound at 27% VALU), (b) alpha fused into GEMM epilogue (wave's 64
// cols == one head), (c) BN apply+ReLU fused into next GEMM's A-staging via
// per-channel scale/shift (bn_prep); standalone apply only after layer 6.
// ---------------------------------------------------------------------------

#define N_NODES 50000
#define N_EDGES 150000
#define N_GRAPHS 2000
#define ATOM_DIM 100
#define HID 512
#define HEADS 8
#define HEAD_DIM 64
#define LAYERS 6
#define TARGETS 13

typedef __attribute__((ext_vector_type(8))) short bf16x8;
typedef __attribute__((ext_vector_type(4))) float f32x4;

__device__ __forceinline__ float lrelu(float v) { return v > 0.f ? v : 0.2f * v; }

__device__ __forceinline__ unsigned short f2bf(float v) {
    __hip_bfloat16 b = __float2bfloat16(v);
    return *reinterpret_cast<unsigned short*>(&b);
}

// ---------------- fp32 GEMM (atom projection only, K=100) ------------------
__launch_bounds__(256)
__global__ void gemm_f32_kernel(const float* __restrict__ A, const float* __restrict__ B,
                                const float* __restrict__ bias, float* __restrict__ C,
                                int N, int K, int M) {
    __shared__ __align__(16) float As[16][68];
    __shared__ __align__(16) float Bs[16][64];
    const int tid = threadIdx.x;
    const int row0 = blockIdx.x * 64;
    const int col0 = blockIdx.y * 64;
    const int tx = tid & 15, ty = tid >> 4;
    float acc[4][4] = {};

    for (int k0 = 0; k0 < K; k0 += 16) {
#pragma unroll
        for (int i = 0; i < 4; ++i) {
            int idx = i * 256 + tid;
            int r = idx >> 4, kk = idx & 15;
            int row = row0 + r;
            As[kk][r] = (row < N && (k0 + kk) < K) ? A[(size_t)row * K + k0 + kk] : 0.f;
            int kb = idx >> 6, c = idx & 63;
            Bs[kb][c] = ((k0 + kb) < K) ? B[(size_t)(k0 + kb) * M + col0 + c] : 0.f;
        }
        __syncthreads();
#pragma unroll
        for (int kk = 0; kk < 16; ++kk) {
            float4 a4 = *reinterpret_cast<const float4*>(&As[kk][ty << 2]);
            float4 b4 = *reinterpret_cast<const float4*>(&Bs[kk][tx << 2]);
            float a[4] = {a4.x, a4.y, a4.z, a4.w};
            float b[4] = {b4.x, b4.y, b4.z, b4.w};
#pragma unroll
            for (int i = 0; i < 4; ++i)
#pragma unroll
                for (int j = 0; j < 4; ++j)
                    acc[i][j] += a[i] * b[j];
        }
        __syncthreads();
    }

#pragma unroll
    for (int i = 0; i < 4; ++i) {
        int row = row0 + (ty << 2) + i;
        if (row >= N) continue;
        int col = col0 + (tx << 2);
        float4 o = make_float4(acc[i][0] + bias[col + 0], acc[i][1] + bias[col + 1],
                               acc[i][2] + bias[col + 2], acc[i][3] + bias[col + 3]);
        *reinterpret_cast<float4*>(C + (size_t)row * M + col) = o;
    }
}

// ---------------- weight transpose + bf16 convert --------------------------
__global__ void wtrans_kernel(const float* __restrict__ W, __hip_bfloat16* __restrict__ Wt) {
    __shared__ float t[32][33];
    int l = blockIdx.z;
    int k0 = blockIdx.x * 32, m0 = blockIdx.y * 32;
    const float* Wl = W + (size_t)l * HID * HID;
    __hip_bfloat16* Wtl = Wt + (size_t)l * HID * HID;
#pragma unroll
    for (int i = 0; i < 32; i += 8)
        t[threadIdx.y + i][threadIdx.x] = Wl[(size_t)(k0 + threadIdx.y + i) * HID + m0 + threadIdx.x];
    __syncthreads();
#pragma unroll
    for (int i = 0; i < 32; i += 8)
        Wtl[(size_t)(m0 + threadIdx.y + i) * HID + k0 + threadIdx.x] =
            __float2bfloat16(t[threadIdx.x][threadIdx.y + i]);
}

// ---------------- bf16 MFMA GEMM with fused BN-on-stage + alpha epilogue ---
// C[N,512] = bf16(relu(A*sc+sh)) @ Bt^T ; also writes as/ad per (row,head).
// A fp32; bn_sc==nullptr -> stage raw (layer 0). 128x128 tile, BK=32.
__launch_bounds__(256)
__global__ void gemm_mfma_kernel(const float* __restrict__ A,
                                 const __hip_bfloat16* __restrict__ Bt,
                                 float* __restrict__ C,
                                 const float* __restrict__ bn_sc,
                                 const float* __restrict__ bn_sh,
                                 const float* __restrict__ att_s,
                                 const float* __restrict__ att_d,
                                 float* __restrict__ as_out,
                                 float* __restrict__ ad_out,
                                 int N) {
    constexpr int K = HID;
    constexpr int LDA = 40; // shorts; 80B row stride
    __shared__ __align__(16) short As[128 * LDA];
    __shared__ __align__(16) short Bs[128 * LDA];
    __shared__ float scs[HID], shs[HID];
    const int tid = threadIdx.x;
    const int wave = tid >> 6, lane = tid & 63;
    const int row0 = blockIdx.x * 128, col0 = blockIdx.y * 128;
    const int wr = (wave >> 1) * 64, wc = (wave & 1) * 64;
    const int q = lane >> 4, r16 = lane & 15;
    const bool has_bn = (bn_sc != nullptr);
    if (has_bn) {
        for (int t = tid; t < HID; t += 256) { scs[t] = bn_sc[t]; shs[t] = bn_sh[t]; }
    }
    __syncthreads();
    f32x4 acc[4][4] = {};

    for (int k0 = 0; k0 < K; k0 += 32) {
#pragma unroll
        for (int c = tid; c < 512; c += 256) {
            int rrow = c >> 2, koff = (c & 3) << 3;
            int grow = row0 + rrow;
            float4 v0 = make_float4(0.f, 0.f, 0.f, 0.f), v1 = v0;
            if (grow < N) {
                const float* ap = A + (size_t)grow * K + k0 + koff;
                v0 = *reinterpret_cast<const float4*>(ap);
                v1 = *reinterpret_cast<const float4*>(ap + 4);
            }
            float vv[8] = {v0.x, v0.y, v0.z, v0.w, v1.x, v1.y, v1.z, v1.w};
            if (has_bn) {
                int cc = k0 + koff;
#pragma unroll
                for (int t = 0; t < 8; ++t) {
                    float val = fmaf(vv[t], scs[cc + t], shs[cc + t]);
                    vv[t] = val > 0.f ? val : 0.f;
                }
            }
            ushort4 p0, p1;
            p0.x = f2bf(vv[0]); p0.y = f2bf(vv[1]); p0.z = f2bf(vv[2]); p0.w = f2bf(vv[3]);
            p1.x = f2bf(vv[4]); p1.y = f2bf(vv[5]); p1.z = f2bf(vv[6]); p1.w = f2bf(vv[7]);
            *reinterpret_cast<ushort4*>(&As[rrow * LDA + koff]) = p0;
            *reinterpret_cast<ushort4*>(&As[rrow * LDA + koff + 4]) = p1;
            float4 w = *reinterpret_cast<const float4*>(Bt + (size_t)(col0 + rrow) * K + k0 + koff);
            *reinterpret_cast<float4*>(&Bs[rrow * LDA + koff]) = w;
        }
        __syncthreads();
        bf16x8 a[4], b[4];
#pragma unroll
        for (int i = 0; i < 4; ++i)
            a[i] = *reinterpret_cast<const bf16x8*>(&As[(wr + i * 16 + r16) * LDA + q * 8]);
#pragma unroll
        for (int j = 0; j < 4; ++j)
            b[j] = *reinterpret_cast<const bf16x8*>(&Bs[(wc + j * 16 + r16) * LDA + q * 8]);
#pragma unroll
        for (int i = 0; i < 4; ++i)
#pragma unroll
            for (int j = 0; j < 4; ++j)
                acc[i][j] = __builtin_amdgcn_mfma_f32_16x16x32_bf16(a[i], b[j], acc[i][j], 0, 0, 0);
        __syncthreads();
    }

    // C write. C/D layout: col = lane&15, row = (lane>>4)*4 + reg
#pragma unroll
    for (int i = 0; i < 4; ++i) {
#pragma unroll
        for (int rr = 0; rr < 4; ++rr) {
            int grow = row0 + wr + i * 16 + q * 4 + rr;
            if (grow >= N) continue;
#pragma unroll
            for (int j = 0; j < 4; ++j)
                C[(size_t)grow * HID + col0 + wc + j * 16 + r16] = acc[i][j][rr];
        }
    }

    // Fused alpha: this wave's 64 cols == head (col0+wc)/64; dot acc rows
    // with att vectors, reduce across the 16 r16 lanes.
    const int head = (col0 + wc) >> 6;
    float avs[4], avd[4];
#pragma unroll
    for (int j = 0; j < 4; ++j) {
        avs[j] = att_s[col0 + wc + j * 16 + r16];
        avd[j] = att_d[col0 + wc + j * 16 + r16];
    }
#pragma unroll
    for (int i = 0; i < 4; ++i) {
#pragma unroll
        for (int rr = 0; rr < 4; ++rr) {
            float ss = 0.f, dd = 0.f;
#pragma unroll
            for (int j = 0; j < 4; ++j) {
                float v = acc[i][j][rr];
                ss += v * avs[j];
                dd += v * avd[j];
            }
#pragma unroll
            for (int off = 8; off > 0; off >>= 1) {
                ss += __shfl_xor(ss, off);
                dd += __shfl_xor(dd, off);
            }
            int grow = row0 + wr + i * 16 + q * 4 + rr;
            if (r16 == 0 && grow < N) {
                as_out[(size_t)grow * HEADS + head] = ss;
                ad_out[(size_t)grow * HEADS + head] = dd;
            }
        }
    }
}

// ---------------- CSR build ------------------------------------------------
__global__ void count_kernel(const int* __restrict__ ei, int* __restrict__ counts) {
    int e = blockIdx.x * blockDim.x + threadIdx.x;
    int tot = N_EDGES + N_NODES;
    if (e >= tot) return;
    int dst = e < N_EDGES ? ei[N_EDGES + e] : e - N_EDGES;
    atomicAdd(&counts[dst], 1);
}

__global__ void scan1_kernel(const int* __restrict__ counts, int* __restrict__ offsets,
                             int* __restrict__ bsums, int n) {
    __shared__ int tmp[1024];
    int tid = threadIdx.x;
    int gid = blockIdx.x * 1024 + tid;
    tmp[tid] = gid < n ? counts[gid] : 0;
    __syncthreads();
    for (int off = 1; off < 1024; off <<= 1) {
        int t = tid >= off ? tmp[tid - off] : 0;
        __syncthreads();
        tmp[tid] += t;
        __syncthreads();
    }
    if (gid < n) offsets[gid + 1] = tmp[tid];
    if (tid == 1023) bsums[blockIdx.x] = tmp[1023];
}

__global__ void scan2_kernel(int* bsums, int nb) {
    if (threadIdx.x == 0) {
        int s = 0;
        for (int i = 0; i < nb; ++i) { s += bsums[i]; bsums[i] = s; }
    }
}

__global__ void scan3_kernel(const int* __restrict__ counts, int* __restrict__ offsets,
                             const int* __restrict__ bsums, int* __restrict__ wp, int n) {
    int tid = threadIdx.x;
    int gid = blockIdx.x * 1024 + tid;
    if (gid == 0) offsets[0] = 0;
    if (gid >= n) return;
    int add = blockIdx.x > 0 ? bsums[blockIdx.x - 1] : 0;
    int v = offsets[gid + 1] + add;
    offsets[gid + 1] = v;
    wp[gid] = v - counts[gid];
}

__global__ void scatter_kernel(const int* __restrict__ ei, int* __restrict__ wp,
                               int* __restrict__ csrc) {
    int e = blockIdx.x * blockDim.x + threadIdx.x;
    int tot = N_EDGES + N_NODES;
    if (e >= tot) return;
    int src = e < N_EDGES ? ei[e] : e - N_EDGES;
    int dst = e < N_EDGES ? ei[N_EDGES + e] : e - N_EDGES;
    int pos = atomicAdd(&wp[dst], 1);
    csrc[pos] = src;
}

// ---------------- softmax-attention aggregation ----------------------------
// One wave per dst node (8 nodes / 512-thread block). Lane owns 8 contiguous
// channels; head = lane>>3. No LDS, no barriers; edges 4-wide so all loads
// are independent. Softmax without max-subtract (logits O(+-2)).
__launch_bounds__(512)
__global__ void agg_kernel(const float* __restrict__ h, const float* __restrict__ as,
                           const float* __restrict__ ad, const int* __restrict__ offsets,
                           const int* __restrict__ csrc, const float* __restrict__ bias,
                           float* __restrict__ out) {
    const int wave = threadIdx.x >> 6, lane = threadIdx.x & 63;
    const int i = blockIdx.x * 8 + wave;
    const int head = lane >> 3;
    const int c0 = lane << 3;
    const int beg = offsets[i];
    const int deg = offsets[i + 1] - beg;
    const float adv = ad[(size_t)i * HEADS + head];

    float a0x = 0.f, a0y = 0.f, a0z = 0.f, a0w = 0.f;
    float a1x = 0.f, a1y = 0.f, a1z = 0.f, a1w = 0.f;
    float den = 0.f;

    for (int e0 = 0; e0 < deg; e0 += 4) {
        int m = deg - e0; if (m > 4) m = 4;
        int s[4];
#pragma unroll
        for (int k = 0; k < 4; ++k) {
            int kk = k < m ? k : m - 1;
            s[k] = csrc[beg + e0 + kk];
        }
        float w[4];
#pragma unroll
        for (int k = 0; k < 4; ++k)
            w[k] = (k < m) ? __expf(lrelu(as[(size_t)s[k] * HEADS + head] + adv)) : 0.f;
#pragma unroll
        for (int k = 0; k < 4; ++k) {
            const float4* hp = reinterpret_cast<const float4*>(h + (size_t)s[k] * HID + c0);
            float4 h0 = hp[0], h1 = hp[1];
            a0x += w[k] * h0.x; a0y += w[k] * h0.y; a0z += w[k] * h0.z; a0w += w[k] * h0.w;
            a1x += w[k] * h1.x; a1y += w[k] * h1.y; a1z += w[k] * h1.z; a1w += w[k] * h1.w;
            den += w[k];
        }
    }
    float inv = 1.f / den;
    const float4* bp = reinterpret_cast<const float4*>(bias + c0);
    float4 b0 = bp[0], b1 = bp[1];
    float4 o0 = make_float4(a0x * inv + b0.x, a0y * inv + b0.y, a0z * inv + b0.z, a0w * inv + b0.w);
    float4 o1 = make_float4(a1x * inv + b1.x, a1y * inv + b1.y, a1z * inv + b1.z, a1w * inv + b1.w);
    float4* op = reinterpret_cast<float4*>(out + (size_t)i * HID + c0);
    op[0] = o0; op[1] = o1;
}

// ---------------- batchnorm ------------------------------------------------
__global__ void bn_stats_kernel(const float* __restrict__ x, float* __restrict__ sum,
                                float* __restrict__ sumsq, int n) {
    int tid = threadIdx.x; // 256
    int rows_per_block = (n + gridDim.x - 1) / gridDim.x;
    int r0 = blockIdx.x * rows_per_block;
    int r1 = min(n, r0 + rows_per_block);
    float s0 = 0.f, q0 = 0.f, s1 = 0.f, q1 = 0.f;
    for (int r = r0; r < r1; ++r) {
        float v0 = x[(size_t)r * HID + tid];
        float v1 = x[(size_t)r * HID + tid + 256];
        s0 += v0; q0 += v0 * v0;
        s1 += v1; q1 += v1 * v1;
    }
    atomicAdd(&sum[tid], s0);       atomicAdd(&sumsq[tid], q0);
    atomicAdd(&sum[tid + 256], s1); atomicAdd(&sumsq[tid + 256], q1);
}

// per-channel scale/shift from accumulated stats
__global__ void bn_prep_kernel(const float* __restrict__ sum, const float* __restrict__ sumsq,
                               const float* __restrict__ gamma, const float* __restrict__ beta,
                               float* __restrict__ sc, float* __restrict__ sh, int n) {
    int c = threadIdx.x; // 512
    float inv_n = 1.f / (float)n;
    float mu = sum[c] * inv_n;
    float var = sumsq[c] * inv_n - mu * mu;
    float s = rsqrtf(var + 1e-5f) * gamma[c];
    sc[c] = s;
    sh[c] = beta[c] - mu * s;
}

// standalone apply (last layer only, feeds the pool)
__global__ void bn_apply_kernel(float* __restrict__ x, const float* __restrict__ sc,
                                const float* __restrict__ sh, int n) {
    size_t idx4 = (size_t)blockIdx.x * blockDim.x + threadIdx.x;
    size_t total4 = (size_t)n * HID / 4;
    if (idx4 >= total4) return;
    size_t idx = idx4 * 4;
    int c = (int)(idx & (HID - 1));
    float4 v = *reinterpret_cast<const float4*>(x + idx);
    float* vv = reinterpret_cast<float*>(&v);
    float o[4];
#pragma unroll
    for (int t = 0; t < 4; ++t) {
        float val = fmaf(vv[t], sc[c + t], sh[c + t]);
        o[t] = val > 0.f ? val : 0.f;
    }
    *reinterpret_cast<float4*>(x + idx) = make_float4(o[0], o[1], o[2], o[3]);
}

// ---------------- pooling + output MLP -------------------------------------
__global__ void pool_kernel(const float* __restrict__ x, const int* __restrict__ batch,
                            float* __restrict__ pooled, int* __restrict__ gcnt) {
    int i = blockIdx.x;
    int g = batch[i];
    for (int c = threadIdx.x; c < HID; c += 256)
        atomicAdd(&pooled[(size_t)g * HID + c], x[(size_t)i * HID + c]);
    if (threadIdx.x == 0) atomicAdd(&gcnt[g], 1);
}

__global__ void mlp1_kernel(const float* __restrict__ pooled, const int* __restrict__ gcnt,
                            const float* __restrict__ w1, const float* __restrict__ b1,
                            float* __restrict__ h1) {
    __shared__ float row[HID];
    int g = blockIdx.x;
    int tid = threadIdx.x; // 256
    row[tid] = pooled[(size_t)g * HID + tid];
    row[tid + 256] = pooled[(size_t)g * HID + tid + 256];
    __syncthreads();
    float inv = 1.f / fmaxf((float)gcnt[g], 1.f);
    float acc = 0.f;
    for (int c = 0; c < HID; ++c) acc += row[c] * w1[c * 256 + tid];
    float v = acc * inv + b1[tid];
    h1[g * 256 + tid] = v > 0.f ? v : 0.f;
}

__global__ void mlp2_kernel(const float* __restrict__ h1, const float* __restrict__ w2,
                            const float* __restrict__ b2, float* __restrict__ out) {
    __shared__ float row[256];
    int g = blockIdx.x;
    int tid = threadIdx.x; // 64
    for (int j = tid; j < 256; j += 64) row[j] = h1[g * 256 + j];
    __syncthreads();
    if (tid < TARGETS) {
        float acc = 0.f;
        for (int j = 0; j < 256; ++j) acc += row[j] * w2[j * TARGETS + tid];
        out[g * TARGETS + tid] = acc + b2[tid];
    }
}

// ---------------------------------------------------------------------------
extern "C" void kernel_launch(void* const* d_in, const int* in_sizes, int n_in,
                              void* d_out, int out_size, void* d_ws, size_t ws_size,
                              hipStream_t stream) {
    const float* atom   = (const float*)d_in[0];
    const int*   ei     = (const int*)d_in[2];   // [2, N_EDGES]
    const int*   batch  = (const int*)d_in[3];
    const float* atom_w = (const float*)d_in[4];
    const float* atom_b = (const float*)d_in[5];
    const float* gat_w  = (const float*)d_in[6];
    const float* att_s  = (const float*)d_in[7];
    const float* att_d  = (const float*)d_in[8];
    const float* gat_b  = (const float*)d_in[9];
    const float* bn_g   = (const float*)d_in[10];
    const float* bn_b   = (const float*)d_in[11];
    const float* w1     = (const float*)d_in[12];
    const float* b1     = (const float*)d_in[13];
    const float* w2     = (const float*)d_in[14];
    const float* b2     = (const float*)d_in[15];
    float* out = (float*)d_out;

    const int ETOT = N_EDGES + N_NODES;

    char* ws = (char*)d_ws;
    size_t off = 0;
    auto alloc = [&](size_t bytes) {
        void* p = ws + off;
        off += (bytes + 255) & ~(size_t)255;
        return p;
    };
    float* x      = (float*)alloc((size_t)N_NODES * HID * 4);   // 102.4 MB
    float* h      = (float*)alloc((size_t)N_NODES * HID * 4);   // 102.4 MB
    __hip_bfloat16* Wt = (__hip_bfloat16*)alloc((size_t)LAYERS * HID * HID * 2); // 3.1 MB
    float* as_    = (float*)alloc((size_t)N_NODES * HEADS * 4);
    float* ad_    = (float*)alloc((size_t)N_NODES * HEADS * 4);
    int* counts   = (int*)alloc(N_NODES * 4);
    int* offsets  = (int*)alloc((N_NODES + 1) * 4);
    int* wp       = (int*)alloc(N_NODES * 4);
    int* csrc     = (int*)alloc(ETOT * 4);
    int* bsums    = (int*)alloc(64 * 4);
    float* bn_sum = (float*)alloc(HID * 4);
    float* bn_sq  = (float*)alloc(HID * 4);
    float* bn_sc  = (float*)alloc(HID * 4);
    float* bn_sh  = (float*)alloc(HID * 4);
    float* pooled = (float*)alloc((size_t)N_GRAPHS * HID * 4);
    int* gcnt     = (int*)alloc(N_GRAPHS * 4);
    float* h1     = (float*)alloc((size_t)N_GRAPHS * 256 * 4);

    // ---- CSR build (by dst; self-loops appended; stores src per slot) ----
    hipMemsetAsync(counts, 0, N_NODES * 4, stream);
    count_kernel<<<(ETOT + 255) / 256, 256, 0, stream>>>(ei, counts);
    int nb = (N_NODES + 1023) / 1024;
    scan1_kernel<<<nb, 1024, 0, stream>>>(counts, offsets, bsums, N_NODES);
    scan2_kernel<<<1, 64, 0, stream>>>(bsums, nb);
    scan3_kernel<<<nb, 1024, 0, stream>>>(counts, offsets, bsums, wp, N_NODES);
    scatter_kernel<<<(ETOT + 255) / 256, 256, 0, stream>>>(ei, wp, csrc);

    // ---- weights: transpose + bf16 convert (all 6 layers) ----
    wtrans_kernel<<<dim3(HID / 32, HID / 32, LAYERS), dim3(32, 8), 0, stream>>>(gat_w, Wt);

    // ---- atom projection -> x (fp32) ----
    gemm_f32_kernel<<<dim3((N_NODES + 63) / 64, HID / 64), 256, 0, stream>>>(
        atom, atom_w, atom_b, x, N_NODES, ATOM_DIM, HID);

    // ---- 6 GAT layers ----
    for (int l = 0; l < LAYERS; ++l) {
        gemm_mfma_kernel<<<dim3((N_NODES + 127) / 128, HID / 128), 256, 0, stream>>>(
            x, Wt + (size_t)l * HID * HID, h,
            l == 0 ? nullptr : bn_sc, l == 0 ? nullptr : bn_sh,
            att_s + l * HID, att_d + l * HID, as_, ad_, N_NODES);
        agg_kernel<<<N_NODES / 8, 512, 0, stream>>>(h, as_, ad_, offsets, csrc,
                                                    gat_b + l * HID, x);
        hipMemsetAsync(bn_sum, 0, HID * 4, stream);
        hipMemsetAsync(bn_sq, 0, HID * 4, stream);
        bn_stats_kernel<<<256, 256, 0, stream>>>(x, bn_sum, bn_sq, N_NODES);
        bn_prep_kernel<<<1, HID, 0, stream>>>(bn_sum, bn_sq, bn_g + l * HID, bn_b + l * HID,
                                              bn_sc, bn_sh, N_NODES);
    }

    // ---- last layer's BN applied standalone (feeds the pool) ----
    bn_apply_kernel<<<(int)(((size_t)N_NODES * HID / 4 + 255) / 256), 256, 0, stream>>>(
        x, bn_sc, bn_sh, N_NODES);

    // ---- global mean pool + MLP head ----
    hipMemsetAsync(pooled, 0, (size_t)N_GRAPHS * HID * 4, stream);
    hipMemsetAsync(gcnt, 0, N_GRAPHS * 4, stream);
    pool_kernel<<<N_NODES, 256, 0, stream>>>(x, batch, pooled, gcnt);
    mlp1_kernel<<<N_GRAPHS, 256, 0, stream>>>(pooled, gcnt, w1, b1, h1);
    mlp2_kernel<<<N_GRAPHS, 64, 0, stream>>>(h1, w2, b2, out);
}

// Round 6
// 1644.304 us; speedup vs baseline: 2.9310x; 1.2176x over previous
//
#include <hip/hip_runtime.h>
#include <hip/hip_bf16.h>

// ---------------------------------------------------------------------------
// MolecularGNN: atom proj -> 6x (GATConv + BN + ReLU) -> mean pool -> MLP
// Round 6: (a) atom projection -> bf16 MFMA with K padded 100->128,
// (b) BN stats fused into agg epilogue (LDS reduce -> 128-bin atomics;
// bn_prep folds bins), (c) final BN apply fused into pool.
// ---------------------------------------------------------------------------

#define N_NODES 50000
#define N_EDGES 150000
#define N_GRAPHS 2000
#define ATOM_DIM 100
#define HID 512
#define HEADS 8
#define HEAD_DIM 64
#define LAYERS 6
#define TARGETS 13
#define NBINS 128

typedef __attribute__((ext_vector_type(8))) short bf16x8;
typedef __attribute__((ext_vector_type(4))) float f32x4;

__device__ __forceinline__ float lrelu(float v) { return v > 0.f ? v : 0.2f * v; }

__device__ __forceinline__ unsigned short f2bf(float v) {
    __hip_bfloat16 b = __float2bfloat16(v);
    return *reinterpret_cast<unsigned short*>(&b);
}

// ---------------- weight transpose + bf16 convert (layer weights) ----------
__global__ void wtrans_kernel(const float* __restrict__ W, __hip_bfloat16* __restrict__ Wt) {
    __shared__ float t[32][33];
    int l = blockIdx.z;
    int k0 = blockIdx.x * 32, m0 = blockIdx.y * 32;
    const float* Wl = W + (size_t)l * HID * HID;
    __hip_bfloat16* Wtl = Wt + (size_t)l * HID * HID;
#pragma unroll
    for (int i = 0; i < 32; i += 8)
        t[threadIdx.y + i][threadIdx.x] = Wl[(size_t)(k0 + threadIdx.y + i) * HID + m0 + threadIdx.x];
    __syncthreads();
#pragma unroll
    for (int i = 0; i < 32; i += 8)
        Wtl[(size_t)(m0 + threadIdx.y + i) * HID + k0 + threadIdx.x] =
            __float2bfloat16(t[threadIdx.x][threadIdx.y + i]);
}

// ---------------- atom_w transpose: Wt0[m][k] = bf16(atom_w[k][m]), k pad 128
__global__ void atomwt_kernel(const float* __restrict__ aw, __hip_bfloat16* __restrict__ Wt0) {
    int idx = blockIdx.x * 256 + threadIdx.x; // 512*128 total
    if (idx >= HID * 128) return;
    int k = idx >> 9, m = idx & (HID - 1);
    float v = (k < ATOM_DIM) ? aw[(size_t)k * HID + m] : 0.f;
    Wt0[(size_t)m * 128 + k] = __float2bfloat16(v);
}

// ---------------- atom projection MFMA: x[N,512] = bf16(atom) @ Wt0^T + b --
// K padded to 128 (cols >=100 are zero in both operands).
__launch_bounds__(256)
__global__ void gemm_atom_kernel(const float* __restrict__ A,
                                 const __hip_bfloat16* __restrict__ Bt,
                                 const float* __restrict__ bias,
                                 float* __restrict__ C, int N) {
    constexpr int KP = 128;
    constexpr int LDA = 40;
    __shared__ __align__(16) short As[128 * LDA];
    __shared__ __align__(16) short Bs[128 * LDA];
    const int tid = threadIdx.x;
    const int wave = tid >> 6, lane = tid & 63;
    const int row0 = blockIdx.x * 128, col0 = blockIdx.y * 128;
    const int wr = (wave >> 1) * 64, wc = (wave & 1) * 64;
    const int q = lane >> 4, r16 = lane & 15;
    f32x4 acc[4][4] = {};

    for (int k0 = 0; k0 < KP; k0 += 32) {
#pragma unroll
        for (int c = tid; c < 512; c += 256) {
            int rrow = c >> 2, koff = (c & 3) << 3;
            int grow = row0 + rrow;
            int kb = k0 + koff;
            float vv[8];
            if (grow < N && kb + 8 <= ATOM_DIM) {
                const float* ap = A + (size_t)grow * ATOM_DIM + kb;
                float4 v0 = *reinterpret_cast<const float4*>(ap);
                float4 v1 = *reinterpret_cast<const float4*>(ap + 4);
                vv[0] = v0.x; vv[1] = v0.y; vv[2] = v0.z; vv[3] = v0.w;
                vv[4] = v1.x; vv[5] = v1.y; vv[6] = v1.z; vv[7] = v1.w;
            } else {
#pragma unroll
                for (int t = 0; t < 8; ++t)
                    vv[t] = (grow < N && kb + t < ATOM_DIM) ? A[(size_t)grow * ATOM_DIM + kb + t] : 0.f;
            }
            ushort4 p0, p1;
            p0.x = f2bf(vv[0]); p0.y = f2bf(vv[1]); p0.z = f2bf(vv[2]); p0.w = f2bf(vv[3]);
            p1.x = f2bf(vv[4]); p1.y = f2bf(vv[5]); p1.z = f2bf(vv[6]); p1.w = f2bf(vv[7]);
            *reinterpret_cast<ushort4*>(&As[rrow * LDA + koff]) = p0;
            *reinterpret_cast<ushort4*>(&As[rrow * LDA + koff + 4]) = p1;
            float4 w = *reinterpret_cast<const float4*>(Bt + (size_t)(col0 + rrow) * KP + kb);
            *reinterpret_cast<float4*>(&Bs[rrow * LDA + koff]) = w;
        }
        __syncthreads();
        bf16x8 a[4], b[4];
#pragma unroll
        for (int i = 0; i < 4; ++i)
            a[i] = *reinterpret_cast<const bf16x8*>(&As[(wr + i * 16 + r16) * LDA + q * 8]);
#pragma unroll
        for (int j = 0; j < 4; ++j)
            b[j] = *reinterpret_cast<const bf16x8*>(&Bs[(wc + j * 16 + r16) * LDA + q * 8]);
#pragma unroll
        for (int i = 0; i < 4; ++i)
#pragma unroll
            for (int j = 0; j < 4; ++j)
                acc[i][j] = __builtin_amdgcn_mfma_f32_16x16x32_bf16(a[i], b[j], acc[i][j], 0, 0, 0);
        __syncthreads();
    }

#pragma unroll
    for (int i = 0; i < 4; ++i) {
#pragma unroll
        for (int rr = 0; rr < 4; ++rr) {
            int grow = row0 + wr + i * 16 + q * 4 + rr;
            if (grow >= N) continue;
#pragma unroll
            for (int j = 0; j < 4; ++j) {
                int col = col0 + wc + j * 16 + r16;
                C[(size_t)grow * HID + col] = acc[i][j][rr] + bias[col];
            }
        }
    }
}

// ---------------- bf16 MFMA GEMM with fused BN-on-stage + alpha epilogue ---
__launch_bounds__(256)
__global__ void gemm_mfma_kernel(const float* __restrict__ A,
                                 const __hip_bfloat16* __restrict__ Bt,
                                 float* __restrict__ C,
                                 const float* __restrict__ bn_sc,
                                 const float* __restrict__ bn_sh,
                                 const float* __restrict__ att_s,
                                 const float* __restrict__ att_d,
                                 float* __restrict__ as_out,
                                 float* __restrict__ ad_out,
                                 int N) {
    constexpr int K = HID;
    constexpr int LDA = 40; // shorts; 80B row stride
    __shared__ __align__(16) short As[128 * LDA];
    __shared__ __align__(16) short Bs[128 * LDA];
    __shared__ float scs[HID], shs[HID];
    const int tid = threadIdx.x;
    const int wave = tid >> 6, lane = tid & 63;
    const int row0 = blockIdx.x * 128, col0 = blockIdx.y * 128;
    const int wr = (wave >> 1) * 64, wc = (wave & 1) * 64;
    const int q = lane >> 4, r16 = lane & 15;
    const bool has_bn = (bn_sc != nullptr);
    if (has_bn) {
        for (int t = tid; t < HID; t += 256) { scs[t] = bn_sc[t]; shs[t] = bn_sh[t]; }
    }
    __syncthreads();
    f32x4 acc[4][4] = {};

    for (int k0 = 0; k0 < K; k0 += 32) {
#pragma unroll
        for (int c = tid; c < 512; c += 256) {
            int rrow = c >> 2, koff = (c & 3) << 3;
            int grow = row0 + rrow;
            float4 v0 = make_float4(0.f, 0.f, 0.f, 0.f), v1 = v0;
            if (grow < N) {
                const float* ap = A + (size_t)grow * K + k0 + koff;
                v0 = *reinterpret_cast<const float4*>(ap);
                v1 = *reinterpret_cast<const float4*>(ap + 4);
            }
            float vv[8] = {v0.x, v0.y, v0.z, v0.w, v1.x, v1.y, v1.z, v1.w};
            if (has_bn) {
                int cc = k0 + koff;
#pragma unroll
                for (int t = 0; t < 8; ++t) {
                    float val = fmaf(vv[t], scs[cc + t], shs[cc + t]);
                    vv[t] = val > 0.f ? val : 0.f;
                }
            }
            ushort4 p0, p1;
            p0.x = f2bf(vv[0]); p0.y = f2bf(vv[1]); p0.z = f2bf(vv[2]); p0.w = f2bf(vv[3]);
            p1.x = f2bf(vv[4]); p1.y = f2bf(vv[5]); p1.z = f2bf(vv[6]); p1.w = f2bf(vv[7]);
            *reinterpret_cast<ushort4*>(&As[rrow * LDA + koff]) = p0;
            *reinterpret_cast<ushort4*>(&As[rrow * LDA + koff + 4]) = p1;
            float4 w = *reinterpret_cast<const float4*>(Bt + (size_t)(col0 + rrow) * K + k0 + koff);
            *reinterpret_cast<float4*>(&Bs[rrow * LDA + koff]) = w;
        }
        __syncthreads();
        bf16x8 a[4], b[4];
#pragma unroll
        for (int i = 0; i < 4; ++i)
            a[i] = *reinterpret_cast<const bf16x8*>(&As[(wr + i * 16 + r16) * LDA + q * 8]);
#pragma unroll
        for (int j = 0; j < 4; ++j)
            b[j] = *reinterpret_cast<const bf16x8*>(&Bs[(wc + j * 16 + r16) * LDA + q * 8]);
#pragma unroll
        for (int i = 0; i < 4; ++i)
#pragma unroll
            for (int j = 0; j < 4; ++j)
                acc[i][j] = __builtin_amdgcn_mfma_f32_16x16x32_bf16(a[i], b[j], acc[i][j], 0, 0, 0);
        __syncthreads();
    }

    // C write. C/D layout: col = lane&15, row = (lane>>4)*4 + reg
#pragma unroll
    for (int i = 0; i < 4; ++i) {
#pragma unroll
        for (int rr = 0; rr < 4; ++rr) {
            int grow = row0 + wr + i * 16 + q * 4 + rr;
            if (grow >= N) continue;
#pragma unroll
            for (int j = 0; j < 4; ++j)
                C[(size_t)grow * HID + col0 + wc + j * 16 + r16] = acc[i][j][rr];
        }
    }

    // Fused alpha: wave's 64 cols == one head
    const int head = (col0 + wc) >> 6;
    float avs[4], avd[4];
#pragma unroll
    for (int j = 0; j < 4; ++j) {
        avs[j] = att_s[col0 + wc + j * 16 + r16];
        avd[j] = att_d[col0 + wc + j * 16 + r16];
    }
#pragma unroll
    for (int i = 0; i < 4; ++i) {
#pragma unroll
        for (int rr = 0; rr < 4; ++rr) {
            float ss = 0.f, dd = 0.f;
#pragma unroll
            for (int j = 0; j < 4; ++j) {
                float v = acc[i][j][rr];
                ss += v * avs[j];
                dd += v * avd[j];
            }
#pragma unroll
            for (int off = 8; off > 0; off >>= 1) {
                ss += __shfl_xor(ss, off);
                dd += __shfl_xor(dd, off);
            }
            int grow = row0 + wr + i * 16 + q * 4 + rr;
            if (r16 == 0 && grow < N) {
                as_out[(size_t)grow * HEADS + head] = ss;
                ad_out[(size_t)grow * HEADS + head] = dd;
            }
        }
    }
}

// ---------------- CSR build ------------------------------------------------
__global__ void count_kernel(const int* __restrict__ ei, int* __restrict__ counts) {
    int e = blockIdx.x * blockDim.x + threadIdx.x;
    int tot = N_EDGES + N_NODES;
    if (e >= tot) return;
    int dst = e < N_EDGES ? ei[N_EDGES + e] : e - N_EDGES;
    atomicAdd(&counts[dst], 1);
}

__global__ void scan1_kernel(const int* __restrict__ counts, int* __restrict__ offsets,
                             int* __restrict__ bsums, int n) {
    __shared__ int tmp[1024];
    int tid = threadIdx.x;
    int gid = blockIdx.x * 1024 + tid;
    tmp[tid] = gid < n ? counts[gid] : 0;
    __syncthreads();
    for (int off = 1; off < 1024; off <<= 1) {
        int t = tid >= off ? tmp[tid - off] : 0;
        __syncthreads();
        tmp[tid] += t;
        __syncthreads();
    }
    if (gid < n) offsets[gid + 1] = tmp[tid];
    if (tid == 1023) bsums[blockIdx.x] = tmp[1023];
}

__global__ void scan2_kernel(int* bsums, int nb) {
    if (threadIdx.x == 0) {
        int s = 0;
        for (int i = 0; i < nb; ++i) { s += bsums[i]; bsums[i] = s; }
    }
}

__global__ void scan3_kernel(const int* __restrict__ counts, int* __restrict__ offsets,
                             const int* __restrict__ bsums, int* __restrict__ wp, int n) {
    int tid = threadIdx.x;
    int gid = blockIdx.x * 1024 + tid;
    if (gid == 0) offsets[0] = 0;
    if (gid >= n) return;
    int add = blockIdx.x > 0 ? bsums[blockIdx.x - 1] : 0;
    int v = offsets[gid + 1] + add;
    offsets[gid + 1] = v;
    wp[gid] = v - counts[gid];
}

__global__ void scatter_kernel(const int* __restrict__ ei, int* __restrict__ wp,
                               int* __restrict__ csrc) {
    int e = blockIdx.x * blockDim.x + threadIdx.x;
    int tot = N_EDGES + N_NODES;
    if (e >= tot) return;
    int src = e < N_EDGES ? ei[e] : e - N_EDGES;
    int dst = e < N_EDGES ? ei[N_EDGES + e] : e - N_EDGES;
    int pos = atomicAdd(&wp[dst], 1);
    csrc[pos] = src;
}

// ---------------- softmax-attention aggregation + fused BN stats -----------
// One wave per dst node (8/block). Lane owns 8 contiguous channels.
// Epilogue: block-level LDS reduce of sum/sumsq -> 128-bin global atomics.
__launch_bounds__(512)
__global__ void agg_kernel(const float* __restrict__ h, const float* __restrict__ as,
                           const float* __restrict__ ad, const int* __restrict__ offsets,
                           const int* __restrict__ csrc, const float* __restrict__ bias,
                           float* __restrict__ out,
                           float* __restrict__ ps, float* __restrict__ pq) {
    __shared__ float psum[8][HID];
    const int wave = threadIdx.x >> 6, lane = threadIdx.x & 63;
    const int i = blockIdx.x * 8 + wave;
    const int head = lane >> 3;
    const int c0 = lane << 3;
    const int beg = offsets[i];
    const int deg = offsets[i + 1] - beg;
    const float adv = ad[(size_t)i * HEADS + head];

    float a0x = 0.f, a0y = 0.f, a0z = 0.f, a0w = 0.f;
    float a1x = 0.f, a1y = 0.f, a1z = 0.f, a1w = 0.f;
    float den = 0.f;

    for (int e0 = 0; e0 < deg; e0 += 4) {
        int m = deg - e0; if (m > 4) m = 4;
        int s[4];
#pragma unroll
        for (int k = 0; k < 4; ++k) {
            int kk = k < m ? k : m - 1;
            s[k] = csrc[beg + e0 + kk];
        }
        float w[4];
#pragma unroll
        for (int k = 0; k < 4; ++k)
            w[k] = (k < m) ? __expf(lrelu(as[(size_t)s[k] * HEADS + head] + adv)) : 0.f;
#pragma unroll
        for (int k = 0; k < 4; ++k) {
            const float4* hp = reinterpret_cast<const float4*>(h + (size_t)s[k] * HID + c0);
            float4 h0 = hp[0], h1 = hp[1];
            a0x += w[k] * h0.x; a0y += w[k] * h0.y; a0z += w[k] * h0.z; a0w += w[k] * h0.w;
            a1x += w[k] * h1.x; a1y += w[k] * h1.y; a1z += w[k] * h1.z; a1w += w[k] * h1.w;
            den += w[k];
        }
    }
    float inv = 1.f / den;
    const float4* bp = reinterpret_cast<const float4*>(bias + c0);
    float4 b0 = bp[0], b1 = bp[1];
    float4 o0 = make_float4(a0x * inv + b0.x, a0y * inv + b0.y, a0z * inv + b0.z, a0w * inv + b0.w);
    float4 o1 = make_float4(a1x * inv + b1.x, a1y * inv + b1.y, a1z * inv + b1.z, a1w * inv + b1.w);
    float4* op = reinterpret_cast<float4*>(out + (size_t)i * HID + c0);
    op[0] = o0; op[1] = o1;

    // fused BN stats
    *reinterpret_cast<float4*>(&psum[wave][c0]) = o0;
    *reinterpret_cast<float4*>(&psum[wave][c0 + 4]) = o1;
    __syncthreads();
    int c = threadIdx.x; // 512 == HID
    float s = 0.f, q = 0.f;
#pragma unroll
    for (int w = 0; w < 8; ++w) {
        float v = psum[w][c];
        s += v; q += v * v;
    }
    int bin = blockIdx.x & (NBINS - 1);
    atomicAdd(&ps[bin * HID + c], s);
    atomicAdd(&pq[bin * HID + c], q);
}

// ---------------- BN prep: fold bins -> per-channel scale/shift ------------
__global__ void bn_prep_kernel(const float* __restrict__ ps, const float* __restrict__ pq,
                               const float* __restrict__ gamma, const float* __restrict__ beta,
                               float* __restrict__ sc, float* __restrict__ sh, int n) {
    int c = threadIdx.x; // 512
    float s = 0.f, q = 0.f;
    for (int b = 0; b < NBINS; ++b) {
        s += ps[b * HID + c];
        q += pq[b * HID + c];
    }
    float inv_n = 1.f / (float)n;
    float mu = s * inv_n;
    float var = q * inv_n - mu * mu;
    float g = rsqrtf(var + 1e-5f) * gamma[c];
    sc[c] = g;
    sh[c] = beta[c] - mu * g;
}

// ---------------- pooling with fused final BN+ReLU -------------------------
__global__ void pool_bn_kernel(const float* __restrict__ x, const int* __restrict__ batch,
                               const float* __restrict__ sc, const float* __restrict__ sh,
                               float* __restrict__ pooled, int* __restrict__ gcnt) {
    int i = blockIdx.x;
    int g = batch[i];
    for (int c = threadIdx.x; c < HID; c += 256) {
        float v = fmaf(x[(size_t)i * HID + c], sc[c], sh[c]);
        v = v > 0.f ? v : 0.f;
        atomicAdd(&pooled[(size_t)g * HID + c], v);
    }
    if (threadIdx.x == 0) atomicAdd(&gcnt[g], 1);
}

__global__ void mlp1_kernel(const float* __restrict__ pooled, const int* __restrict__ gcnt,
                            const float* __restrict__ w1, const float* __restrict__ b1,
                            float* __restrict__ h1) {
    __shared__ float row[HID];
    int g = blockIdx.x;
    int tid = threadIdx.x; // 256
    row[tid] = pooled[(size_t)g * HID + tid];
    row[tid + 256] = pooled[(size_t)g * HID + tid + 256];
    __syncthreads();
    float inv = 1.f / fmaxf((float)gcnt[g], 1.f);
    float acc = 0.f;
    for (int c = 0; c < HID; ++c) acc += row[c] * w1[c * 256 + tid];
    float v = acc * inv + b1[tid];
    h1[g * 256 + tid] = v > 0.f ? v : 0.f;
}

__global__ void mlp2_kernel(const float* __restrict__ h1, const float* __restrict__ w2,
                            const float* __restrict__ b2, float* __restrict__ out) {
    __shared__ float row[256];
    int g = blockIdx.x;
    int tid = threadIdx.x; // 64
    for (int j = tid; j < 256; j += 64) row[j] = h1[g * 256 + j];
    __syncthreads();
    if (tid < TARGETS) {
        float acc = 0.f;
        for (int j = 0; j < 256; ++j) acc += row[j] * w2[j * TARGETS + tid];
        out[g * TARGETS + tid] = acc + b2[tid];
    }
}

// ---------------------------------------------------------------------------
extern "C" void kernel_launch(void* const* d_in, const int* in_sizes, int n_in,
                              void* d_out, int out_size, void* d_ws, size_t ws_size,
                              hipStream_t stream) {
    const float* atom   = (const float*)d_in[0];
    const int*   ei     = (const int*)d_in[2];   // [2, N_EDGES]
    const int*   batch  = (const int*)d_in[3];
    const float* atom_w = (const float*)d_in[4];
    const float* atom_b = (const float*)d_in[5];
    const float* gat_w  = (const float*)d_in[6];
    const float* att_s  = (const float*)d_in[7];
    const float* att_d  = (const float*)d_in[8];
    const float* gat_b  = (const float*)d_in[9];
    const float* bn_g   = (const float*)d_in[10];
    const float* bn_b   = (const float*)d_in[11];
    const float* w1     = (const float*)d_in[12];
    const float* b1     = (const float*)d_in[13];
    const float* w2     = (const float*)d_in[14];
    const float* b2     = (const float*)d_in[15];
    float* out = (float*)d_out;

    const int ETOT = N_EDGES + N_NODES;

    char* ws = (char*)d_ws;
    size_t off = 0;
    auto alloc = [&](size_t bytes) {
        void* p = ws + off;
        off += (bytes + 255) & ~(size_t)255;
        return p;
    };
    float* x      = (float*)alloc((size_t)N_NODES * HID * 4);   // 102.4 MB
    float* h      = (float*)alloc((size_t)N_NODES * HID * 4);   // 102.4 MB
    __hip_bfloat16* Wt  = (__hip_bfloat16*)alloc((size_t)LAYERS * HID * HID * 2); // 3.1 MB
    __hip_bfloat16* Wt0 = (__hip_bfloat16*)alloc((size_t)HID * 128 * 2);          // 131 KB
    float* as_    = (float*)alloc((size_t)N_NODES * HEADS * 4);
    float* ad_    = (float*)alloc((size_t)N_NODES * HEADS * 4);
    int* counts   = (int*)alloc(N_NODES * 4);
    int* offsets  = (int*)alloc((N_NODES + 1) * 4);
    int* wp       = (int*)alloc(N_NODES * 4);
    int* csrc     = (int*)alloc(ETOT * 4);
    int* bsums    = (int*)alloc(64 * 4);
    float* part_s = (float*)alloc((size_t)NBINS * HID * 4);     // 256 KB
    float* part_q = (float*)alloc((size_t)NBINS * HID * 4);     // 256 KB
    float* bn_sc  = (float*)alloc(HID * 4);
    float* bn_sh  = (float*)alloc(HID * 4);
    float* pooled = (float*)alloc((size_t)N_GRAPHS * HID * 4);
    int* gcnt     = (int*)alloc(N_GRAPHS * 4);
    float* h1     = (float*)alloc((size_t)N_GRAPHS * 256 * 4);

    // ---- CSR build (by dst; self-loops appended; stores src per slot) ----
    hipMemsetAsync(counts, 0, N_NODES * 4, stream);
    count_kernel<<<(ETOT + 255) / 256, 256, 0, stream>>>(ei, counts);
    int nb = (N_NODES + 1023) / 1024;
    scan1_kernel<<<nb, 1024, 0, stream>>>(counts, offsets, bsums, N_NODES);
    scan2_kernel<<<1, 64, 0, stream>>>(bsums, nb);
    scan3_kernel<<<nb, 1024, 0, stream>>>(counts, offsets, bsums, wp, N_NODES);
    scatter_kernel<<<(ETOT + 255) / 256, 256, 0, stream>>>(ei, wp, csrc);

    // ---- weights: transpose + bf16 convert ----
    wtrans_kernel<<<dim3(HID / 32, HID / 32, LAYERS), dim3(32, 8), 0, stream>>>(gat_w, Wt);
    atomwt_kernel<<<(HID * 128 + 255) / 256, 256, 0, stream>>>(atom_w, Wt0);

    // ---- atom projection -> x (fp32) via MFMA (K padded to 128) ----
    gemm_atom_kernel<<<dim3((N_NODES + 127) / 128, HID / 128), 256, 0, stream>>>(
        atom, Wt0, atom_b, x, N_NODES);

    // ---- 6 GAT layers ----
    for (int l = 0; l < LAYERS; ++l) {
        gemm_mfma_kernel<<<dim3((N_NODES + 127) / 128, HID / 128), 256, 0, stream>>>(
            x, Wt + (size_t)l * HID * HID, h,
            l == 0 ? nullptr : bn_sc, l == 0 ? nullptr : bn_sh,
            att_s + l * HID, att_d + l * HID, as_, ad_, N_NODES);
        hipMemsetAsync(part_s, 0, (size_t)NBINS * HID * 4, stream);
        hipMemsetAsync(part_q, 0, (size_t)NBINS * HID * 4, stream);
        agg_kernel<<<N_NODES / 8, 512, 0, stream>>>(h, as_, ad_, offsets, csrc,
                                                    gat_b + l * HID, x, part_s, part_q);
        bn_prep_kernel<<<1, HID, 0, stream>>>(part_s, part_q, bn_g + l * HID, bn_b + l * HID,
                                              bn_sc, bn_sh, N_NODES);
    }

    // ---- global mean pool (with fused final BN+ReLU) + MLP head ----
    hipMemsetAsync(pooled, 0, (size_t)N_GRAPHS * HID * 4, stream);
    hipMemsetAsync(gcnt, 0, N_GRAPHS * 4, stream);
    pool_bn_kernel<<<N_NODES, 256, 0, stream>>>(x, batch, bn_sc, bn_sh, pooled, gcnt);
    mlp1_kernel<<<N_GRAPHS, 256, 0, stream>>>(pooled, gcnt, w1, b1, h1);
    mlp2_kernel<<<N_GRAPHS, 64, 0, stream>>>(h1, w2, b2, out);
}

// Round 7
// 1390.582 us; speedup vs baseline: 3.4657x; 1.1825x over previous
//
#include <hip/hip_runtime.h>
#include <hip/hip_bf16.h>

// ---------------------------------------------------------------------------
// MolecularGNN: atom proj -> 6x (GATConv + BN + ReLU) -> mean pool -> MLP
// Round 7: intermediate buffers x,h -> bf16 (R6 showed gemm_mfma and agg are
// pure HBM-traffic-bound: 324 MB/dispatch at 2.4 TB/s). BN still fp32 math:
// stats from fp32 registers in agg epilogue; scale/shift applied in fp32
// during GEMM staging after the bf16 load. Workspace ~117 MB.
// ---------------------------------------------------------------------------

#define N_NODES 50000
#define N_EDGES 150000
#define N_GRAPHS 2000
#define ATOM_DIM 100
#define HID 512
#define HEADS 8
#define HEAD_DIM 64
#define LAYERS 6
#define TARGETS 13
#define NBINS 128

typedef __attribute__((ext_vector_type(8))) short bf16x8;
typedef __attribute__((ext_vector_type(4))) float f32x4;

__device__ __forceinline__ float lrelu(float v) { return v > 0.f ? v : 0.2f * v; }

__device__ __forceinline__ unsigned short f2bf(float v) {
    __hip_bfloat16 b = __float2bfloat16(v);
    return *reinterpret_cast<unsigned short*>(&b);
}
__device__ __forceinline__ float bf2f(unsigned short u) {
    unsigned int x = ((unsigned int)u) << 16;
    return __uint_as_float(x);
}

// ---------------- weight transpose + bf16 convert (layer weights) ----------
__global__ void wtrans_kernel(const float* __restrict__ W, __hip_bfloat16* __restrict__ Wt) {
    __shared__ float t[32][33];
    int l = blockIdx.z;
    int k0 = blockIdx.x * 32, m0 = blockIdx.y * 32;
    const float* Wl = W + (size_t)l * HID * HID;
    __hip_bfloat16* Wtl = Wt + (size_t)l * HID * HID;
#pragma unroll
    for (int i = 0; i < 32; i += 8)
        t[threadIdx.y + i][threadIdx.x] = Wl[(size_t)(k0 + threadIdx.y + i) * HID + m0 + threadIdx.x];
    __syncthreads();
#pragma unroll
    for (int i = 0; i < 32; i += 8)
        Wtl[(size_t)(m0 + threadIdx.y + i) * HID + k0 + threadIdx.x] =
            __float2bfloat16(t[threadIdx.x][threadIdx.y + i]);
}

// ---------------- atom_w transpose: Wt0[m][k] = bf16(atom_w[k][m]), k pad 128
__global__ void atomwt_kernel(const float* __restrict__ aw, __hip_bfloat16* __restrict__ Wt0) {
    int idx = blockIdx.x * 256 + threadIdx.x; // 512*128 total
    if (idx >= HID * 128) return;
    int k = idx >> 9, m = idx & (HID - 1);
    float v = (k < ATOM_DIM) ? aw[(size_t)k * HID + m] : 0.f;
    Wt0[(size_t)m * 128 + k] = __float2bfloat16(v);
}

// ---------------- atom projection MFMA: xb[N,512] = bf16(atom) @ Wt0^T + b -
__launch_bounds__(256)
__global__ void gemm_atom_kernel(const float* __restrict__ A,
                                 const __hip_bfloat16* __restrict__ Bt,
                                 const float* __restrict__ bias,
                                 __hip_bfloat16* __restrict__ Cb, int N) {
    constexpr int KP = 128;
    constexpr int LDA = 40;
    __shared__ __align__(16) short As[128 * LDA];
    __shared__ __align__(16) short Bs[128 * LDA];
    const int tid = threadIdx.x;
    const int wave = tid >> 6, lane = tid & 63;
    const int row0 = blockIdx.x * 128, col0 = blockIdx.y * 128;
    const int wr = (wave >> 1) * 64, wc = (wave & 1) * 64;
    const int q = lane >> 4, r16 = lane & 15;
    f32x4 acc[4][4] = {};

    for (int k0 = 0; k0 < KP; k0 += 32) {
#pragma unroll
        for (int c = tid; c < 512; c += 256) {
            int rrow = c >> 2, koff = (c & 3) << 3;
            int grow = row0 + rrow;
            int kb = k0 + koff;
            float vv[8];
            if (grow < N && kb + 8 <= ATOM_DIM) {
                const float* ap = A + (size_t)grow * ATOM_DIM + kb;
                float4 v0 = *reinterpret_cast<const float4*>(ap);
                float4 v1 = *reinterpret_cast<const float4*>(ap + 4);
                vv[0] = v0.x; vv[1] = v0.y; vv[2] = v0.z; vv[3] = v0.w;
                vv[4] = v1.x; vv[5] = v1.y; vv[6] = v1.z; vv[7] = v1.w;
            } else {
#pragma unroll
                for (int t = 0; t < 8; ++t)
                    vv[t] = (grow < N && kb + t < ATOM_DIM) ? A[(size_t)grow * ATOM_DIM + kb + t] : 0.f;
            }
            ushort4 p0, p1;
            p0.x = f2bf(vv[0]); p0.y = f2bf(vv[1]); p0.z = f2bf(vv[2]); p0.w = f2bf(vv[3]);
            p1.x = f2bf(vv[4]); p1.y = f2bf(vv[5]); p1.z = f2bf(vv[6]); p1.w = f2bf(vv[7]);
            *reinterpret_cast<ushort4*>(&As[rrow * LDA + koff]) = p0;
            *reinterpret_cast<ushort4*>(&As[rrow * LDA + koff + 4]) = p1;
            float4 w = *reinterpret_cast<const float4*>(Bt + (size_t)(col0 + rrow) * KP + kb);
            *reinterpret_cast<float4*>(&Bs[rrow * LDA + koff]) = w;
        }
        __syncthreads();
        bf16x8 a[4], b[4];
#pragma unroll
        for (int i = 0; i < 4; ++i)
            a[i] = *reinterpret_cast<const bf16x8*>(&As[(wr + i * 16 + r16) * LDA + q * 8]);
#pragma unroll
        for (int j = 0; j < 4; ++j)
            b[j] = *reinterpret_cast<const bf16x8*>(&Bs[(wc + j * 16 + r16) * LDA + q * 8]);
#pragma unroll
        for (int i = 0; i < 4; ++i)
#pragma unroll
            for (int j = 0; j < 4; ++j)
                acc[i][j] = __builtin_amdgcn_mfma_f32_16x16x32_bf16(a[i], b[j], acc[i][j], 0, 0, 0);
        __syncthreads();
    }

#pragma unroll
    for (int i = 0; i < 4; ++i) {
#pragma unroll
        for (int rr = 0; rr < 4; ++rr) {
            int grow = row0 + wr + i * 16 + q * 4 + rr;
            if (grow >= N) continue;
#pragma unroll
            for (int j = 0; j < 4; ++j) {
                int col = col0 + wc + j * 16 + r16;
                Cb[(size_t)grow * HID + col] =
                    __float2bfloat16(acc[i][j][rr] + bias[col]);
            }
        }
    }
}

// ---------------- bf16 MFMA GEMM with fused BN-on-stage + alpha epilogue ---
// Cb[N,512] = bf16(relu(bf2f(A)*sc+sh)) @ Bt^T ; also writes as/ad.
// A bf16; bn_sc==nullptr -> stage raw copy (layer 0).
__launch_bounds__(256)
__global__ void gemm_mfma_kernel(const __hip_bfloat16* __restrict__ A,
                                 const __hip_bfloat16* __restrict__ Bt,
                                 __hip_bfloat16* __restrict__ Cb,
                                 const float* __restrict__ bn_sc,
                                 const float* __restrict__ bn_sh,
                                 const float* __restrict__ att_s,
                                 const float* __restrict__ att_d,
                                 float* __restrict__ as_out,
                                 float* __restrict__ ad_out,
                                 int N) {
    constexpr int K = HID;
    constexpr int LDA = 40; // shorts; 80B row stride
    __shared__ __align__(16) short As[128 * LDA];
    __shared__ __align__(16) short Bs[128 * LDA];
    __shared__ float scs[HID], shs[HID];
    const int tid = threadIdx.x;
    const int wave = tid >> 6, lane = tid & 63;
    const int row0 = blockIdx.x * 128, col0 = blockIdx.y * 128;
    const int wr = (wave >> 1) * 64, wc = (wave & 1) * 64;
    const int q = lane >> 4, r16 = lane & 15;
    const bool has_bn = (bn_sc != nullptr);
    if (has_bn) {
        for (int t = tid; t < HID; t += 256) { scs[t] = bn_sc[t]; shs[t] = bn_sh[t]; }
    }
    __syncthreads();
    f32x4 acc[4][4] = {};

    for (int k0 = 0; k0 < K; k0 += 32) {
#pragma unroll
        for (int c = tid; c < 512; c += 256) {
            int rrow = c >> 2, koff = (c & 3) << 3;
            int grow = row0 + rrow;
            ushort4 r0 = make_ushort4(0, 0, 0, 0), r1 = r0;
            if (grow < N) {
                const ushort4* ap = reinterpret_cast<const ushort4*>(A + (size_t)grow * K + k0 + koff);
                r0 = ap[0]; r1 = ap[1];
            }
            if (has_bn) {
                int cc = k0 + koff;
                unsigned short u[8] = {r0.x, r0.y, r0.z, r0.w, r1.x, r1.y, r1.z, r1.w};
#pragma unroll
                for (int t = 0; t < 8; ++t) {
                    float val = fmaf(bf2f(u[t]), scs[cc + t], shs[cc + t]);
                    u[t] = f2bf(val > 0.f ? val : 0.f);
                }
                r0 = make_ushort4(u[0], u[1], u[2], u[3]);
                r1 = make_ushort4(u[4], u[5], u[6], u[7]);
            }
            *reinterpret_cast<ushort4*>(&As[rrow * LDA + koff]) = r0;
            *reinterpret_cast<ushort4*>(&As[rrow * LDA + koff + 4]) = r1;
            float4 w = *reinterpret_cast<const float4*>(Bt + (size_t)(col0 + rrow) * K + k0 + koff);
            *reinterpret_cast<float4*>(&Bs[rrow * LDA + koff]) = w;
        }
        __syncthreads();
        bf16x8 a[4], b[4];
#pragma unroll
        for (int i = 0; i < 4; ++i)
            a[i] = *reinterpret_cast<const bf16x8*>(&As[(wr + i * 16 + r16) * LDA + q * 8]);
#pragma unroll
        for (int j = 0; j < 4; ++j)
            b[j] = *reinterpret_cast<const bf16x8*>(&Bs[(wc + j * 16 + r16) * LDA + q * 8]);
#pragma unroll
        for (int i = 0; i < 4; ++i)
#pragma unroll
            for (int j = 0; j < 4; ++j)
                acc[i][j] = __builtin_amdgcn_mfma_f32_16x16x32_bf16(a[i], b[j], acc[i][j], 0, 0, 0);
        __syncthreads();
    }

    // C write (bf16). C/D layout: col = lane&15, row = (lane>>4)*4 + reg
#pragma unroll
    for (int i = 0; i < 4; ++i) {
#pragma unroll
        for (int rr = 0; rr < 4; ++rr) {
            int grow = row0 + wr + i * 16 + q * 4 + rr;
            if (grow >= N) continue;
#pragma unroll
            for (int j = 0; j < 4; ++j)
                Cb[(size_t)grow * HID + col0 + wc + j * 16 + r16] =
                    __float2bfloat16(acc[i][j][rr]);
        }
    }

    // Fused alpha: wave's 64 cols == one head (fp32 from accumulators)
    const int head = (col0 + wc) >> 6;
    float avs[4], avd[4];
#pragma unroll
    for (int j = 0; j < 4; ++j) {
        avs[j] = att_s[col0 + wc + j * 16 + r16];
        avd[j] = att_d[col0 + wc + j * 16 + r16];
    }
#pragma unroll
    for (int i = 0; i < 4; ++i) {
#pragma unroll
        for (int rr = 0; rr < 4; ++rr) {
            float ss = 0.f, dd = 0.f;
#pragma unroll
            for (int j = 0; j < 4; ++j) {
                float v = acc[i][j][rr];
                ss += v * avs[j];
                dd += v * avd[j];
            }
#pragma unroll
            for (int off = 8; off > 0; off >>= 1) {
                ss += __shfl_xor(ss, off);
                dd += __shfl_xor(dd, off);
            }
            int grow = row0 + wr + i * 16 + q * 4 + rr;
            if (r16 == 0 && grow < N) {
                as_out[(size_t)grow * HEADS + head] = ss;
                ad_out[(size_t)grow * HEADS + head] = dd;
            }
        }
    }
}

// ---------------- CSR build ------------------------------------------------
__global__ void count_kernel(const int* __restrict__ ei, int* __restrict__ counts) {
    int e = blockIdx.x * blockDim.x + threadIdx.x;
    int tot = N_EDGES + N_NODES;
    if (e >= tot) return;
    int dst = e < N_EDGES ? ei[N_EDGES + e] : e - N_EDGES;
    atomicAdd(&counts[dst], 1);
}

__global__ void scan1_kernel(const int* __restrict__ counts, int* __restrict__ offsets,
                             int* __restrict__ bsums, int n) {
    __shared__ int tmp[1024];
    int tid = threadIdx.x;
    int gid = blockIdx.x * 1024 + tid;
    tmp[tid] = gid < n ? counts[gid] : 0;
    __syncthreads();
    for (int off = 1; off < 1024; off <<= 1) {
        int t = tid >= off ? tmp[tid - off] : 0;
        __syncthreads();
        tmp[tid] += t;
        __syncthreads();
    }
    if (gid < n) offsets[gid + 1] = tmp[tid];
    if (tid == 1023) bsums[blockIdx.x] = tmp[1023];
}

__global__ void scan2_kernel(int* bsums, int nb) {
    if (threadIdx.x == 0) {
        int s = 0;
        for (int i = 0; i < nb; ++i) { s += bsums[i]; bsums[i] = s; }
    }
}

__global__ void scan3_kernel(const int* __restrict__ counts, int* __restrict__ offsets,
                             const int* __restrict__ bsums, int* __restrict__ wp, int n) {
    int tid = threadIdx.x;
    int gid = blockIdx.x * 1024 + tid;
    if (gid == 0) offsets[0] = 0;
    if (gid >= n) return;
    int add = blockIdx.x > 0 ? bsums[blockIdx.x - 1] : 0;
    int v = offsets[gid + 1] + add;
    offsets[gid + 1] = v;
    wp[gid] = v - counts[gid];
}

__global__ void scatter_kernel(const int* __restrict__ ei, int* __restrict__ wp,
                               int* __restrict__ csrc) {
    int e = blockIdx.x * blockDim.x + threadIdx.x;
    int tot = N_EDGES + N_NODES;
    if (e >= tot) return;
    int src = e < N_EDGES ? ei[e] : e - N_EDGES;
    int dst = e < N_EDGES ? ei[N_EDGES + e] : e - N_EDGES;
    int pos = atomicAdd(&wp[dst], 1);
    csrc[pos] = src;
}

// ---------------- softmax-attention aggregation + fused BN stats -----------
// One wave per dst node (8/block). Lane owns 8 contiguous channels (16B bf16
// load per edge). BN stats from fp32 registers; output stored bf16.
__launch_bounds__(512)
__global__ void agg_kernel(const __hip_bfloat16* __restrict__ hb, const float* __restrict__ as,
                           const float* __restrict__ ad, const int* __restrict__ offsets,
                           const int* __restrict__ csrc, const float* __restrict__ bias,
                           __hip_bfloat16* __restrict__ outb,
                           float* __restrict__ ps, float* __restrict__ pq) {
    __shared__ float psum[8][HID];
    const int wave = threadIdx.x >> 6, lane = threadIdx.x & 63;
    const int i = blockIdx.x * 8 + wave;
    const int head = lane >> 3;
    const int c0 = lane << 3;
    const int beg = offsets[i];
    const int deg = offsets[i + 1] - beg;
    const float adv = ad[(size_t)i * HEADS + head];

    float a[8] = {};
    float den = 0.f;

    for (int e0 = 0; e0 < deg; e0 += 4) {
        int m = deg - e0; if (m > 4) m = 4;
        int s[4];
#pragma unroll
        for (int k = 0; k < 4; ++k) {
            int kk = k < m ? k : m - 1;
            s[k] = csrc[beg + e0 + kk];
        }
        float w[4];
#pragma unroll
        for (int k = 0; k < 4; ++k)
            w[k] = (k < m) ? __expf(lrelu(as[(size_t)s[k] * HEADS + head] + adv)) : 0.f;
#pragma unroll
        for (int k = 0; k < 4; ++k) {
            bf16x8 hv = *reinterpret_cast<const bf16x8*>(hb + (size_t)s[k] * HID + c0);
#pragma unroll
            for (int t = 0; t < 8; ++t)
                a[t] += w[k] * bf2f((unsigned short)hv[t]);
            den += w[k];
        }
    }
    float inv = 1.f / den;
    float o[8];
    const float4* bp = reinterpret_cast<const float4*>(bias + c0);
    float4 b0 = bp[0], b1 = bp[1];
    float bb[8] = {b0.x, b0.y, b0.z, b0.w, b1.x, b1.y, b1.z, b1.w};
    ushort4 p0, p1;
#pragma unroll
    for (int t = 0; t < 8; ++t) o[t] = a[t] * inv + bb[t];
    p0.x = f2bf(o[0]); p0.y = f2bf(o[1]); p0.z = f2bf(o[2]); p0.w = f2bf(o[3]);
    p1.x = f2bf(o[4]); p1.y = f2bf(o[5]); p1.z = f2bf(o[6]); p1.w = f2bf(o[7]);
    ushort4* op = reinterpret_cast<ushort4*>(outb + (size_t)i * HID + c0);
    op[0] = p0; op[1] = p1;

    // fused BN stats (from fp32 values)
#pragma unroll
    for (int t = 0; t < 4; ++t) psum[wave][c0 + t] = o[t];
#pragma unroll
    for (int t = 4; t < 8; ++t) psum[wave][c0 + t] = o[t];
    __syncthreads();
    int c = threadIdx.x; // 512 == HID
    float s = 0.f, q = 0.f;
#pragma unroll
    for (int w = 0; w < 8; ++w) {
        float v = psum[w][c];
        s += v; q += v * v;
    }
    int bin = blockIdx.x & (NBINS - 1);
    atomicAdd(&ps[bin * HID + c], s);
    atomicAdd(&pq[bin * HID + c], q);
}

// ---------------- BN prep: fold bins -> per-channel scale/shift ------------
__global__ void bn_prep_kernel(const float* __restrict__ ps, const float* __restrict__ pq,
                               const float* __restrict__ gamma, const float* __restrict__ beta,
                               float* __restrict__ sc, float* __restrict__ sh, int n) {
    int c = threadIdx.x; // 512
    float s = 0.f, q = 0.f;
    for (int b = 0; b < NBINS; ++b) {
        s += ps[b * HID + c];
        q += pq[b * HID + c];
    }
    float inv_n = 1.f / (float)n;
    float mu = s * inv_n;
    float var = q * inv_n - mu * mu;
    float g = rsqrtf(var + 1e-5f) * gamma[c];
    sc[c] = g;
    sh[c] = beta[c] - mu * g;
}

// ---------------- pooling with fused final BN+ReLU -------------------------
__global__ void pool_bn_kernel(const __hip_bfloat16* __restrict__ xb, const int* __restrict__ batch,
                               const float* __restrict__ sc, const float* __restrict__ sh,
                               float* __restrict__ pooled, int* __restrict__ gcnt) {
    int i = blockIdx.x;
    int g = batch[i];
    for (int c = threadIdx.x; c < HID; c += 256) {
        float xv = __bfloat162float(xb[(size_t)i * HID + c]);
        float v = fmaf(xv, sc[c], sh[c]);
        v = v > 0.f ? v : 0.f;
        atomicAdd(&pooled[(size_t)g * HID + c], v);
    }
    if (threadIdx.x == 0) atomicAdd(&gcnt[g], 1);
}

__global__ void mlp1_kernel(const float* __restrict__ pooled, const int* __restrict__ gcnt,
                            const float* __restrict__ w1, const float* __restrict__ b1,
                            float* __restrict__ h1) {
    __shared__ float row[HID];
    int g = blockIdx.x;
    int tid = threadIdx.x; // 256
    row[tid] = pooled[(size_t)g * HID + tid];
    row[tid + 256] = pooled[(size_t)g * HID + tid + 256];
    __syncthreads();
    float inv = 1.f / fmaxf((float)gcnt[g], 1.f);
    float acc = 0.f;
    for (int c = 0; c < HID; ++c) acc += row[c] * w1[c * 256 + tid];
    float v = acc * inv + b1[tid];
    h1[g * 256 + tid] = v > 0.f ? v : 0.f;
}

__global__ void mlp2_kernel(const float* __restrict__ h1, const float* __restrict__ w2,
                            const float* __restrict__ b2, float* __restrict__ out) {
    __shared__ float row[256];
    int g = blockIdx.x;
    int tid = threadIdx.x; // 64
    for (int j = tid; j < 256; j += 64) row[j] = h1[g * 256 + j];
    __syncthreads();
    if (tid < TARGETS) {
        float acc = 0.f;
        for (int j = 0; j < 256; ++j) acc += row[j] * w2[j * TARGETS + tid];
        out[g * TARGETS + tid] = acc + b2[tid];
    }
}

// ---------------------------------------------------------------------------
extern "C" void kernel_launch(void* const* d_in, const int* in_sizes, int n_in,
                              void* d_out, int out_size, void* d_ws, size_t ws_size,
                              hipStream_t stream) {
    const float* atom   = (const float*)d_in[0];
    const int*   ei     = (const int*)d_in[2];   // [2, N_EDGES]
    const int*   batch  = (const int*)d_in[3];
    const float* atom_w = (const float*)d_in[4];
    const float* atom_b = (const float*)d_in[5];
    const float* gat_w  = (const float*)d_in[6];
    const float* att_s  = (const float*)d_in[7];
    const float* att_d  = (const float*)d_in[8];
    const float* gat_b  = (const float*)d_in[9];
    const float* bn_g   = (const float*)d_in[10];
    const float* bn_b   = (const float*)d_in[11];
    const float* w1     = (const float*)d_in[12];
    const float* b1     = (const float*)d_in[13];
    const float* w2     = (const float*)d_in[14];
    const float* b2     = (const float*)d_in[15];
    float* out = (float*)d_out;

    const int ETOT = N_EDGES + N_NODES;

    char* ws = (char*)d_ws;
    size_t off = 0;
    auto alloc = [&](size_t bytes) {
        void* p = ws + off;
        off += (bytes + 255) & ~(size_t)255;
        return p;
    };
    __hip_bfloat16* xb  = (__hip_bfloat16*)alloc((size_t)N_NODES * HID * 2); // 51.2 MB
    __hip_bfloat16* hb  = (__hip_bfloat16*)alloc((size_t)N_NODES * HID * 2); // 51.2 MB
    __hip_bfloat16* Wt  = (__hip_bfloat16*)alloc((size_t)LAYERS * HID * HID * 2); // 3.1 MB
    __hip_bfloat16* Wt0 = (__hip_bfloat16*)alloc((size_t)HID * 128 * 2);          // 131 KB
    float* as_    = (float*)alloc((size_t)N_NODES * HEADS * 4);
    float* ad_    = (float*)alloc((size_t)N_NODES * HEADS * 4);
    int* counts   = (int*)alloc(N_NODES * 4);
    int* offsets  = (int*)alloc((N_NODES + 1) * 4);
    int* wp       = (int*)alloc(N_NODES * 4);
    int* csrc     = (int*)alloc(ETOT * 4);
    int* bsums    = (int*)alloc(64 * 4);
    float* part_s = (float*)alloc((size_t)NBINS * HID * 4);     // 256 KB
    float* part_q = (float*)alloc((size_t)NBINS * HID * 4);     // 256 KB
    float* bn_sc  = (float*)alloc(HID * 4);
    float* bn_sh  = (float*)alloc(HID * 4);
    float* pooled = (float*)alloc((size_t)N_GRAPHS * HID * 4);
    int* gcnt     = (int*)alloc(N_GRAPHS * 4);
    float* h1     = (float*)alloc((size_t)N_GRAPHS * 256 * 4);

    // ---- CSR build (by dst; self-loops appended; stores src per slot) ----
    hipMemsetAsync(counts, 0, N_NODES * 4, stream);
    count_kernel<<<(ETOT + 255) / 256, 256, 0, stream>>>(ei, counts);
    int nb = (N_NODES + 1023) / 1024;
    scan1_kernel<<<nb, 1024, 0, stream>>>(counts, offsets, bsums, N_NODES);
    scan2_kernel<<<1, 64, 0, stream>>>(bsums, nb);
    scan3_kernel<<<nb, 1024, 0, stream>>>(counts, offsets, bsums, wp, N_NODES);
    scatter_kernel<<<(ETOT + 255) / 256, 256, 0, stream>>>(ei, wp, csrc);

    // ---- weights: transpose + bf16 convert ----
    wtrans_kernel<<<dim3(HID / 32, HID / 32, LAYERS), dim3(32, 8), 0, stream>>>(gat_w, Wt);
    atomwt_kernel<<<(HID * 128 + 255) / 256, 256, 0, stream>>>(atom_w, Wt0);

    // ---- atom projection -> xb (bf16) via MFMA (K padded to 128) ----
    gemm_atom_kernel<<<dim3((N_NODES + 127) / 128, HID / 128), 256, 0, stream>>>(
        atom, Wt0, atom_b, xb, N_NODES);

    // ---- 6 GAT layers ----
    for (int l = 0; l < LAYERS; ++l) {
        gemm_mfma_kernel<<<dim3((N_NODES + 127) / 128, HID / 128), 256, 0, stream>>>(
            xb, Wt + (size_t)l * HID * HID, hb,
            l == 0 ? nullptr : bn_sc, l == 0 ? nullptr : bn_sh,
            att_s + l * HID, att_d + l * HID, as_, ad_, N_NODES);
        hipMemsetAsync(part_s, 0, (size_t)NBINS * HID * 4, stream);
        hipMemsetAsync(part_q, 0, (size_t)NBINS * HID * 4, stream);
        agg_kernel<<<N_NODES / 8, 512, 0, stream>>>(hb, as_, ad_, offsets, csrc,
                                                    gat_b + l * HID, xb, part_s, part_q);
        bn_prep_kernel<<<1, HID, 0, stream>>>(part_s, part_q, bn_g + l * HID, bn_b + l * HID,
                                              bn_sc, bn_sh, N_NODES);
    }

    // ---- global mean pool (with fused final BN+ReLU) + MLP head ----
    hipMemsetAsync(pooled, 0, (size_t)N_GRAPHS * HID * 4, stream);
    hipMemsetAsync(gcnt, 0, N_GRAPHS * 4, stream);
    pool_bn_kernel<<<N_NODES, 256, 0, stream>>>(xb, batch, bn_sc, bn_sh, pooled, gcnt);
    mlp1_kernel<<<N_GRAPHS, 256, 0, stream>>>(pooled, gcnt, w1, b1, h1);
    mlp2_kernel<<<N_GRAPHS, 64, 0, stream>>>(h1, w2, b2, out);
}

// Round 8
// 1179.856 us; speedup vs baseline: 4.0847x; 1.1786x over previous
//
#include <hip/hip_runtime.h>
#include <hip/hip_bf16.h>

// ---------------------------------------------------------------------------
// MolecularGNN: atom proj -> 6x (GATConv + BN + ReLU) -> mean pool -> MLP
// Round 8: R7 showed gemm_mfma is latency-bound (all pipes idle), not HBM-
// bound. Rewrite as m97-structure: pure bf16 GEMM, global_load_lds(16B) for
// A and B, BK=64 (32 MFMA/wave per barrier), XOR-swizzled lane-linear LDS.
// BN moves out of GEMM staging into a standalone bf16 bn_apply pass (5x;
// layer-5 BN stays fused in pool). bn_prep parallelized (wave/channel).
// ---------------------------------------------------------------------------

#define N_NODES 50000
#define N_EDGES 150000
#define N_GRAPHS 2000
#define ATOM_DIM 100
#define HID 512
#define HEADS 8
#define HEAD_DIM 64
#define LAYERS 6
#define TARGETS 13
#define NBINS 128
#define BK 64

typedef __attribute__((ext_vector_type(8))) short bf16x8;
typedef __attribute__((ext_vector_type(4))) float f32x4;

__device__ __forceinline__ float lrelu(float v) { return v > 0.f ? v : 0.2f * v; }

__device__ __forceinline__ unsigned short f2bf(float v) {
    __hip_bfloat16 b = __float2bfloat16(v);
    return *reinterpret_cast<unsigned short*>(&b);
}
__device__ __forceinline__ float bf2f(unsigned short u) {
    unsigned int x = ((unsigned int)u) << 16;
    return __uint_as_float(x);
}

typedef __attribute__((address_space(3))) unsigned int lds_uint;
typedef __attribute__((address_space(1))) const unsigned int glob_uint;

// async global->LDS, 16B per lane; lds dest = wave-uniform base + lane*16
__device__ __forceinline__ void gload_lds16(const void* g, void* l) {
    __builtin_amdgcn_global_load_lds((glob_uint*)g, (lds_uint*)l, 16, 0, 0);
}

// ---------------- weight transpose + bf16 convert (layer weights) ----------
__global__ void wtrans_kernel(const float* __restrict__ W, __hip_bfloat16* __restrict__ Wt) {
    __shared__ float t[32][33];
    int l = blockIdx.z;
    int k0 = blockIdx.x * 32, m0 = blockIdx.y * 32;
    const float* Wl = W + (size_t)l * HID * HID;
    __hip_bfloat16* Wtl = Wt + (size_t)l * HID * HID;
#pragma unroll
    for (int i = 0; i < 32; i += 8)
        t[threadIdx.y + i][threadIdx.x] = Wl[(size_t)(k0 + threadIdx.y + i) * HID + m0 + threadIdx.x];
    __syncthreads();
#pragma unroll
    for (int i = 0; i < 32; i += 8)
        Wtl[(size_t)(m0 + threadIdx.y + i) * HID + k0 + threadIdx.x] =
            __float2bfloat16(t[threadIdx.x][threadIdx.y + i]);
}

// ---------------- atom_w transpose: Wt0[m][k] = bf16(atom_w[k][m]), k pad 128
__global__ void atomwt_kernel(const float* __restrict__ aw, __hip_bfloat16* __restrict__ Wt0) {
    int idx = blockIdx.x * 256 + threadIdx.x; // 512*128 total
    if (idx >= HID * 128) return;
    int k = idx >> 9, m = idx & (HID - 1);
    float v = (k < ATOM_DIM) ? aw[(size_t)k * HID + m] : 0.f;
    Wt0[(size_t)m * 128 + k] = __float2bfloat16(v);
}

// ---------------- atom projection MFMA: xn[N,512] = bf16(atom) @ Wt0^T + b -
__launch_bounds__(256)
__global__ void gemm_atom_kernel(const float* __restrict__ A,
                                 const __hip_bfloat16* __restrict__ Bt,
                                 const float* __restrict__ bias,
                                 __hip_bfloat16* __restrict__ Cb, int N) {
    constexpr int KP = 128;
    constexpr int LDA = 40;
    __shared__ __align__(16) short As[128 * LDA];
    __shared__ __align__(16) short Bs[128 * LDA];
    const int tid = threadIdx.x;
    const int wave = tid >> 6, lane = tid & 63;
    const int row0 = blockIdx.x * 128, col0 = blockIdx.y * 128;
    const int wr = (wave >> 1) * 64, wc = (wave & 1) * 64;
    const int q = lane >> 4, r16 = lane & 15;
    f32x4 acc[4][4] = {};

    for (int k0 = 0; k0 < KP; k0 += 32) {
#pragma unroll
        for (int c = tid; c < 512; c += 256) {
            int rrow = c >> 2, koff = (c & 3) << 3;
            int grow = row0 + rrow;
            int kb = k0 + koff;
            float vv[8];
            if (grow < N && kb + 8 <= ATOM_DIM) {
                const float* ap = A + (size_t)grow * ATOM_DIM + kb;
                float4 v0 = *reinterpret_cast<const float4*>(ap);
                float4 v1 = *reinterpret_cast<const float4*>(ap + 4);
                vv[0] = v0.x; vv[1] = v0.y; vv[2] = v0.z; vv[3] = v0.w;
                vv[4] = v1.x; vv[5] = v1.y; vv[6] = v1.z; vv[7] = v1.w;
            } else {
#pragma unroll
                for (int t = 0; t < 8; ++t)
                    vv[t] = (grow < N && kb + t < ATOM_DIM) ? A[(size_t)grow * ATOM_DIM + kb + t] : 0.f;
            }
            ushort4 p0, p1;
            p0.x = f2bf(vv[0]); p0.y = f2bf(vv[1]); p0.z = f2bf(vv[2]); p0.w = f2bf(vv[3]);
            p1.x = f2bf(vv[4]); p1.y = f2bf(vv[5]); p1.z = f2bf(vv[6]); p1.w = f2bf(vv[7]);
            *reinterpret_cast<ushort4*>(&As[rrow * LDA + koff]) = p0;
            *reinterpret_cast<ushort4*>(&As[rrow * LDA + koff + 4]) = p1;
            float4 w = *reinterpret_cast<const float4*>(Bt + (size_t)(col0 + rrow) * KP + kb);
            *reinterpret_cast<float4*>(&Bs[rrow * LDA + koff]) = w;
        }
        __syncthreads();
        bf16x8 a[4], b[4];
#pragma unroll
        for (int i = 0; i < 4; ++i)
            a[i] = *reinterpret_cast<const bf16x8*>(&As[(wr + i * 16 + r16) * LDA + q * 8]);
#pragma unroll
        for (int j = 0; j < 4; ++j)
            b[j] = *reinterpret_cast<const bf16x8*>(&Bs[(wc + j * 16 + r16) * LDA + q * 8]);
#pragma unroll
        for (int i = 0; i < 4; ++i)
#pragma unroll
            for (int j = 0; j < 4; ++j)
                acc[i][j] = __builtin_amdgcn_mfma_f32_16x16x32_bf16(a[i], b[j], acc[i][j], 0, 0, 0);
        __syncthreads();
    }

#pragma unroll
    for (int i = 0; i < 4; ++i) {
#pragma unroll
        for (int rr = 0; rr < 4; ++rr) {
            int grow = row0 + wr + i * 16 + q * 4 + rr;
            if (grow >= N) continue;
#pragma unroll
            for (int j = 0; j < 4; ++j) {
                int col = col0 + wc + j * 16 + r16;
                Cb[(size_t)grow * HID + col] =
                    __float2bfloat16(acc[i][j][rr] + bias[col]);
            }
        }
    }
}

// ---------------- pure bf16 MFMA GEMM (m97 structure) + alpha epilogue -----
// Cb[N,512] = A[N,512](bf16) @ Bt[512,512]^T(bf16); writes as/ad per head.
// 128x128 tile, BK=64, global_load_lds(16B) staging, XOR-swizzled LDS:
// LDS(row, slot) holds global chunk slot^(row&7); frag reads un-swizzle.
__launch_bounds__(256)
__global__ void gemm_mfma_kernel(const __hip_bfloat16* __restrict__ A,
                                 const __hip_bfloat16* __restrict__ Bt,
                                 __hip_bfloat16* __restrict__ Cb,
                                 const float* __restrict__ att_s,
                                 const float* __restrict__ att_d,
                                 float* __restrict__ as_out,
                                 float* __restrict__ ad_out,
                                 int N) {
    constexpr int K = HID;
    __shared__ __align__(16) short As[128 * BK];
    __shared__ __align__(16) short Bs[128 * BK];
    const int tid = threadIdx.x;
    const int wave = tid >> 6, lane = tid & 63;
    const int row0 = blockIdx.x * 128, col0 = blockIdx.y * 128;
    const int wr = (wave >> 1) * 64, wc = (wave & 1) * 64;
    const int q = lane >> 4, r16 = lane & 15;
    f32x4 acc[4][4] = {};

    // staging geometry: issue is covers flat chunks fc=(wave*4+is)*64+lane;
    // row = fc>>3 (8 rows/wave-issue, 128B contiguous per row), slot = fc&7.
    int rows[4], gchs[4];
#pragma unroll
    for (int is = 0; is < 4; ++is) {
        int fc = (wave * 4 + is) * 64 + lane;
        int row = fc >> 3;
        rows[is] = row;
        gchs[is] = (fc & 7) ^ (row & 7);
    }

    for (int k0 = 0; k0 < K; k0 += BK) {
#pragma unroll
        for (int is = 0; is < 4; ++is) {
            int row = rows[is], gch = gchs[is];
            int gra = row0 + row; if (gra > N - 1) gra = N - 1; // clamp (unused rows)
            gload_lds16(A + (size_t)gra * K + k0 + gch * 8, &As[(wave * 4 + is) * 512]);
            gload_lds16(Bt + (size_t)(col0 + row) * K + k0 + gch * 8, &Bs[(wave * 4 + is) * 512]);
        }
        __syncthreads();
#pragma unroll
        for (int kk = 0; kk < 2; ++kk) {
            bf16x8 a[4], b[4];
#pragma unroll
            for (int i = 0; i < 4; ++i) {
                int row = wr + i * 16 + r16;
                int sw = (kk * 4 + q) ^ (row & 7);
                a[i] = *reinterpret_cast<const bf16x8*>(&As[row * BK + sw * 8]);
            }
#pragma unroll
            for (int j = 0; j < 4; ++j) {
                int row = wc + j * 16 + r16;
                int sw = (kk * 4 + q) ^ (row & 7);
                b[j] = *reinterpret_cast<const bf16x8*>(&Bs[row * BK + sw * 8]);
            }
#pragma unroll
            for (int i = 0; i < 4; ++i)
#pragma unroll
                for (int j = 0; j < 4; ++j)
                    acc[i][j] = __builtin_amdgcn_mfma_f32_16x16x32_bf16(a[i], b[j], acc[i][j], 0, 0, 0);
        }
        __syncthreads();
    }

    // C write (bf16). C/D layout: col = lane&15, row = (lane>>4)*4 + reg
#pragma unroll
    for (int i = 0; i < 4; ++i) {
#pragma unroll
        for (int rr = 0; rr < 4; ++rr) {
            int grow = row0 + wr + i * 16 + q * 4 + rr;
            if (grow >= N) continue;
#pragma unroll
            for (int j = 0; j < 4; ++j)
                Cb[(size_t)grow * HID + col0 + wc + j * 16 + r16] =
                    __float2bfloat16(acc[i][j][rr]);
        }
    }

    // Fused alpha: wave's 64 cols == one head (fp32 from accumulators)
    const int head = (col0 + wc) >> 6;
    float avs[4], avd[4];
#pragma unroll
    for (int j = 0; j < 4; ++j) {
        avs[j] = att_s[col0 + wc + j * 16 + r16];
        avd[j] = att_d[col0 + wc + j * 16 + r16];
    }
#pragma unroll
    for (int i = 0; i < 4; ++i) {
#pragma unroll
        for (int rr = 0; rr < 4; ++rr) {
            float ss = 0.f, dd = 0.f;
#pragma unroll
            for (int j = 0; j < 4; ++j) {
                float v = acc[i][j][rr];
                ss += v * avs[j];
                dd += v * avd[j];
            }
#pragma unroll
            for (int off = 8; off > 0; off >>= 1) {
                ss += __shfl_xor(ss, off);
                dd += __shfl_xor(dd, off);
            }
            int grow = row0 + wr + i * 16 + q * 4 + rr;
            if (r16 == 0 && grow < N) {
                as_out[(size_t)grow * HEADS + head] = ss;
                ad_out[(size_t)grow * HEADS + head] = dd;
            }
        }
    }
}

// ---------------- CSR build ------------------------------------------------
__global__ void count_kernel(const int* __restrict__ ei, int* __restrict__ counts) {
    int e = blockIdx.x * blockDim.x + threadIdx.x;
    int tot = N_EDGES + N_NODES;
    if (e >= tot) return;
    int dst = e < N_EDGES ? ei[N_EDGES + e] : e - N_EDGES;
    atomicAdd(&counts[dst], 1);
}

__global__ void scan1_kernel(const int* __restrict__ counts, int* __restrict__ offsets,
                             int* __restrict__ bsums, int n) {
    __shared__ int tmp[1024];
    int tid = threadIdx.x;
    int gid = blockIdx.x * 1024 + tid;
    tmp[tid] = gid < n ? counts[gid] : 0;
    __syncthreads();
    for (int off = 1; off < 1024; off <<= 1) {
        int t = tid >= off ? tmp[tid - off] : 0;
        __syncthreads();
        tmp[tid] += t;
        __syncthreads();
    }
    if (gid < n) offsets[gid + 1] = tmp[tid];
    if (tid == 1023) bsums[blockIdx.x] = tmp[1023];
}

__global__ void scan2_kernel(int* bsums, int nb) {
    if (threadIdx.x == 0) {
        int s = 0;
        for (int i = 0; i < nb; ++i) { s += bsums[i]; bsums[i] = s; }
    }
}

__global__ void scan3_kernel(const int* __restrict__ counts, int* __restrict__ offsets,
                             const int* __restrict__ bsums, int* __restrict__ wp, int n) {
    int tid = threadIdx.x;
    int gid = blockIdx.x * 1024 + tid;
    if (gid == 0) offsets[0] = 0;
    if (gid >= n) return;
    int add = blockIdx.x > 0 ? bsums[blockIdx.x - 1] : 0;
    int v = offsets[gid + 1] + add;
    offsets[gid + 1] = v;
    wp[gid] = v - counts[gid];
}

__global__ void scatter_kernel(const int* __restrict__ ei, int* __restrict__ wp,
                               int* __restrict__ csrc) {
    int e = blockIdx.x * blockDim.x + threadIdx.x;
    int tot = N_EDGES + N_NODES;
    if (e >= tot) return;
    int src = e < N_EDGES ? ei[e] : e - N_EDGES;
    int dst = e < N_EDGES ? ei[N_EDGES + e] : e - N_EDGES;
    int pos = atomicAdd(&wp[dst], 1);
    csrc[pos] = src;
}

// ---------------- softmax-attention aggregation + fused BN stats -----------
__launch_bounds__(512)
__global__ void agg_kernel(const __hip_bfloat16* __restrict__ hb, const float* __restrict__ as,
                           const float* __restrict__ ad, const int* __restrict__ offsets,
                           const int* __restrict__ csrc, const float* __restrict__ bias,
                           __hip_bfloat16* __restrict__ outb,
                           float* __restrict__ ps, float* __restrict__ pq) {
    __shared__ float psum[8][HID];
    const int wave = threadIdx.x >> 6, lane = threadIdx.x & 63;
    const int i = blockIdx.x * 8 + wave;
    const int head = lane >> 3;
    const int c0 = lane << 3;
    const int beg = offsets[i];
    const int deg = offsets[i + 1] - beg;
    const float adv = ad[(size_t)i * HEADS + head];

    float a[8] = {};
    float den = 0.f;

    for (int e0 = 0; e0 < deg; e0 += 4) {
        int m = deg - e0; if (m > 4) m = 4;
        int s[4];
#pragma unroll
        for (int k = 0; k < 4; ++k) {
            int kk = k < m ? k : m - 1;
            s[k] = csrc[beg + e0 + kk];
        }
        float w[4];
#pragma unroll
        for (int k = 0; k < 4; ++k)
            w[k] = (k < m) ? __expf(lrelu(as[(size_t)s[k] * HEADS + head] + adv)) : 0.f;
#pragma unroll
        for (int k = 0; k < 4; ++k) {
            bf16x8 hv = *reinterpret_cast<const bf16x8*>(hb + (size_t)s[k] * HID + c0);
#pragma unroll
            for (int t = 0; t < 8; ++t)
                a[t] += w[k] * bf2f((unsigned short)hv[t]);
            den += w[k];
        }
    }
    float inv = 1.f / den;
    float o[8];
    const float4* bp = reinterpret_cast<const float4*>(bias + c0);
    float4 b0 = bp[0], b1 = bp[1];
    float bb[8] = {b0.x, b0.y, b0.z, b0.w, b1.x, b1.y, b1.z, b1.w};
    ushort4 p0, p1;
#pragma unroll
    for (int t = 0; t < 8; ++t) o[t] = a[t] * inv + bb[t];
    p0.x = f2bf(o[0]); p0.y = f2bf(o[1]); p0.z = f2bf(o[2]); p0.w = f2bf(o[3]);
    p1.x = f2bf(o[4]); p1.y = f2bf(o[5]); p1.z = f2bf(o[6]); p1.w = f2bf(o[7]);
    ushort4* op = reinterpret_cast<ushort4*>(outb + (size_t)i * HID + c0);
    op[0] = p0; op[1] = p1;

    // fused BN stats (from fp32 values)
#pragma unroll
    for (int t = 0; t < 8; ++t) psum[wave][c0 + t] = o[t];
    __syncthreads();
    int c = threadIdx.x; // 512 == HID
    float s = 0.f, q = 0.f;
#pragma unroll
    for (int w = 0; w < 8; ++w) {
        float v = psum[w][c];
        s += v; q += v * v;
    }
    int bin = blockIdx.x & (NBINS - 1);
    atomicAdd(&ps[bin * HID + c], s);
    atomicAdd(&pq[bin * HID + c], q);
}

// ---------------- BN prep: fold bins (wave per channel) --------------------
// grid 64 blocks x 512 threads; NBINS=128: lane covers bins lane, lane+64.
__global__ void bn_prep_kernel(const float* __restrict__ ps, const float* __restrict__ pq,
                               const float* __restrict__ gamma, const float* __restrict__ beta,
                               float* __restrict__ sc, float* __restrict__ sh, int n) {
    int wave = threadIdx.x >> 6, lane = threadIdx.x & 63;
    int c = blockIdx.x * 8 + wave;
    float s = ps[lane * HID + c] + ps[(lane + 64) * HID + c];
    float q = pq[lane * HID + c] + pq[(lane + 64) * HID + c];
#pragma unroll
    for (int off = 32; off > 0; off >>= 1) {
        s += __shfl_xor(s, off);
        q += __shfl_xor(q, off);
    }
    if (lane == 0) {
        float inv_n = 1.f / (float)n;
        float mu = s * inv_n;
        float var = q * inv_n - mu * mu;
        float g = rsqrtf(var + 1e-5f) * gamma[c];
        sc[c] = g;
        sh[c] = beta[c] - mu * g;
    }
}

// ---------------- standalone BN apply: xn = bf16(relu(xb*sc+sh)) -----------
__launch_bounds__(256)
__global__ void bn_apply_kernel(const __hip_bfloat16* __restrict__ xin,
                                __hip_bfloat16* __restrict__ xout,
                                const float* __restrict__ sc, const float* __restrict__ sh) {
    size_t idx = ((size_t)blockIdx.x * 256 + threadIdx.x) * 8;
    int c = (int)(idx & (HID - 1));
    bf16x8 v = *reinterpret_cast<const bf16x8*>(xin + idx);
    const float4* scp = reinterpret_cast<const float4*>(sc + c);
    const float4* shp = reinterpret_cast<const float4*>(sh + c);
    float4 s0 = scp[0], s1 = scp[1], h0 = shp[0], h1 = shp[1];
    float scv[8] = {s0.x, s0.y, s0.z, s0.w, s1.x, s1.y, s1.z, s1.w};
    float shv[8] = {h0.x, h0.y, h0.z, h0.w, h1.x, h1.y, h1.z, h1.w};
    bf16x8 o;
#pragma unroll
    for (int t = 0; t < 8; ++t) {
        float val = fmaf(bf2f((unsigned short)v[t]), scv[t], shv[t]);
        o[t] = (short)f2bf(val > 0.f ? val : 0.f);
    }
    *reinterpret_cast<bf16x8*>(xout + idx) = o;
}

// ---------------- pooling with fused final BN+ReLU -------------------------
__global__ void pool_bn_kernel(const __hip_bfloat16* __restrict__ xb, const int* __restrict__ batch,
                               const float* __restrict__ sc, const float* __restrict__ sh,
                               float* __restrict__ pooled, int* __restrict__ gcnt) {
    int i = blockIdx.x;
    int g = batch[i];
    for (int c = threadIdx.x; c < HID; c += 256) {
        float xv = __bfloat162float(xb[(size_t)i * HID + c]);
        float v = fmaf(xv, sc[c], sh[c]);
        v = v > 0.f ? v : 0.f;
        atomicAdd(&pooled[(size_t)g * HID + c], v);
    }
    if (threadIdx.x == 0) atomicAdd(&gcnt[g], 1);
}

__global__ void mlp1_kernel(const float* __restrict__ pooled, const int* __restrict__ gcnt,
                            const float* __restrict__ w1, const float* __restrict__ b1,
                            float* __restrict__ h1) {
    __shared__ float row[HID];
    int g = blockIdx.x;
    int tid = threadIdx.x; // 256
    row[tid] = pooled[(size_t)g * HID + tid];
    row[tid + 256] = pooled[(size_t)g * HID + tid + 256];
    __syncthreads();
    float inv = 1.f / fmaxf((float)gcnt[g], 1.f);
    float acc = 0.f;
    for (int c = 0; c < HID; ++c) acc += row[c] * w1[c * 256 + tid];
    float v = acc * inv + b1[tid];
    h1[g * 256 + tid] = v > 0.f ? v : 0.f;
}

__global__ void mlp2_kernel(const float* __restrict__ h1, const float* __restrict__ w2,
                            const float* __restrict__ b2, float* __restrict__ out) {
    __shared__ float row[256];
    int g = blockIdx.x;
    int tid = threadIdx.x; // 64
    for (int j = tid; j < 256; j += 64) row[j] = h1[g * 256 + j];
    __syncthreads();
    if (tid < TARGETS) {
        float acc = 0.f;
        for (int j = 0; j < 256; ++j) acc += row[j] * w2[j * TARGETS + tid];
        out[g * TARGETS + tid] = acc + b2[tid];
    }
}

// ---------------------------------------------------------------------------
extern "C" void kernel_launch(void* const* d_in, const int* in_sizes, int n_in,
                              void* d_out, int out_size, void* d_ws, size_t ws_size,
                              hipStream_t stream) {
    const float* atom   = (const float*)d_in[0];
    const int*   ei     = (const int*)d_in[2];   // [2, N_EDGES]
    const int*   batch  = (const int*)d_in[3];
    const float* atom_w = (const float*)d_in[4];
    const float* atom_b = (const float*)d_in[5];
    const float* gat_w  = (const float*)d_in[6];
    const float* att_s  = (const float*)d_in[7];
    const float* att_d  = (const float*)d_in[8];
    const float* gat_b  = (const float*)d_in[9];
    const float* bn_g   = (const float*)d_in[10];
    const float* bn_b   = (const float*)d_in[11];
    const float* w1     = (const float*)d_in[12];
    const float* b1     = (const float*)d_in[13];
    const float* w2     = (const float*)d_in[14];
    const float* b2     = (const float*)d_in[15];
    float* out = (float*)d_out;

    const int ETOT = N_EDGES + N_NODES;

    char* ws = (char*)d_ws;
    size_t off = 0;
    auto alloc = [&](size_t bytes) {
        void* p = ws + off;
        off += (bytes + 255) & ~(size_t)255;
        return p;
    };
    __hip_bfloat16* xn  = (__hip_bfloat16*)alloc((size_t)N_NODES * HID * 2); // 51.2 MB (BN'd input)
    __hip_bfloat16* xb  = (__hip_bfloat16*)alloc((size_t)N_NODES * HID * 2); // 51.2 MB (raw agg out)
    __hip_bfloat16* hb  = (__hip_bfloat16*)alloc((size_t)N_NODES * HID * 2); // 51.2 MB
    __hip_bfloat16* Wt  = (__hip_bfloat16*)alloc((size_t)LAYERS * HID * HID * 2); // 3.1 MB
    __hip_bfloat16* Wt0 = (__hip_bfloat16*)alloc((size_t)HID * 128 * 2);          // 131 KB
    float* as_    = (float*)alloc((size_t)N_NODES * HEADS * 4);
    float* ad_    = (float*)alloc((size_t)N_NODES * HEADS * 4);
    int* counts   = (int*)alloc(N_NODES * 4);
    int* offsets  = (int*)alloc((N_NODES + 1) * 4);
    int* wp       = (int*)alloc(N_NODES * 4);
    int* csrc     = (int*)alloc(ETOT * 4);
    int* bsums    = (int*)alloc(64 * 4);
    float* part_s = (float*)alloc((size_t)NBINS * HID * 4);     // 256 KB
    float* part_q = (float*)alloc((size_t)NBINS * HID * 4);     // 256 KB
    float* bn_sc  = (float*)alloc(HID * 4);
    float* bn_sh  = (float*)alloc(HID * 4);
    float* pooled = (float*)alloc((size_t)N_GRAPHS * HID * 4);
    int* gcnt     = (int*)alloc(N_GRAPHS * 4);
    float* h1     = (float*)alloc((size_t)N_GRAPHS * 256 * 4);

    // ---- CSR build (by dst; self-loops appended; stores src per slot) ----
    hipMemsetAsync(counts, 0, N_NODES * 4, stream);
    count_kernel<<<(ETOT + 255) / 256, 256, 0, stream>>>(ei, counts);
    int nb = (N_NODES + 1023) / 1024;
    scan1_kernel<<<nb, 1024, 0, stream>>>(counts, offsets, bsums, N_NODES);
    scan2_kernel<<<1, 64, 0, stream>>>(bsums, nb);
    scan3_kernel<<<nb, 1024, 0, stream>>>(counts, offsets, bsums, wp, N_NODES);
    scatter_kernel<<<(ETOT + 255) / 256, 256, 0, stream>>>(ei, wp, csrc);

    // ---- weights: transpose + bf16 convert ----
    wtrans_kernel<<<dim3(HID / 32, HID / 32, LAYERS), dim3(32, 8), 0, stream>>>(gat_w, Wt);
    atomwt_kernel<<<(HID * 128 + 255) / 256, 256, 0, stream>>>(atom_w, Wt0);

    // ---- atom projection -> xn (bf16) via MFMA (K padded to 128) ----
    gemm_atom_kernel<<<dim3((N_NODES + 127) / 128, HID / 128), 256, 0, stream>>>(
        atom, Wt0, atom_b, xn, N_NODES);

    // ---- 6 GAT layers ----
    for (int l = 0; l < LAYERS; ++l) {
        gemm_mfma_kernel<<<dim3((N_NODES + 127) / 128, HID / 128), 256, 0, stream>>>(
            xn, Wt + (size_t)l * HID * HID, hb,
            att_s + l * HID, att_d + l * HID, as_, ad_, N_NODES);
        hipMemsetAsync(part_s, 0, (size_t)NBINS * HID * 4, stream);
        hipMemsetAsync(part_q, 0, (size_t)NBINS * HID * 4, stream);
        agg_kernel<<<N_NODES / 8, 512, 0, stream>>>(hb, as_, ad_, offsets, csrc,
                                                    gat_b + l * HID, xb, part_s, part_q);
        bn_prep_kernel<<<64, 512, 0, stream>>>(part_s, part_q, bn_g + l * HID, bn_b + l * HID,
                                               bn_sc, bn_sh, N_NODES);
        if (l < LAYERS - 1)
            bn_apply_kernel<<<(int)((size_t)N_NODES * HID / 8 / 256), 256, 0, stream>>>(
                xb, xn, bn_sc, bn_sh);
    }

    // ---- global mean pool (with fused final BN+ReLU) + MLP head ----
    hipMemsetAsync(pooled, 0, (size_t)N_GRAPHS * HID * 4, stream);
    hipMemsetAsync(gcnt, 0, N_GRAPHS * 4, stream);
    pool_bn_kernel<<<N_NODES, 256, 0, stream>>>(xb, batch, bn_sc, bn_sh, pooled, gcnt);
    mlp1_kernel<<<N_GRAPHS, 256, 0, stream>>>(pooled, gcnt, w1, b1, h1);
    mlp2_kernel<<<N_GRAPHS, 64, 0, stream>>>(h1, w2, b2, out);
}

// Round 9
// 1104.899 us; speedup vs baseline: 4.3618x; 1.0678x over previous
//
#include <hip/hip_runtime.h>
#include <hip/hip_bf16.h>

// ---------------------------------------------------------------------------
// MolecularGNN: atom proj -> 6x (GATConv + BN + ReLU) -> mean pool -> MLP
// Round 9: pool rewritten atomic-free. R8 counters: pool_bn's 50000x512
// fp32 atomicAdds each wrote through to HBM (WRITE_SIZE 101.5MB == every
// atomic), 104us. batch is sorted -> per-graph node ranges are contiguous:
// build graph offsets (count+scan, n=2000), then one wave per graph
// accumulates rows in registers (BN+ReLU inline), writes mean once.
// ---------------------------------------------------------------------------

#define N_NODES 50000
#define N_EDGES 150000
#define N_GRAPHS 2000
#define ATOM_DIM 100
#define HID 512
#define HEADS 8
#define HEAD_DIM 64
#define LAYERS 6
#define TARGETS 13
#define NBINS 128
#define BK 64

typedef __attribute__((ext_vector_type(8))) short bf16x8;
typedef __attribute__((ext_vector_type(4))) float f32x4;

__device__ __forceinline__ float lrelu(float v) { return v > 0.f ? v : 0.2f * v; }

__device__ __forceinline__ unsigned short f2bf(float v) {
    __hip_bfloat16 b = __float2bfloat16(v);
    return *reinterpret_cast<unsigned short*>(&b);
}
__device__ __forceinline__ float bf2f(unsigned short u) {
    unsigned int x = ((unsigned int)u) << 16;
    return __uint_as_float(x);
}

typedef __attribute__((address_space(3))) unsigned int lds_uint;
typedef __attribute__((address_space(1))) const unsigned int glob_uint;

// async global->LDS, 16B per lane; lds dest = wave-uniform base + lane*16
__device__ __forceinline__ void gload_lds16(const void* g, void* l) {
    __builtin_amdgcn_global_load_lds((glob_uint*)g, (lds_uint*)l, 16, 0, 0);
}

// ---------------- weight transpose + bf16 convert (layer weights) ----------
__global__ void wtrans_kernel(const float* __restrict__ W, __hip_bfloat16* __restrict__ Wt) {
    __shared__ float t[32][33];
    int l = blockIdx.z;
    int k0 = blockIdx.x * 32, m0 = blockIdx.y * 32;
    const float* Wl = W + (size_t)l * HID * HID;
    __hip_bfloat16* Wtl = Wt + (size_t)l * HID * HID;
#pragma unroll
    for (int i = 0; i < 32; i += 8)
        t[threadIdx.y + i][threadIdx.x] = Wl[(size_t)(k0 + threadIdx.y + i) * HID + m0 + threadIdx.x];
    __syncthreads();
#pragma unroll
    for (int i = 0; i < 32; i += 8)
        Wtl[(size_t)(m0 + threadIdx.y + i) * HID + k0 + threadIdx.x] =
            __float2bfloat16(t[threadIdx.x][threadIdx.y + i]);
}

// ---------------- atom_w transpose: Wt0[m][k] = bf16(atom_w[k][m]), k pad 128
__global__ void atomwt_kernel(const float* __restrict__ aw, __hip_bfloat16* __restrict__ Wt0) {
    int idx = blockIdx.x * 256 + threadIdx.x; // 512*128 total
    if (idx >= HID * 128) return;
    int k = idx >> 9, m = idx & (HID - 1);
    float v = (k < ATOM_DIM) ? aw[(size_t)k * HID + m] : 0.f;
    Wt0[(size_t)m * 128 + k] = __float2bfloat16(v);
}

// ---------------- atom projection MFMA: xn[N,512] = bf16(atom) @ Wt0^T + b -
__launch_bounds__(256)
__global__ void gemm_atom_kernel(const float* __restrict__ A,
                                 const __hip_bfloat16* __restrict__ Bt,
                                 const float* __restrict__ bias,
                                 __hip_bfloat16* __restrict__ Cb, int N) {
    constexpr int KP = 128;
    constexpr int LDA = 40;
    __shared__ __align__(16) short As[128 * LDA];
    __shared__ __align__(16) short Bs[128 * LDA];
    const int tid = threadIdx.x;
    const int wave = tid >> 6, lane = tid & 63;
    const int row0 = blockIdx.x * 128, col0 = blockIdx.y * 128;
    const int wr = (wave >> 1) * 64, wc = (wave & 1) * 64;
    const int q = lane >> 4, r16 = lane & 15;
    f32x4 acc[4][4] = {};

    for (int k0 = 0; k0 < KP; k0 += 32) {
#pragma unroll
        for (int c = tid; c < 512; c += 256) {
            int rrow = c >> 2, koff = (c & 3) << 3;
            int grow = row0 + rrow;
            int kb = k0 + koff;
            float vv[8];
            if (grow < N && kb + 8 <= ATOM_DIM) {
                const float* ap = A + (size_t)grow * ATOM_DIM + kb;
                float4 v0 = *reinterpret_cast<const float4*>(ap);
                float4 v1 = *reinterpret_cast<const float4*>(ap + 4);
                vv[0] = v0.x; vv[1] = v0.y; vv[2] = v0.z; vv[3] = v0.w;
                vv[4] = v1.x; vv[5] = v1.y; vv[6] = v1.z; vv[7] = v1.w;
            } else {
#pragma unroll
                for (int t = 0; t < 8; ++t)
                    vv[t] = (grow < N && kb + t < ATOM_DIM) ? A[(size_t)grow * ATOM_DIM + kb + t] : 0.f;
            }
            ushort4 p0, p1;
            p0.x = f2bf(vv[0]); p0.y = f2bf(vv[1]); p0.z = f2bf(vv[2]); p0.w = f2bf(vv[3]);
            p1.x = f2bf(vv[4]); p1.y = f2bf(vv[5]); p1.z = f2bf(vv[6]); p1.w = f2bf(vv[7]);
            *reinterpret_cast<ushort4*>(&As[rrow * LDA + koff]) = p0;
            *reinterpret_cast<ushort4*>(&As[rrow * LDA + koff + 4]) = p1;
            float4 w = *reinterpret_cast<const float4*>(Bt + (size_t)(col0 + rrow) * KP + kb);
            *reinterpret_cast<float4*>(&Bs[rrow * LDA + koff]) = w;
        }
        __syncthreads();
        bf16x8 a[4], b[4];
#pragma unroll
        for (int i = 0; i < 4; ++i)
            a[i] = *reinterpret_cast<const bf16x8*>(&As[(wr + i * 16 + r16) * LDA + q * 8]);
#pragma unroll
        for (int j = 0; j < 4; ++j)
            b[j] = *reinterpret_cast<const bf16x8*>(&Bs[(wc + j * 16 + r16) * LDA + q * 8]);
#pragma unroll
        for (int i = 0; i < 4; ++i)
#pragma unroll
            for (int j = 0; j < 4; ++j)
                acc[i][j] = __builtin_amdgcn_mfma_f32_16x16x32_bf16(a[i], b[j], acc[i][j], 0, 0, 0);
        __syncthreads();
    }

#pragma unroll
    for (int i = 0; i < 4; ++i) {
#pragma unroll
        for (int rr = 0; rr < 4; ++rr) {
            int grow = row0 + wr + i * 16 + q * 4 + rr;
            if (grow >= N) continue;
#pragma unroll
            for (int j = 0; j < 4; ++j) {
                int col = col0 + wc + j * 16 + r16;
                Cb[(size_t)grow * HID + col] =
                    __float2bfloat16(acc[i][j][rr] + bias[col]);
            }
        }
    }
}

// ---------------- pure bf16 MFMA GEMM (m97 structure) + alpha epilogue -----
// Cb[N,512] = A[N,512](bf16) @ Bt[512,512]^T(bf16); writes as/ad per head.
// 128x128 tile, BK=64, global_load_lds(16B) staging, XOR-swizzled LDS.
__launch_bounds__(256)
__global__ void gemm_mfma_kernel(const __hip_bfloat16* __restrict__ A,
                                 const __hip_bfloat16* __restrict__ Bt,
                                 __hip_bfloat16* __restrict__ Cb,
                                 const float* __restrict__ att_s,
                                 const float* __restrict__ att_d,
                                 float* __restrict__ as_out,
                                 float* __restrict__ ad_out,
                                 int N) {
    constexpr int K = HID;
    __shared__ __align__(16) short As[128 * BK];
    __shared__ __align__(16) short Bs[128 * BK];
    const int tid = threadIdx.x;
    const int wave = tid >> 6, lane = tid & 63;
    const int row0 = blockIdx.x * 128, col0 = blockIdx.y * 128;
    const int wr = (wave >> 1) * 64, wc = (wave & 1) * 64;
    const int q = lane >> 4, r16 = lane & 15;
    f32x4 acc[4][4] = {};

    int rows[4], gchs[4];
#pragma unroll
    for (int is = 0; is < 4; ++is) {
        int fc = (wave * 4 + is) * 64 + lane;
        int row = fc >> 3;
        rows[is] = row;
        gchs[is] = (fc & 7) ^ (row & 7);
    }

    for (int k0 = 0; k0 < K; k0 += BK) {
#pragma unroll
        for (int is = 0; is < 4; ++is) {
            int row = rows[is], gch = gchs[is];
            int gra = row0 + row; if (gra > N - 1) gra = N - 1;
            gload_lds16(A + (size_t)gra * K + k0 + gch * 8, &As[(wave * 4 + is) * 512]);
            gload_lds16(Bt + (size_t)(col0 + row) * K + k0 + gch * 8, &Bs[(wave * 4 + is) * 512]);
        }
        __syncthreads();
#pragma unroll
        for (int kk = 0; kk < 2; ++kk) {
            bf16x8 a[4], b[4];
#pragma unroll
            for (int i = 0; i < 4; ++i) {
                int row = wr + i * 16 + r16;
                int sw = (kk * 4 + q) ^ (row & 7);
                a[i] = *reinterpret_cast<const bf16x8*>(&As[row * BK + sw * 8]);
            }
#pragma unroll
            for (int j = 0; j < 4; ++j) {
                int row = wc + j * 16 + r16;
                int sw = (kk * 4 + q) ^ (row & 7);
                b[j] = *reinterpret_cast<const bf16x8*>(&Bs[row * BK + sw * 8]);
            }
#pragma unroll
            for (int i = 0; i < 4; ++i)
#pragma unroll
                for (int j = 0; j < 4; ++j)
                    acc[i][j] = __builtin_amdgcn_mfma_f32_16x16x32_bf16(a[i], b[j], acc[i][j], 0, 0, 0);
        }
        __syncthreads();
    }

    // C write (bf16). C/D layout: col = lane&15, row = (lane>>4)*4 + reg
#pragma unroll
    for (int i = 0; i < 4; ++i) {
#pragma unroll
        for (int rr = 0; rr < 4; ++rr) {
            int grow = row0 + wr + i * 16 + q * 4 + rr;
            if (grow >= N) continue;
#pragma unroll
            for (int j = 0; j < 4; ++j)
                Cb[(size_t)grow * HID + col0 + wc + j * 16 + r16] =
                    __float2bfloat16(acc[i][j][rr]);
        }
    }

    // Fused alpha: wave's 64 cols == one head (fp32 from accumulators)
    const int head = (col0 + wc) >> 6;
    float avs[4], avd[4];
#pragma unroll
    for (int j = 0; j < 4; ++j) {
        avs[j] = att_s[col0 + wc + j * 16 + r16];
        avd[j] = att_d[col0 + wc + j * 16 + r16];
    }
#pragma unroll
    for (int i = 0; i < 4; ++i) {
#pragma unroll
        for (int rr = 0; rr < 4; ++rr) {
            float ss = 0.f, dd = 0.f;
#pragma unroll
            for (int j = 0; j < 4; ++j) {
                float v = acc[i][j][rr];
                ss += v * avs[j];
                dd += v * avd[j];
            }
#pragma unroll
            for (int off = 8; off > 0; off >>= 1) {
                ss += __shfl_xor(ss, off);
                dd += __shfl_xor(dd, off);
            }
            int grow = row0 + wr + i * 16 + q * 4 + rr;
            if (r16 == 0 && grow < N) {
                as_out[(size_t)grow * HEADS + head] = ss;
                ad_out[(size_t)grow * HEADS + head] = dd;
            }
        }
    }
}

// ---------------- generic count (edges+self-loops -> dst bins) -------------
__global__ void count_kernel(const int* __restrict__ ei, int* __restrict__ counts) {
    int e = blockIdx.x * blockDim.x + threadIdx.x;
    int tot = N_EDGES + N_NODES;
    if (e >= tot) return;
    int dst = e < N_EDGES ? ei[N_EDGES + e] : e - N_EDGES;
    atomicAdd(&counts[dst], 1);
}

// count nodes per graph
__global__ void gcount_kernel(const int* __restrict__ batch, int* __restrict__ gc) {
    int i = blockIdx.x * blockDim.x + threadIdx.x;
    if (i < N_NODES) atomicAdd(&gc[batch[i]], 1);
}

__global__ void scan1_kernel(const int* __restrict__ counts, int* __restrict__ offsets,
                             int* __restrict__ bsums, int n) {
    __shared__ int tmp[1024];
    int tid = threadIdx.x;
    int gid = blockIdx.x * 1024 + tid;
    tmp[tid] = gid < n ? counts[gid] : 0;
    __syncthreads();
    for (int off = 1; off < 1024; off <<= 1) {
        int t = tid >= off ? tmp[tid - off] : 0;
        __syncthreads();
        tmp[tid] += t;
        __syncthreads();
    }
    if (gid < n) offsets[gid + 1] = tmp[tid];
    if (tid == 1023) bsums[blockIdx.x] = tmp[1023];
}

__global__ void scan2_kernel(int* bsums, int nb) {
    if (threadIdx.x == 0) {
        int s = 0;
        for (int i = 0; i < nb; ++i) { s += bsums[i]; bsums[i] = s; }
    }
}

__global__ void scan3_kernel(const int* __restrict__ counts, int* __restrict__ offsets,
                             const int* __restrict__ bsums, int* __restrict__ wp, int n) {
    int tid = threadIdx.x;
    int gid = blockIdx.x * 1024 + tid;
    if (gid == 0) offsets[0] = 0;
    if (gid >= n) return;
    int add = blockIdx.x > 0 ? bsums[blockIdx.x - 1] : 0;
    int v = offsets[gid + 1] + add;
    offsets[gid + 1] = v;
    wp[gid] = v - counts[gid];
}

__global__ void scatter_kernel(const int* __restrict__ ei, int* __restrict__ wp,
                               int* __restrict__ csrc) {
    int e = blockIdx.x * blockDim.x + threadIdx.x;
    int tot = N_EDGES + N_NODES;
    if (e >= tot) return;
    int src = e < N_EDGES ? ei[e] : e - N_EDGES;
    int dst = e < N_EDGES ? ei[N_EDGES + e] : e - N_EDGES;
    int pos = atomicAdd(&wp[dst], 1);
    csrc[pos] = src;
}

// ---------------- softmax-attention aggregation + fused BN stats -----------
__launch_bounds__(512)
__global__ void agg_kernel(const __hip_bfloat16* __restrict__ hb, const float* __restrict__ as,
                           const float* __restrict__ ad, const int* __restrict__ offsets,
                           const int* __restrict__ csrc, const float* __restrict__ bias,
                           __hip_bfloat16* __restrict__ outb,
                           float* __restrict__ ps, float* __restrict__ pq) {
    __shared__ float psum[8][HID];
    const int wave = threadIdx.x >> 6, lane = threadIdx.x & 63;
    const int i = blockIdx.x * 8 + wave;
    const int head = lane >> 3;
    const int c0 = lane << 3;
    const int beg = offsets[i];
    const int deg = offsets[i + 1] - beg;
    const float adv = ad[(size_t)i * HEADS + head];

    float a[8] = {};
    float den = 0.f;

    for (int e0 = 0; e0 < deg; e0 += 4) {
        int m = deg - e0; if (m > 4) m = 4;
        int s[4];
#pragma unroll
        for (int k = 0; k < 4; ++k) {
            int kk = k < m ? k : m - 1;
            s[k] = csrc[beg + e0 + kk];
        }
        float w[4];
#pragma unroll
        for (int k = 0; k < 4; ++k)
            w[k] = (k < m) ? __expf(lrelu(as[(size_t)s[k] * HEADS + head] + adv)) : 0.f;
#pragma unroll
        for (int k = 0; k < 4; ++k) {
            bf16x8 hv = *reinterpret_cast<const bf16x8*>(hb + (size_t)s[k] * HID + c0);
#pragma unroll
            for (int t = 0; t < 8; ++t)
                a[t] += w[k] * bf2f((unsigned short)hv[t]);
            den += w[k];
        }
    }
    float inv = 1.f / den;
    float o[8];
    const float4* bp = reinterpret_cast<const float4*>(bias + c0);
    float4 b0 = bp[0], b1 = bp[1];
    float bb[8] = {b0.x, b0.y, b0.z, b0.w, b1.x, b1.y, b1.z, b1.w};
    ushort4 p0, p1;
#pragma unroll
    for (int t = 0; t < 8; ++t) o[t] = a[t] * inv + bb[t];
    p0.x = f2bf(o[0]); p0.y = f2bf(o[1]); p0.z = f2bf(o[2]); p0.w = f2bf(o[3]);
    p1.x = f2bf(o[4]); p1.y = f2bf(o[5]); p1.z = f2bf(o[6]); p1.w = f2bf(o[7]);
    ushort4* op = reinterpret_cast<ushort4*>(outb + (size_t)i * HID + c0);
    op[0] = p0; op[1] = p1;

    // fused BN stats (from fp32 values)
#pragma unroll
    for (int t = 0; t < 8; ++t) psum[wave][c0 + t] = o[t];
    __syncthreads();
    int c = threadIdx.x; // 512 == HID
    float s = 0.f, q = 0.f;
#pragma unroll
    for (int w = 0; w < 8; ++w) {
        float v = psum[w][c];
        s += v; q += v * v;
    }
    int bin = blockIdx.x & (NBINS - 1);
    atomicAdd(&ps[bin * HID + c], s);
    atomicAdd(&pq[bin * HID + c], q);
}

// ---------------- BN prep: fold bins (wave per channel) --------------------
__global__ void bn_prep_kernel(const float* __restrict__ ps, const float* __restrict__ pq,
                               const float* __restrict__ gamma, const float* __restrict__ beta,
                               float* __restrict__ sc, float* __restrict__ sh, int n) {
    int wave = threadIdx.x >> 6, lane = threadIdx.x & 63;
    int c = blockIdx.x * 8 + wave;
    float s = ps[lane * HID + c] + ps[(lane + 64) * HID + c];
    float q = pq[lane * HID + c] + pq[(lane + 64) * HID + c];
#pragma unroll
    for (int off = 32; off > 0; off >>= 1) {
        s += __shfl_xor(s, off);
        q += __shfl_xor(q, off);
    }
    if (lane == 0) {
        float inv_n = 1.f / (float)n;
        float mu = s * inv_n;
        float var = q * inv_n - mu * mu;
        float g = rsqrtf(var + 1e-5f) * gamma[c];
        sc[c] = g;
        sh[c] = beta[c] - mu * g;
    }
}

// ---------------- standalone BN apply: xn = bf16(relu(xb*sc+sh)) -----------
__launch_bounds__(256)
__global__ void bn_apply_kernel(const __hip_bfloat16* __restrict__ xin,
                                __hip_bfloat16* __restrict__ xout,
                                const float* __restrict__ sc, const float* __restrict__ sh) {
    size_t idx = ((size_t)blockIdx.x * 256 + threadIdx.x) * 8;
    int c = (int)(idx & (HID - 1));
    bf16x8 v = *reinterpret_cast<const bf16x8*>(xin + idx);
    const float4* scp = reinterpret_cast<const float4*>(sc + c);
    const float4* shp = reinterpret_cast<const float4*>(sh + c);
    float4 s0 = scp[0], s1 = scp[1], h0 = shp[0], h1 = shp[1];
    float scv[8] = {s0.x, s0.y, s0.z, s0.w, s1.x, s1.y, s1.z, s1.w};
    float shv[8] = {h0.x, h0.y, h0.z, h0.w, h1.x, h1.y, h1.z, h1.w};
    bf16x8 o;
#pragma unroll
    for (int t = 0; t < 8; ++t) {
        float val = fmaf(bf2f((unsigned short)v[t]), scv[t], shv[t]);
        o[t] = (short)f2bf(val > 0.f ? val : 0.f);
    }
    *reinterpret_cast<bf16x8*>(xout + idx) = o;
}

// ---------------- pooling: wave per graph, no atomics ----------------------
// batch is sorted; graph g's nodes are rows [goff[g], goff[g+1]). Lane owns
// 8 channels; BN+ReLU per element, then mean. pooled = mean directly.
__launch_bounds__(256)
__global__ void pool_bn_kernel(const __hip_bfloat16* __restrict__ xb,
                               const int* __restrict__ goff,
                               const float* __restrict__ sc, const float* __restrict__ sh,
                               float* __restrict__ pooled) {
    const int wave = threadIdx.x >> 6, lane = threadIdx.x & 63;
    const int g = blockIdx.x * 4 + wave;
    if (g >= N_GRAPHS) return;
    const int beg = goff[g], end = goff[g + 1];
    const int c0 = lane << 3;
    const float4* scp = reinterpret_cast<const float4*>(sc + c0);
    const float4* shp = reinterpret_cast<const float4*>(sh + c0);
    float4 s0 = scp[0], s1 = scp[1], h0 = shp[0], h1 = shp[1];
    float scv[8] = {s0.x, s0.y, s0.z, s0.w, s1.x, s1.y, s1.z, s1.w};
    float shv[8] = {h0.x, h0.y, h0.z, h0.w, h1.x, h1.y, h1.z, h1.w};
    float acc[8] = {};
    for (int i = beg; i < end; ++i) {
        bf16x8 v = *reinterpret_cast<const bf16x8*>(xb + (size_t)i * HID + c0);
#pragma unroll
        for (int t = 0; t < 8; ++t) {
            float val = fmaf(bf2f((unsigned short)v[t]), scv[t], shv[t]);
            acc[t] += val > 0.f ? val : 0.f;
        }
    }
    int cnt = end - beg;
    float inv = 1.f / (float)(cnt > 0 ? cnt : 1);
    float4 o0 = make_float4(acc[0] * inv, acc[1] * inv, acc[2] * inv, acc[3] * inv);
    float4 o1 = make_float4(acc[4] * inv, acc[5] * inv, acc[6] * inv, acc[7] * inv);
    float4* op = reinterpret_cast<float4*>(pooled + (size_t)g * HID + c0);
    op[0] = o0; op[1] = o1;
}

__global__ void mlp1_kernel(const float* __restrict__ pooled,
                            const float* __restrict__ w1, const float* __restrict__ b1,
                            float* __restrict__ h1) {
    __shared__ float row[HID];
    int g = blockIdx.x;
    int tid = threadIdx.x; // 256
    row[tid] = pooled[(size_t)g * HID + tid];
    row[tid + 256] = pooled[(size_t)g * HID + tid + 256];
    __syncthreads();
    float acc = 0.f;
    for (int c = 0; c < HID; ++c) acc += row[c] * w1[c * 256 + tid];
    float v = acc + b1[tid];
    h1[g * 256 + tid] = v > 0.f ? v : 0.f;
}

__global__ void mlp2_kernel(const float* __restrict__ h1, const float* __restrict__ w2,
                            const float* __restrict__ b2, float* __restrict__ out) {
    __shared__ float row[256];
    int g = blockIdx.x;
    int tid = threadIdx.x; // 64
    for (int j = tid; j < 256; j += 64) row[j] = h1[g * 256 + j];
    __syncthreads();
    if (tid < TARGETS) {
        float acc = 0.f;
        for (int j = 0; j < 256; ++j) acc += row[j] * w2[j * TARGETS + tid];
        out[g * TARGETS + tid] = acc + b2[tid];
    }
}

// ---------------------------------------------------------------------------
extern "C" void kernel_launch(void* const* d_in, const int* in_sizes, int n_in,
                              void* d_out, int out_size, void* d_ws, size_t ws_size,
                              hipStream_t stream) {
    const float* atom   = (const float*)d_in[0];
    const int*   ei     = (const int*)d_in[2];   // [2, N_EDGES]
    const int*   batch  = (const int*)d_in[3];
    const float* atom_w = (const float*)d_in[4];
    const float* atom_b = (const float*)d_in[5];
    const float* gat_w  = (const float*)d_in[6];
    const float* att_s  = (const float*)d_in[7];
    const float* att_d  = (const float*)d_in[8];
    const float* gat_b  = (const float*)d_in[9];
    const float* bn_g   = (const float*)d_in[10];
    const float* bn_b   = (const float*)d_in[11];
    const float* w1     = (const float*)d_in[12];
    const float* b1     = (const float*)d_in[13];
    const float* w2     = (const float*)d_in[14];
    const float* b2     = (const float*)d_in[15];
    float* out = (float*)d_out;

    const int ETOT = N_EDGES + N_NODES;

    char* ws = (char*)d_ws;
    size_t off = 0;
    auto alloc = [&](size_t bytes) {
        void* p = ws + off;
        off += (bytes + 255) & ~(size_t)255;
        return p;
    };
    __hip_bfloat16* xn  = (__hip_bfloat16*)alloc((size_t)N_NODES * HID * 2); // 51.2 MB
    __hip_bfloat16* xb  = (__hip_bfloat16*)alloc((size_t)N_NODES * HID * 2); // 51.2 MB
    __hip_bfloat16* hb  = (__hip_bfloat16*)alloc((size_t)N_NODES * HID * 2); // 51.2 MB
    __hip_bfloat16* Wt  = (__hip_bfloat16*)alloc((size_t)LAYERS * HID * HID * 2); // 3.1 MB
    __hip_bfloat16* Wt0 = (__hip_bfloat16*)alloc((size_t)HID * 128 * 2);          // 131 KB
    float* as_    = (float*)alloc((size_t)N_NODES * HEADS * 4);
    float* ad_    = (float*)alloc((size_t)N_NODES * HEADS * 4);
    int* counts   = (int*)alloc(N_NODES * 4);
    int* offsets  = (int*)alloc((N_NODES + 1) * 4);
    int* wp       = (int*)alloc(N_NODES * 4);
    int* csrc     = (int*)alloc(ETOT * 4);
    int* bsums    = (int*)alloc(64 * 4);
    int* gcounts  = (int*)alloc(N_GRAPHS * 4);
    int* goff     = (int*)alloc((N_GRAPHS + 1) * 4);
    float* part_s = (float*)alloc((size_t)NBINS * HID * 4);     // 256 KB
    float* part_q = (float*)alloc((size_t)NBINS * HID * 4);     // 256 KB
    float* bn_sc  = (float*)alloc(HID * 4);
    float* bn_sh  = (float*)alloc(HID * 4);
    float* pooled = (float*)alloc((size_t)N_GRAPHS * HID * 4);
    float* h1     = (float*)alloc((size_t)N_GRAPHS * 256 * 4);

    // ---- edge CSR build (by dst; self-loops appended; stores src/slot) ----
    hipMemsetAsync(counts, 0, N_NODES * 4, stream);
    count_kernel<<<(ETOT + 255) / 256, 256, 0, stream>>>(ei, counts);
    int nb = (N_NODES + 1023) / 1024;
    scan1_kernel<<<nb, 1024, 0, stream>>>(counts, offsets, bsums, N_NODES);
    scan2_kernel<<<1, 64, 0, stream>>>(bsums, nb);
    scan3_kernel<<<nb, 1024, 0, stream>>>(counts, offsets, bsums, wp, N_NODES);
    scatter_kernel<<<(ETOT + 255) / 256, 256, 0, stream>>>(ei, wp, csrc);

    // ---- graph offsets from sorted batch (count + scan, n=2000) ----
    hipMemsetAsync(gcounts, 0, N_GRAPHS * 4, stream);
    gcount_kernel<<<(N_NODES + 255) / 256, 256, 0, stream>>>(batch, gcounts);
    int nbg = (N_GRAPHS + 1023) / 1024;
    scan1_kernel<<<nbg, 1024, 0, stream>>>(gcounts, goff, bsums, N_GRAPHS);
    scan2_kernel<<<1, 64, 0, stream>>>(bsums, nbg);
    scan3_kernel<<<nbg, 1024, 0, stream>>>(gcounts, goff, bsums, wp, N_GRAPHS);

    // ---- weights: transpose + bf16 convert ----
    wtrans_kernel<<<dim3(HID / 32, HID / 32, LAYERS), dim3(32, 8), 0, stream>>>(gat_w, Wt);
    atomwt_kernel<<<(HID * 128 + 255) / 256, 256, 0, stream>>>(atom_w, Wt0);

    // ---- atom projection -> xn (bf16) via MFMA (K padded to 128) ----
    gemm_atom_kernel<<<dim3((N_NODES + 127) / 128, HID / 128), 256, 0, stream>>>(
        atom, Wt0, atom_b, xn, N_NODES);

    // ---- 6 GAT layers ----
    for (int l = 0; l < LAYERS; ++l) {
        gemm_mfma_kernel<<<dim3((N_NODES + 127) / 128, HID / 128), 256, 0, stream>>>(
            xn, Wt + (size_t)l * HID * HID, hb,
            att_s + l * HID, att_d + l * HID, as_, ad_, N_NODES);
        hipMemsetAsync(part_s, 0, (size_t)NBINS * HID * 4, stream);
        hipMemsetAsync(part_q, 0, (size_t)NBINS * HID * 4, stream);
        agg_kernel<<<N_NODES / 8, 512, 0, stream>>>(hb, as_, ad_, offsets, csrc,
                                                    gat_b + l * HID, xb, part_s, part_q);
        bn_prep_kernel<<<64, 512, 0, stream>>>(part_s, part_q, bn_g + l * HID, bn_b + l * HID,
                                               bn_sc, bn_sh, N_NODES);
        if (l < LAYERS - 1)
            bn_apply_kernel<<<(int)((size_t)N_NODES * HID / 8 / 256), 256, 0, stream>>>(
                xb, xn, bn_sc, bn_sh);
    }

    // ---- pool (wave/graph, BN+ReLU fused, atomic-free) + MLP head ----
    pool_bn_kernel<<<(N_GRAPHS + 3) / 4, 256, 0, stream>>>(xb, goff, bn_sc, bn_sh, pooled);
    mlp1_kernel<<<N_GRAPHS, 256, 0, stream>>>(pooled, w1, b1, h1);
    mlp2_kernel<<<N_GRAPHS, 64, 0, stream>>>(h1, w2, b2, out);
}

// Round 10
// 1014.773 us; speedup vs baseline: 4.7492x; 1.0888x over previous
//
#include <hip/hip_runtime.h>
#include <hip/hip_bf16.h>

// ---------------------------------------------------------------------------
// MolecularGNN: atom proj -> 6x (GATConv + BN + ReLU) -> mean pool -> MLP
// Round 10: gemm block widened to 128x256 (512 thr / 8 waves, each wave the
// same 64x64 sub-tile; acc unchanged). Halves A column-passes (4->2): R9
// showed FETCH 103MB vs 52MB ideal and dur == bytes/2.43TB/s. LDS 48KB.
// ---------------------------------------------------------------------------

#define N_NODES 50000
#define N_EDGES 150000
#define N_GRAPHS 2000
#define ATOM_DIM 100
#define HID 512
#define HEADS 8
#define HEAD_DIM 64
#define LAYERS 6
#define TARGETS 13
#define NBINS 128
#define BK 64

typedef __attribute__((ext_vector_type(8))) short bf16x8;
typedef __attribute__((ext_vector_type(4))) float f32x4;

__device__ __forceinline__ float lrelu(float v) { return v > 0.f ? v : 0.2f * v; }

__device__ __forceinline__ unsigned short f2bf(float v) {
    __hip_bfloat16 b = __float2bfloat16(v);
    return *reinterpret_cast<unsigned short*>(&b);
}
__device__ __forceinline__ float bf2f(unsigned short u) {
    unsigned int x = ((unsigned int)u) << 16;
    return __uint_as_float(x);
}

typedef __attribute__((address_space(3))) unsigned int lds_uint;
typedef __attribute__((address_space(1))) const unsigned int glob_uint;

__device__ __forceinline__ void gload_lds16(const void* g, void* l) {
    __builtin_amdgcn_global_load_lds((glob_uint*)g, (lds_uint*)l, 16, 0, 0);
}

// ---------------- weight transpose + bf16 convert (layer weights) ----------
__global__ void wtrans_kernel(const float* __restrict__ W, __hip_bfloat16* __restrict__ Wt) {
    __shared__ float t[32][33];
    int l = blockIdx.z;
    int k0 = blockIdx.x * 32, m0 = blockIdx.y * 32;
    const float* Wl = W + (size_t)l * HID * HID;
    __hip_bfloat16* Wtl = Wt + (size_t)l * HID * HID;
#pragma unroll
    for (int i = 0; i < 32; i += 8)
        t[threadIdx.y + i][threadIdx.x] = Wl[(size_t)(k0 + threadIdx.y + i) * HID + m0 + threadIdx.x];
    __syncthreads();
#pragma unroll
    for (int i = 0; i < 32; i += 8)
        Wtl[(size_t)(m0 + threadIdx.y + i) * HID + k0 + threadIdx.x] =
            __float2bfloat16(t[threadIdx.x][threadIdx.y + i]);
}

// ---------------- atom_w transpose: Wt0[m][k] = bf16(atom_w[k][m]), k pad 128
__global__ void atomwt_kernel(const float* __restrict__ aw, __hip_bfloat16* __restrict__ Wt0) {
    int idx = blockIdx.x * 256 + threadIdx.x; // 512*128 total
    if (idx >= HID * 128) return;
    int k = idx >> 9, m = idx & (HID - 1);
    float v = (k < ATOM_DIM) ? aw[(size_t)k * HID + m] : 0.f;
    Wt0[(size_t)m * 128 + k] = __float2bfloat16(v);
}

// ---------------- atom projection MFMA: xn[N,512] = bf16(atom) @ Wt0^T + b -
__launch_bounds__(256)
__global__ void gemm_atom_kernel(const float* __restrict__ A,
                                 const __hip_bfloat16* __restrict__ Bt,
                                 const float* __restrict__ bias,
                                 __hip_bfloat16* __restrict__ Cb, int N) {
    constexpr int KP = 128;
    constexpr int LDA = 40;
    __shared__ __align__(16) short As[128 * LDA];
    __shared__ __align__(16) short Bs[128 * LDA];
    const int tid = threadIdx.x;
    const int wave = tid >> 6, lane = tid & 63;
    const int row0 = blockIdx.x * 128, col0 = blockIdx.y * 128;
    const int wr = (wave >> 1) * 64, wc = (wave & 1) * 64;
    const int q = lane >> 4, r16 = lane & 15;
    f32x4 acc[4][4] = {};

    for (int k0 = 0; k0 < KP; k0 += 32) {
#pragma unroll
        for (int c = tid; c < 512; c += 256) {
            int rrow = c >> 2, koff = (c & 3) << 3;
            int grow = row0 + rrow;
            int kb = k0 + koff;
            float vv[8];
            if (grow < N && kb + 8 <= ATOM_DIM) {
                const float* ap = A + (size_t)grow * ATOM_DIM + kb;
                float4 v0 = *reinterpret_cast<const float4*>(ap);
                float4 v1 = *reinterpret_cast<const float4*>(ap + 4);
                vv[0] = v0.x; vv[1] = v0.y; vv[2] = v0.z; vv[3] = v0.w;
                vv[4] = v1.x; vv[5] = v1.y; vv[6] = v1.z; vv[7] = v1.w;
            } else {
#pragma unroll
                for (int t = 0; t < 8; ++t)
                    vv[t] = (grow < N && kb + t < ATOM_DIM) ? A[(size_t)grow * ATOM_DIM + kb + t] : 0.f;
            }
            ushort4 p0, p1;
            p0.x = f2bf(vv[0]); p0.y = f2bf(vv[1]); p0.z = f2bf(vv[2]); p0.w = f2bf(vv[3]);
            p1.x = f2bf(vv[4]); p1.y = f2bf(vv[5]); p1.z = f2bf(vv[6]); p1.w = f2bf(vv[7]);
            *reinterpret_cast<ushort4*>(&As[rrow * LDA + koff]) = p0;
            *reinterpret_cast<ushort4*>(&As[rrow * LDA + koff + 4]) = p1;
            float4 w = *reinterpret_cast<const float4*>(Bt + (size_t)(col0 + rrow) * KP + kb);
            *reinterpret_cast<float4*>(&Bs[rrow * LDA + koff]) = w;
        }
        __syncthreads();
        bf16x8 a[4], b[4];
#pragma unroll
        for (int i = 0; i < 4; ++i)
            a[i] = *reinterpret_cast<const bf16x8*>(&As[(wr + i * 16 + r16) * LDA + q * 8]);
#pragma unroll
        for (int j = 0; j < 4; ++j)
            b[j] = *reinterpret_cast<const bf16x8*>(&Bs[(wc + j * 16 + r16) * LDA + q * 8]);
#pragma unroll
        for (int i = 0; i < 4; ++i)
#pragma unroll
            for (int j = 0; j < 4; ++j)
                acc[i][j] = __builtin_amdgcn_mfma_f32_16x16x32_bf16(a[i], b[j], acc[i][j], 0, 0, 0);
        __syncthreads();
    }

#pragma unroll
    for (int i = 0; i < 4; ++i) {
#pragma unroll
        for (int rr = 0; rr < 4; ++rr) {
            int grow = row0 + wr + i * 16 + q * 4 + rr;
            if (grow >= N) continue;
#pragma unroll
            for (int j = 0; j < 4; ++j) {
                int col = col0 + wc + j * 16 + r16;
                Cb[(size_t)grow * HID + col] =
                    __float2bfloat16(acc[i][j][rr] + bias[col]);
            }
        }
    }
}

// ---------------- pure bf16 MFMA GEMM (m97 structure) + alpha epilogue -----
// 128x256 tile, 512 threads = 8 waves (each 64x64), BK=64,
// global_load_lds(16B) staging, XOR-swizzled LDS.
__launch_bounds__(512)
__global__ void gemm_mfma_kernel(const __hip_bfloat16* __restrict__ A,
                                 const __hip_bfloat16* __restrict__ Bt,
                                 __hip_bfloat16* __restrict__ Cb,
                                 const float* __restrict__ att_s,
                                 const float* __restrict__ att_d,
                                 float* __restrict__ as_out,
                                 float* __restrict__ ad_out,
                                 int N) {
    constexpr int K = HID;
    __shared__ __align__(16) short As[128 * BK];   // 16 KB
    __shared__ __align__(16) short Bs[256 * BK];   // 32 KB
    const int tid = threadIdx.x;
    const int wave = tid >> 6, lane = tid & 63;
    const int row0 = blockIdx.x * 128, col0 = blockIdx.y * 256;
    const int wr = (wave >> 2) * 64, wc = (wave & 3) * 64;
    const int q = lane >> 4, r16 = lane & 15;
    f32x4 acc[4][4] = {};

    // A staging: 1024 chunks; wave issues is in {0,1}: fc=(wave*2+is)*64+lane
    int arows[2], agchs[2];
#pragma unroll
    for (int is = 0; is < 2; ++is) {
        int fc = (wave * 2 + is) * 64 + lane;
        int row = fc >> 3;
        arows[is] = row;
        agchs[is] = (fc & 7) ^ (row & 7);
    }
    // B staging: 2048 chunks; wave issues is in {0..3}: fc=(wave*4+is)*64+lane
    int brows[4], bgchs[4];
#pragma unroll
    for (int is = 0; is < 4; ++is) {
        int fc = (wave * 4 + is) * 64 + lane;
        int row = fc >> 3;
        brows[is] = row;
        bgchs[is] = (fc & 7) ^ (row & 7);
    }

    for (int k0 = 0; k0 < K; k0 += BK) {
#pragma unroll
        for (int is = 0; is < 2; ++is) {
            int gra = row0 + arows[is]; if (gra > N - 1) gra = N - 1;
            gload_lds16(A + (size_t)gra * K + k0 + agchs[is] * 8, &As[(wave * 2 + is) * 512]);
        }
#pragma unroll
        for (int is = 0; is < 4; ++is) {
            gload_lds16(Bt + (size_t)(col0 + brows[is]) * K + k0 + bgchs[is] * 8,
                        &Bs[(wave * 4 + is) * 512]);
        }
        __syncthreads();
#pragma unroll
        for (int kk = 0; kk < 2; ++kk) {
            bf16x8 a[4], b[4];
#pragma unroll
            for (int i = 0; i < 4; ++i) {
                int row = wr + i * 16 + r16;
                int sw = (kk * 4 + q) ^ (row & 7);
                a[i] = *reinterpret_cast<const bf16x8*>(&As[row * BK + sw * 8]);
            }
#pragma unroll
            for (int j = 0; j < 4; ++j) {
                int row = wc + j * 16 + r16;
                int sw = (kk * 4 + q) ^ (row & 7);
                b[j] = *reinterpret_cast<const bf16x8*>(&Bs[row * BK + sw * 8]);
            }
#pragma unroll
            for (int i = 0; i < 4; ++i)
#pragma unroll
                for (int j = 0; j < 4; ++j)
                    acc[i][j] = __builtin_amdgcn_mfma_f32_16x16x32_bf16(a[i], b[j], acc[i][j], 0, 0, 0);
        }
        __syncthreads();
    }

    // C write (bf16). C/D layout: col = lane&15, row = (lane>>4)*4 + reg
#pragma unroll
    for (int i = 0; i < 4; ++i) {
#pragma unroll
        for (int rr = 0; rr < 4; ++rr) {
            int grow = row0 + wr + i * 16 + q * 4 + rr;
            if (grow >= N) continue;
#pragma unroll
            for (int j = 0; j < 4; ++j)
                Cb[(size_t)grow * HID + col0 + wc + j * 16 + r16] =
                    __float2bfloat16(acc[i][j][rr]);
        }
    }

    // Fused alpha: wave's 64 cols == one head
    const int head = (col0 + wc) >> 6;
    float avs[4], avd[4];
#pragma unroll
    for (int j = 0; j < 4; ++j) {
        avs[j] = att_s[col0 + wc + j * 16 + r16];
        avd[j] = att_d[col0 + wc + j * 16 + r16];
    }
#pragma unroll
    for (int i = 0; i < 4; ++i) {
#pragma unroll
        for (int rr = 0; rr < 4; ++rr) {
            float ss = 0.f, dd = 0.f;
#pragma unroll
            for (int j = 0; j < 4; ++j) {
                float v = acc[i][j][rr];
                ss += v * avs[j];
                dd += v * avd[j];
            }
#pragma unroll
            for (int off = 8; off > 0; off >>= 1) {
                ss += __shfl_xor(ss, off);
                dd += __shfl_xor(dd, off);
            }
            int grow = row0 + wr + i * 16 + q * 4 + rr;
            if (r16 == 0 && grow < N) {
                as_out[(size_t)grow * HEADS + head] = ss;
                ad_out[(size_t)grow * HEADS + head] = dd;
            }
        }
    }
}

// ---------------- generic count (edges+self-loops -> dst bins) -------------
__global__ void count_kernel(const int* __restrict__ ei, int* __restrict__ counts) {
    int e = blockIdx.x * blockDim.x + threadIdx.x;
    int tot = N_EDGES + N_NODES;
    if (e >= tot) return;
    int dst = e < N_EDGES ? ei[N_EDGES + e] : e - N_EDGES;
    atomicAdd(&counts[dst], 1);
}

__global__ void gcount_kernel(const int* __restrict__ batch, int* __restrict__ gc) {
    int i = blockIdx.x * blockDim.x + threadIdx.x;
    if (i < N_NODES) atomicAdd(&gc[batch[i]], 1);
}

__global__ void scan1_kernel(const int* __restrict__ counts, int* __restrict__ offsets,
                             int* __restrict__ bsums, int n) {
    __shared__ int tmp[1024];
    int tid = threadIdx.x;
    int gid = blockIdx.x * 1024 + tid;
    tmp[tid] = gid < n ? counts[gid] : 0;
    __syncthreads();
    for (int off = 1; off < 1024; off <<= 1) {
        int t = tid >= off ? tmp[tid - off] : 0;
        __syncthreads();
        tmp[tid] += t;
        __syncthreads();
    }
    if (gid < n) offsets[gid + 1] = tmp[tid];
    if (tid == 1023) bsums[blockIdx.x] = tmp[1023];
}

__global__ void scan2_kernel(int* bsums, int nb) {
    if (threadIdx.x == 0) {
        int s = 0;
        for (int i = 0; i < nb; ++i) { s += bsums[i]; bsums[i] = s; }
    }
}

__global__ void scan3_kernel(const int* __restrict__ counts, int* __restrict__ offsets,
                             const int* __restrict__ bsums, int* __restrict__ wp, int n) {
    int tid = threadIdx.x;
    int gid = blockIdx.x * 1024 + tid;
    if (gid == 0) offsets[0] = 0;
    if (gid >= n) return;
    int add = blockIdx.x > 0 ? bsums[blockIdx.x - 1] : 0;
    int v = offsets[gid + 1] + add;
    offsets[gid + 1] = v;
    wp[gid] = v - counts[gid];
}

__global__ void scatter_kernel(const int* __restrict__ ei, int* __restrict__ wp,
                               int* __restrict__ csrc) {
    int e = blockIdx.x * blockDim.x + threadIdx.x;
    int tot = N_EDGES + N_NODES;
    if (e >= tot) return;
    int src = e < N_EDGES ? ei[e] : e - N_EDGES;
    int dst = e < N_EDGES ? ei[N_EDGES + e] : e - N_EDGES;
    int pos = atomicAdd(&wp[dst], 1);
    csrc[pos] = src;
}

// ---------------- softmax-attention aggregation + fused BN stats -----------
__launch_bounds__(512)
__global__ void agg_kernel(const __hip_bfloat16* __restrict__ hb, const float* __restrict__ as,
                           const float* __restrict__ ad, const int* __restrict__ offsets,
                           const int* __restrict__ csrc, const float* __restrict__ bias,
                           __hip_bfloat16* __restrict__ outb,
                           float* __restrict__ ps, float* __restrict__ pq) {
    __shared__ float psum[8][HID];
    const int wave = threadIdx.x >> 6, lane = threadIdx.x & 63;
    const int i = blockIdx.x * 8 + wave;
    const int head = lane >> 3;
    const int c0 = lane << 3;
    const int beg = offsets[i];
    const int deg = offsets[i + 1] - beg;
    const float adv = ad[(size_t)i * HEADS + head];

    float a[8] = {};
    float den = 0.f;

    for (int e0 = 0; e0 < deg; e0 += 4) {
        int m = deg - e0; if (m > 4) m = 4;
        int s[4];
#pragma unroll
        for (int k = 0; k < 4; ++k) {
            int kk = k < m ? k : m - 1;
            s[k] = csrc[beg + e0 + kk];
        }
        float w[4];
#pragma unroll
        for (int k = 0; k < 4; ++k)
            w[k] = (k < m) ? __expf(lrelu(as[(size_t)s[k] * HEADS + head] + adv)) : 0.f;
#pragma unroll
        for (int k = 0; k < 4; ++k) {
            bf16x8 hv = *reinterpret_cast<const bf16x8*>(hb + (size_t)s[k] * HID + c0);
#pragma unroll
            for (int t = 0; t < 8; ++t)
                a[t] += w[k] * bf2f((unsigned short)hv[t]);
            den += w[k];
        }
    }
    float inv = 1.f / den;
    float o[8];
    const float4* bp = reinterpret_cast<const float4*>(bias + c0);
    float4 b0 = bp[0], b1 = bp[1];
    float bb[8] = {b0.x, b0.y, b0.z, b0.w, b1.x, b1.y, b1.z, b1.w};
    ushort4 p0, p1;
#pragma unroll
    for (int t = 0; t < 8; ++t) o[t] = a[t] * inv + bb[t];
    p0.x = f2bf(o[0]); p0.y = f2bf(o[1]); p0.z = f2bf(o[2]); p0.w = f2bf(o[3]);
    p1.x = f2bf(o[4]); p1.y = f2bf(o[5]); p1.z = f2bf(o[6]); p1.w = f2bf(o[7]);
    ushort4* op = reinterpret_cast<ushort4*>(outb + (size_t)i * HID + c0);
    op[0] = p0; op[1] = p1;

    // fused BN stats (from fp32 values)
#pragma unroll
    for (int t = 0; t < 8; ++t) psum[wave][c0 + t] = o[t];
    __syncthreads();
    int c = threadIdx.x; // 512 == HID
    float s = 0.f, q = 0.f;
#pragma unroll
    for (int w = 0; w < 8; ++w) {
        float v = psum[w][c];
        s += v; q += v * v;
    }
    int bin = blockIdx.x & (NBINS - 1);
    atomicAdd(&ps[bin * HID + c], s);
    atomicAdd(&pq[bin * HID + c], q);
}

// ---------------- BN prep: fold bins (wave per channel) --------------------
__global__ void bn_prep_kernel(const float* __restrict__ ps, const float* __restrict__ pq,
                               const float* __restrict__ gamma, const float* __restrict__ beta,
                               float* __restrict__ sc, float* __restrict__ sh, int n) {
    int wave = threadIdx.x >> 6, lane = threadIdx.x & 63;
    int c = blockIdx.x * 8 + wave;
    float s = ps[lane * HID + c] + ps[(lane + 64) * HID + c];
    float q = pq[lane * HID + c] + pq[(lane + 64) * HID + c];
#pragma unroll
    for (int off = 32; off > 0; off >>= 1) {
        s += __shfl_xor(s, off);
        q += __shfl_xor(q, off);
    }
    if (lane == 0) {
        float inv_n = 1.f / (float)n;
        float mu = s * inv_n;
        float var = q * inv_n - mu * mu;
        float g = rsqrtf(var + 1e-5f) * gamma[c];
        sc[c] = g;
        sh[c] = beta[c] - mu * g;
    }
}

// ---------------- standalone BN apply: xn = bf16(relu(xb*sc+sh)) -----------
__launch_bounds__(256)
__global__ void bn_apply_kernel(const __hip_bfloat16* __restrict__ xin,
                                __hip_bfloat16* __restrict__ xout,
                                const float* __restrict__ sc, const float* __restrict__ sh) {
    size_t idx = ((size_t)blockIdx.x * 256 + threadIdx.x) * 8;
    int c = (int)(idx & (HID - 1));
    bf16x8 v = *reinterpret_cast<const bf16x8*>(xin + idx);
    const float4* scp = reinterpret_cast<const float4*>(sc + c);
    const float4* shp = reinterpret_cast<const float4*>(sh + c);
    float4 s0 = scp[0], s1 = scp[1], h0 = shp[0], h1 = shp[1];
    float scv[8] = {s0.x, s0.y, s0.z, s0.w, s1.x, s1.y, s1.z, s1.w};
    float shv[8] = {h0.x, h0.y, h0.z, h0.w, h1.x, h1.y, h1.z, h1.w};
    bf16x8 o;
#pragma unroll
    for (int t = 0; t < 8; ++t) {
        float val = fmaf(bf2f((unsigned short)v[t]), scv[t], shv[t]);
        o[t] = (short)f2bf(val > 0.f ? val : 0.f);
    }
    *reinterpret_cast<bf16x8*>(xout + idx) = o;
}

// ---------------- pooling: wave per graph, no atomics ----------------------
__launch_bounds__(256)
__global__ void pool_bn_kernel(const __hip_bfloat16* __restrict__ xb,
                               const int* __restrict__ goff,
                               const float* __restrict__ sc, const float* __restrict__ sh,
                               float* __restrict__ pooled) {
    const int wave = threadIdx.x >> 6, lane = threadIdx.x & 63;
    const int g = blockIdx.x * 4 + wave;
    if (g >= N_GRAPHS) return;
    const int beg = goff[g], end = goff[g + 1];
    const int c0 = lane << 3;
    const float4* scp = reinterpret_cast<const float4*>(sc + c0);
    const float4* shp = reinterpret_cast<const float4*>(sh + c0);
    float4 s0 = scp[0], s1 = scp[1], h0 = shp[0], h1 = shp[1];
    float scv[8] = {s0.x, s0.y, s0.z, s0.w, s1.x, s1.y, s1.z, s1.w};
    float shv[8] = {h0.x, h0.y, h0.z, h0.w, h1.x, h1.y, h1.z, h1.w};
    float acc[8] = {};
    for (int i = beg; i < end; ++i) {
        bf16x8 v = *reinterpret_cast<const bf16x8*>(xb + (size_t)i * HID + c0);
#pragma unroll
        for (int t = 0; t < 8; ++t) {
            float val = fmaf(bf2f((unsigned short)v[t]), scv[t], shv[t]);
            acc[t] += val > 0.f ? val : 0.f;
        }
    }
    int cnt = end - beg;
    float inv = 1.f / (float)(cnt > 0 ? cnt : 1);
    float4 o0 = make_float4(acc[0] * inv, acc[1] * inv, acc[2] * inv, acc[3] * inv);
    float4 o1 = make_float4(acc[4] * inv, acc[5] * inv, acc[6] * inv, acc[7] * inv);
    float4* op = reinterpret_cast<float4*>(pooled + (size_t)g * HID + c0);
    op[0] = o0; op[1] = o1;
}

__global__ void mlp1_kernel(const float* __restrict__ pooled,
                            const float* __restrict__ w1, const float* __restrict__ b1,
                            float* __restrict__ h1) {
    __shared__ float row[HID];
    int g = blockIdx.x;
    int tid = threadIdx.x; // 256
    row[tid] = pooled[(size_t)g * HID + tid];
    row[tid + 256] = pooled[(size_t)g * HID + tid + 256];
    __syncthreads();
    float acc = 0.f;
    for (int c = 0; c < HID; ++c) acc += row[c] * w1[c * 256 + tid];
    float v = acc + b1[tid];
    h1[g * 256 + tid] = v > 0.f ? v : 0.f;
}

__global__ void mlp2_kernel(const float* __restrict__ h1, const float* __restrict__ w2,
                            const float* __restrict__ b2, float* __restrict__ out) {
    __shared__ float row[256];
    int g = blockIdx.x;
    int tid = threadIdx.x; // 64
    for (int j = tid; j < 256; j += 64) row[j] = h1[g * 256 + j];
    __syncthreads();
    if (tid < TARGETS) {
        float acc = 0.f;
        for (int j = 0; j < 256; ++j) acc += row[j] * w2[j * TARGETS + tid];
        out[g * TARGETS + tid] = acc + b2[tid];
    }
}

// ---------------------------------------------------------------------------
extern "C" void kernel_launch(void* const* d_in, const int* in_sizes, int n_in,
                              void* d_out, int out_size, void* d_ws, size_t ws_size,
                              hipStream_t stream) {
    const float* atom   = (const float*)d_in[0];
    const int*   ei     = (const int*)d_in[2];   // [2, N_EDGES]
    const int*   batch  = (const int*)d_in[3];
    const float* atom_w = (const float*)d_in[4];
    const float* atom_b = (const float*)d_in[5];
    const float* gat_w  = (const float*)d_in[6];
    const float* att_s  = (const float*)d_in[7];
    const float* att_d  = (const float*)d_in[8];
    const float* gat_b  = (const float*)d_in[9];
    const float* bn_g   = (const float*)d_in[10];
    const float* bn_b   = (const float*)d_in[11];
    const float* w1     = (const float*)d_in[12];
    const float* b1     = (const float*)d_in[13];
    const float* w2     = (const float*)d_in[14];
    const float* b2     = (const float*)d_in[15];
    float* out = (float*)d_out;

    const int ETOT = N_EDGES + N_NODES;

    char* ws = (char*)d_ws;
    size_t off = 0;
    auto alloc = [&](size_t bytes) {
        void* p = ws + off;
        off += (bytes + 255) & ~(size_t)255;
        return p;
    };
    __hip_bfloat16* xn  = (__hip_bfloat16*)alloc((size_t)N_NODES * HID * 2); // 51.2 MB
    __hip_bfloat16* xb  = (__hip_bfloat16*)alloc((size_t)N_NODES * HID * 2); // 51.2 MB
    __hip_bfloat16* hb  = (__hip_bfloat16*)alloc((size_t)N_NODES * HID * 2); // 51.2 MB
    __hip_bfloat16* Wt  = (__hip_bfloat16*)alloc((size_t)LAYERS * HID * HID * 2); // 3.1 MB
    __hip_bfloat16* Wt0 = (__hip_bfloat16*)alloc((size_t)HID * 128 * 2);          // 131 KB
    float* as_    = (float*)alloc((size_t)N_NODES * HEADS * 4);
    float* ad_    = (float*)alloc((size_t)N_NODES * HEADS * 4);
    int* counts   = (int*)alloc(N_NODES * 4);
    int* offsets  = (int*)alloc((N_NODES + 1) * 4);
    int* wp       = (int*)alloc(N_NODES * 4);
    int* csrc     = (int*)alloc(ETOT * 4);
    int* bsums    = (int*)alloc(64 * 4);
    int* gcounts  = (int*)alloc(N_GRAPHS * 4);
    int* goff     = (int*)alloc((N_GRAPHS + 1) * 4);
    float* part_s = (float*)alloc((size_t)NBINS * HID * 4);     // 256 KB
    float* part_q = (float*)alloc((size_t)NBINS * HID * 4);     // 256 KB
    float* bn_sc  = (float*)alloc(HID * 4);
    float* bn_sh  = (float*)alloc(HID * 4);
    float* pooled = (float*)alloc((size_t)N_GRAPHS * HID * 4);
    float* h1     = (float*)alloc((size_t)N_GRAPHS * 256 * 4);

    // ---- edge CSR build (by dst; self-loops appended; stores src/slot) ----
    hipMemsetAsync(counts, 0, N_NODES * 4, stream);
    count_kernel<<<(ETOT + 255) / 256, 256, 0, stream>>>(ei, counts);
    int nb = (N_NODES + 1023) / 1024;
    scan1_kernel<<<nb, 1024, 0, stream>>>(counts, offsets, bsums, N_NODES);
    scan2_kernel<<<1, 64, 0, stream>>>(bsums, nb);
    scan3_kernel<<<nb, 1024, 0, stream>>>(counts, offsets, bsums, wp, N_NODES);
    scatter_kernel<<<(ETOT + 255) / 256, 256, 0, stream>>>(ei, wp, csrc);

    // ---- graph offsets from sorted batch (count + scan, n=2000) ----
    hipMemsetAsync(gcounts, 0, N_GRAPHS * 4, stream);
    gcount_kernel<<<(N_NODES + 255) / 256, 256, 0, stream>>>(batch, gcounts);
    int nbg = (N_GRAPHS + 1023) / 1024;
    scan1_kernel<<<nbg, 1024, 0, stream>>>(gcounts, goff, bsums, N_GRAPHS);
    scan2_kernel<<<1, 64, 0, stream>>>(bsums, nbg);
    scan3_kernel<<<nbg, 1024, 0, stream>>>(gcounts, goff, bsums, wp, N_GRAPHS);

    // ---- weights: transpose + bf16 convert ----
    wtrans_kernel<<<dim3(HID / 32, HID / 32, LAYERS), dim3(32, 8), 0, stream>>>(gat_w, Wt);
    atomwt_kernel<<<(HID * 128 + 255) / 256, 256, 0, stream>>>(atom_w, Wt0);

    // ---- atom projection -> xn (bf16) via MFMA (K padded to 128) ----
    gemm_atom_kernel<<<dim3((N_NODES + 127) / 128, HID / 128), 256, 0, stream>>>(
        atom, Wt0, atom_b, xn, N_NODES);

    // ---- 6 GAT layers ----
    for (int l = 0; l < LAYERS; ++l) {
        gemm_mfma_kernel<<<dim3((N_NODES + 127) / 128, HID / 256), 512, 0, stream>>>(
            xn, Wt + (size_t)l * HID * HID, hb,
            att_s + l * HID, att_d + l * HID, as_, ad_, N_NODES);
        hipMemsetAsync(part_s, 0, (size_t)NBINS * HID * 4, stream);
        hipMemsetAsync(part_q, 0, (size_t)NBINS * HID * 4, stream);
        agg_kernel<<<N_NODES / 8, 512, 0, stream>>>(hb, as_, ad_, offsets, csrc,
                                                    gat_b + l * HID, xb, part_s, part_q);
        bn_prep_kernel<<<64, 512, 0, stream>>>(part_s, part_q, bn_g + l * HID, bn_b + l * HID,
                                               bn_sc, bn_sh, N_NODES);
        if (l < LAYERS - 1)
            bn_apply_kernel<<<(int)((size_t)N_NODES * HID / 8 / 256), 256, 0, stream>>>(
                xb, xn, bn_sc, bn_sh);
    }

    // ---- pool (wave/graph, BN+ReLU fused, atomic-free) + MLP head ----
    pool_bn_kernel<<<(N_GRAPHS + 3) / 4, 256, 0, stream>>>(xb, goff, bn_sc, bn_sh, pooled);
    mlp1_kernel<<<N_GRAPHS, 256, 0, stream>>>(pooled, w1, b1, h1);
    mlp2_kernel<<<N_GRAPHS, 64, 0, stream>>>(h1, w2, b2, out);
}

// Round 11
// 946.409 us; speedup vs baseline: 5.0923x; 1.0722x over previous
//
#include <hip/hip_runtime.h>
#include <hip/hip_bf16.h>

// ---------------------------------------------------------------------------
// MolecularGNN: atom proj -> 6x (GATConv + BN + ReLU) -> mean pool -> MLP
// Round 11: BN+ReLU fused into GEMM A-staging (VGPR ds_write path, fp32 BN
// math, same XOR-swizzled LDS layout; B stays global_load_lds). Removes the
// 5x bn_apply pass (103 MB RMW each) that existed only because
// global_load_lds can't transform. Layer 0 keeps full async staging.
// ---------------------------------------------------------------------------

#define N_NODES 50000
#define N_EDGES 150000
#define N_GRAPHS 2000
#define ATOM_DIM 100
#define HID 512
#define HEADS 8
#define HEAD_DIM 64
#define LAYERS 6
#define TARGETS 13
#define NBINS 128
#define BK 64

typedef __attribute__((ext_vector_type(8))) short bf16x8;
typedef __attribute__((ext_vector_type(4))) float f32x4;

__device__ __forceinline__ float lrelu(float v) { return v > 0.f ? v : 0.2f * v; }

__device__ __forceinline__ unsigned short f2bf(float v) {
    __hip_bfloat16 b = __float2bfloat16(v);
    return *reinterpret_cast<unsigned short*>(&b);
}
__device__ __forceinline__ float bf2f(unsigned short u) {
    unsigned int x = ((unsigned int)u) << 16;
    return __uint_as_float(x);
}

typedef __attribute__((address_space(3))) unsigned int lds_uint;
typedef __attribute__((address_space(1))) const unsigned int glob_uint;

__device__ __forceinline__ void gload_lds16(const void* g, void* l) {
    __builtin_amdgcn_global_load_lds((glob_uint*)g, (lds_uint*)l, 16, 0, 0);
}

// ---------------- weight transpose + bf16 convert (layer weights) ----------
__global__ void wtrans_kernel(const float* __restrict__ W, __hip_bfloat16* __restrict__ Wt) {
    __shared__ float t[32][33];
    int l = blockIdx.z;
    int k0 = blockIdx.x * 32, m0 = blockIdx.y * 32;
    const float* Wl = W + (size_t)l * HID * HID;
    __hip_bfloat16* Wtl = Wt + (size_t)l * HID * HID;
#pragma unroll
    for (int i = 0; i < 32; i += 8)
        t[threadIdx.y + i][threadIdx.x] = Wl[(size_t)(k0 + threadIdx.y + i) * HID + m0 + threadIdx.x];
    __syncthreads();
#pragma unroll
    for (int i = 0; i < 32; i += 8)
        Wtl[(size_t)(m0 + threadIdx.y + i) * HID + k0 + threadIdx.x] =
            __float2bfloat16(t[threadIdx.x][threadIdx.y + i]);
}

// ---------------- atom_w transpose: Wt0[m][k] = bf16(atom_w[k][m]), k pad 128
__global__ void atomwt_kernel(const float* __restrict__ aw, __hip_bfloat16* __restrict__ Wt0) {
    int idx = blockIdx.x * 256 + threadIdx.x; // 512*128 total
    if (idx >= HID * 128) return;
    int k = idx >> 9, m = idx & (HID - 1);
    float v = (k < ATOM_DIM) ? aw[(size_t)k * HID + m] : 0.f;
    Wt0[(size_t)m * 128 + k] = __float2bfloat16(v);
}

// ---------------- atom projection MFMA: xn[N,512] = bf16(atom) @ Wt0^T + b -
__launch_bounds__(256)
__global__ void gemm_atom_kernel(const float* __restrict__ A,
                                 const __hip_bfloat16* __restrict__ Bt,
                                 const float* __restrict__ bias,
                                 __hip_bfloat16* __restrict__ Cb, int N) {
    constexpr int KP = 128;
    constexpr int LDA = 40;
    __shared__ __align__(16) short As[128 * LDA];
    __shared__ __align__(16) short Bs[128 * LDA];
    const int tid = threadIdx.x;
    const int wave = tid >> 6, lane = tid & 63;
    const int row0 = blockIdx.x * 128, col0 = blockIdx.y * 128;
    const int wr = (wave >> 1) * 64, wc = (wave & 1) * 64;
    const int q = lane >> 4, r16 = lane & 15;
    f32x4 acc[4][4] = {};

    for (int k0 = 0; k0 < KP; k0 += 32) {
#pragma unroll
        for (int c = tid; c < 512; c += 256) {
            int rrow = c >> 2, koff = (c & 3) << 3;
            int grow = row0 + rrow;
            int kb = k0 + koff;
            float vv[8];
            if (grow < N && kb + 8 <= ATOM_DIM) {
                const float* ap = A + (size_t)grow * ATOM_DIM + kb;
                float4 v0 = *reinterpret_cast<const float4*>(ap);
                float4 v1 = *reinterpret_cast<const float4*>(ap + 4);
                vv[0] = v0.x; vv[1] = v0.y; vv[2] = v0.z; vv[3] = v0.w;
                vv[4] = v1.x; vv[5] = v1.y; vv[6] = v1.z; vv[7] = v1.w;
            } else {
#pragma unroll
                for (int t = 0; t < 8; ++t)
                    vv[t] = (grow < N && kb + t < ATOM_DIM) ? A[(size_t)grow * ATOM_DIM + kb + t] : 0.f;
            }
            ushort4 p0, p1;
            p0.x = f2bf(vv[0]); p0.y = f2bf(vv[1]); p0.z = f2bf(vv[2]); p0.w = f2bf(vv[3]);
            p1.x = f2bf(vv[4]); p1.y = f2bf(vv[5]); p1.z = f2bf(vv[6]); p1.w = f2bf(vv[7]);
            *reinterpret_cast<ushort4*>(&As[rrow * LDA + koff]) = p0;
            *reinterpret_cast<ushort4*>(&As[rrow * LDA + koff + 4]) = p1;
            float4 w = *reinterpret_cast<const float4*>(Bt + (size_t)(col0 + rrow) * KP + kb);
            *reinterpret_cast<float4*>(&Bs[rrow * LDA + koff]) = w;
        }
        __syncthreads();
        bf16x8 a[4], b[4];
#pragma unroll
        for (int i = 0; i < 4; ++i)
            a[i] = *reinterpret_cast<const bf16x8*>(&As[(wr + i * 16 + r16) * LDA + q * 8]);
#pragma unroll
        for (int j = 0; j < 4; ++j)
            b[j] = *reinterpret_cast<const bf16x8*>(&Bs[(wc + j * 16 + r16) * LDA + q * 8]);
#pragma unroll
        for (int i = 0; i < 4; ++i)
#pragma unroll
            for (int j = 0; j < 4; ++j)
                acc[i][j] = __builtin_amdgcn_mfma_f32_16x16x32_bf16(a[i], b[j], acc[i][j], 0, 0, 0);
        __syncthreads();
    }

#pragma unroll
    for (int i = 0; i < 4; ++i) {
#pragma unroll
        for (int rr = 0; rr < 4; ++rr) {
            int grow = row0 + wr + i * 16 + q * 4 + rr;
            if (grow >= N) continue;
#pragma unroll
            for (int j = 0; j < 4; ++j) {
                int col = col0 + wc + j * 16 + r16;
                Cb[(size_t)grow * HID + col] =
                    __float2bfloat16(acc[i][j][rr] + bias[col]);
            }
        }
    }
}

// ---------------- bf16 MFMA GEMM (m97 structure) + alpha epilogue ----------
// 128x256 tile, 512 threads = 8 waves, BK=64, XOR-swizzled LDS.
// HAS_BN=0: A via global_load_lds. HAS_BN=1: A via VGPR ds_write with fused
// fp32 relu(x*sc+sh) (same LDS layout). B always global_load_lds.
template <int HAS_BN>
__launch_bounds__(512)
__global__ void gemm_mfma_kernel(const __hip_bfloat16* __restrict__ A,
                                 const __hip_bfloat16* __restrict__ Bt,
                                 __hip_bfloat16* __restrict__ Cb,
                                 const float* __restrict__ bn_sc,
                                 const float* __restrict__ bn_sh,
                                 const float* __restrict__ att_s,
                                 const float* __restrict__ att_d,
                                 float* __restrict__ as_out,
                                 float* __restrict__ ad_out,
                                 int N) {
    constexpr int K = HID;
    __shared__ __align__(16) short As[128 * BK];   // 16 KB
    __shared__ __align__(16) short Bs[256 * BK];   // 32 KB
    __shared__ float scs[HID], shs[HID];
    const int tid = threadIdx.x;
    const int wave = tid >> 6, lane = tid & 63;
    const int row0 = blockIdx.x * 128, col0 = blockIdx.y * 256;
    const int wr = (wave >> 2) * 64, wc = (wave & 3) * 64;
    const int q = lane >> 4, r16 = lane & 15;
    f32x4 acc[4][4] = {};

    if (HAS_BN) {
        if (tid < HID) { scs[tid] = bn_sc[tid]; shs[tid] = bn_sh[tid]; }
        __syncthreads();
    }

    // A staging: 1024 chunks; wave issues is in {0,1}: fc=(wave*2+is)*64+lane
    int arows[2], agchs[2];
#pragma unroll
    for (int is = 0; is < 2; ++is) {
        int fc = (wave * 2 + is) * 64 + lane;
        int row = fc >> 3;
        arows[is] = row;
        agchs[is] = (fc & 7) ^ (row & 7);
    }
    // B staging: 2048 chunks; wave issues is in {0..3}
    int brows[4], bgchs[4];
#pragma unroll
    for (int is = 0; is < 4; ++is) {
        int fc = (wave * 4 + is) * 64 + lane;
        int row = fc >> 3;
        brows[is] = row;
        bgchs[is] = (fc & 7) ^ (row & 7);
    }

    for (int k0 = 0; k0 < K; k0 += BK) {
        if (!HAS_BN) {
#pragma unroll
            for (int is = 0; is < 2; ++is) {
                int gra = row0 + arows[is]; if (gra > N - 1) gra = N - 1;
                gload_lds16(A + (size_t)gra * K + k0 + agchs[is] * 8, &As[(wave * 2 + is) * 512]);
            }
        } else {
#pragma unroll
            for (int is = 0; is < 2; ++is) {
                int gra = row0 + arows[is]; if (gra > N - 1) gra = N - 1;
                int cc = k0 + agchs[is] * 8;
                bf16x8 v = *reinterpret_cast<const bf16x8*>(A + (size_t)gra * K + cc);
                bf16x8 o;
#pragma unroll
                for (int t = 0; t < 8; ++t) {
                    float val = fmaf(bf2f((unsigned short)v[t]), scs[cc + t], shs[cc + t]);
                    o[t] = (short)f2bf(val > 0.f ? val : 0.f);
                }
                // per-lane ds_write to the same lane-linear dest global_load_lds uses
                *reinterpret_cast<bf16x8*>(&As[((wave * 2 + is) * 64 + lane) * 8]) = o;
            }
        }
#pragma unroll
        for (int is = 0; is < 4; ++is) {
            gload_lds16(Bt + (size_t)(col0 + brows[is]) * K + k0 + bgchs[is] * 8,
                        &Bs[(wave * 4 + is) * 512]);
        }
        __syncthreads();
#pragma unroll
        for (int kk = 0; kk < 2; ++kk) {
            bf16x8 a[4], b[4];
#pragma unroll
            for (int i = 0; i < 4; ++i) {
                int row = wr + i * 16 + r16;
                int sw = (kk * 4 + q) ^ (row & 7);
                a[i] = *reinterpret_cast<const bf16x8*>(&As[row * BK + sw * 8]);
            }
#pragma unroll
            for (int j = 0; j < 4; ++j) {
                int row = wc + j * 16 + r16;
                int sw = (kk * 4 + q) ^ (row & 7);
                b[j] = *reinterpret_cast<const bf16x8*>(&Bs[row * BK + sw * 8]);
            }
#pragma unroll
            for (int i = 0; i < 4; ++i)
#pragma unroll
                for (int j = 0; j < 4; ++j)
                    acc[i][j] = __builtin_amdgcn_mfma_f32_16x16x32_bf16(a[i], b[j], acc[i][j], 0, 0, 0);
        }
        __syncthreads();
    }

    // C write (bf16). C/D layout: col = lane&15, row = (lane>>4)*4 + reg
#pragma unroll
    for (int i = 0; i < 4; ++i) {
#pragma unroll
        for (int rr = 0; rr < 4; ++rr) {
            int grow = row0 + wr + i * 16 + q * 4 + rr;
            if (grow >= N) continue;
#pragma unroll
            for (int j = 0; j < 4; ++j)
                Cb[(size_t)grow * HID + col0 + wc + j * 16 + r16] =
                    __float2bfloat16(acc[i][j][rr]);
        }
    }

    // Fused alpha: wave's 64 cols == one head
    const int head = (col0 + wc) >> 6;
    float avs[4], avd[4];
#pragma unroll
    for (int j = 0; j < 4; ++j) {
        avs[j] = att_s[col0 + wc + j * 16 + r16];
        avd[j] = att_d[col0 + wc + j * 16 + r16];
    }
#pragma unroll
    for (int i = 0; i < 4; ++i) {
#pragma unroll
        for (int rr = 0; rr < 4; ++rr) {
            float ss = 0.f, dd = 0.f;
#pragma unroll
            for (int j = 0; j < 4; ++j) {
                float v = acc[i][j][rr];
                ss += v * avs[j];
                dd += v * avd[j];
            }
#pragma unroll
            for (int off = 8; off > 0; off >>= 1) {
                ss += __shfl_xor(ss, off);
                dd += __shfl_xor(dd, off);
            }
            int grow = row0 + wr + i * 16 + q * 4 + rr;
            if (r16 == 0 && grow < N) {
                as_out[(size_t)grow * HEADS + head] = ss;
                ad_out[(size_t)grow * HEADS + head] = dd;
            }
        }
    }
}

// ---------------- generic count (edges+self-loops -> dst bins) -------------
__global__ void count_kernel(const int* __restrict__ ei, int* __restrict__ counts) {
    int e = blockIdx.x * blockDim.x + threadIdx.x;
    int tot = N_EDGES + N_NODES;
    if (e >= tot) return;
    int dst = e < N_EDGES ? ei[N_EDGES + e] : e - N_EDGES;
    atomicAdd(&counts[dst], 1);
}

__global__ void gcount_kernel(const int* __restrict__ batch, int* __restrict__ gc) {
    int i = blockIdx.x * blockDim.x + threadIdx.x;
    if (i < N_NODES) atomicAdd(&gc[batch[i]], 1);
}

__global__ void scan1_kernel(const int* __restrict__ counts, int* __restrict__ offsets,
                             int* __restrict__ bsums, int n) {
    __shared__ int tmp[1024];
    int tid = threadIdx.x;
    int gid = blockIdx.x * 1024 + tid;
    tmp[tid] = gid < n ? counts[gid] : 0;
    __syncthreads();
    for (int off = 1; off < 1024; off <<= 1) {
        int t = tid >= off ? tmp[tid - off] : 0;
        __syncthreads();
        tmp[tid] += t;
        __syncthreads();
    }
    if (gid < n) offsets[gid + 1] = tmp[tid];
    if (tid == 1023) bsums[blockIdx.x] = tmp[1023];
}

__global__ void scan2_kernel(int* bsums, int nb) {
    if (threadIdx.x == 0) {
        int s = 0;
        for (int i = 0; i < nb; ++i) { s += bsums[i]; bsums[i] = s; }
    }
}

__global__ void scan3_kernel(const int* __restrict__ counts, int* __restrict__ offsets,
                             const int* __restrict__ bsums, int* __restrict__ wp, int n) {
    int tid = threadIdx.x;
    int gid = blockIdx.x * 1024 + tid;
    if (gid == 0) offsets[0] = 0;
    if (gid >= n) return;
    int add = blockIdx.x > 0 ? bsums[blockIdx.x - 1] : 0;
    int v = offsets[gid + 1] + add;
    offsets[gid + 1] = v;
    wp[gid] = v - counts[gid];
}

__global__ void scatter_kernel(const int* __restrict__ ei, int* __restrict__ wp,
                               int* __restrict__ csrc) {
    int e = blockIdx.x * blockDim.x + threadIdx.x;
    int tot = N_EDGES + N_NODES;
    if (e >= tot) return;
    int src = e < N_EDGES ? ei[e] : e - N_EDGES;
    int dst = e < N_EDGES ? ei[N_EDGES + e] : e - N_EDGES;
    int pos = atomicAdd(&wp[dst], 1);
    csrc[pos] = src;
}

// ---------------- softmax-attention aggregation + fused BN stats -----------
__launch_bounds__(512)
__global__ void agg_kernel(const __hip_bfloat16* __restrict__ hb, const float* __restrict__ as,
                           const float* __restrict__ ad, const int* __restrict__ offsets,
                           const int* __restrict__ csrc, const float* __restrict__ bias,
                           __hip_bfloat16* __restrict__ outb,
                           float* __restrict__ ps, float* __restrict__ pq) {
    __shared__ float psum[8][HID];
    const int wave = threadIdx.x >> 6, lane = threadIdx.x & 63;
    const int i = blockIdx.x * 8 + wave;
    const int head = lane >> 3;
    const int c0 = lane << 3;
    const int beg = offsets[i];
    const int deg = offsets[i + 1] - beg;
    const float adv = ad[(size_t)i * HEADS + head];

    float a[8] = {};
    float den = 0.f;

    for (int e0 = 0; e0 < deg; e0 += 4) {
        int m = deg - e0; if (m > 4) m = 4;
        int s[4];
#pragma unroll
        for (int k = 0; k < 4; ++k) {
            int kk = k < m ? k : m - 1;
            s[k] = csrc[beg + e0 + kk];
        }
        float w[4];
#pragma unroll
        for (int k = 0; k < 4; ++k)
            w[k] = (k < m) ? __expf(lrelu(as[(size_t)s[k] * HEADS + head] + adv)) : 0.f;
#pragma unroll
        for (int k = 0; k < 4; ++k) {
            bf16x8 hv = *reinterpret_cast<const bf16x8*>(hb + (size_t)s[k] * HID + c0);
#pragma unroll
            for (int t = 0; t < 8; ++t)
                a[t] += w[k] * bf2f((unsigned short)hv[t]);
            den += w[k];
        }
    }
    float inv = 1.f / den;
    float o[8];
    const float4* bp = reinterpret_cast<const float4*>(bias + c0);
    float4 b0 = bp[0], b1 = bp[1];
    float bb[8] = {b0.x, b0.y, b0.z, b0.w, b1.x, b1.y, b1.z, b1.w};
    ushort4 p0, p1;
#pragma unroll
    for (int t = 0; t < 8; ++t) o[t] = a[t] * inv + bb[t];
    p0.x = f2bf(o[0]); p0.y = f2bf(o[1]); p0.z = f2bf(o[2]); p0.w = f2bf(o[3]);
    p1.x = f2bf(o[4]); p1.y = f2bf(o[5]); p1.z = f2bf(o[6]); p1.w = f2bf(o[7]);
    ushort4* op = reinterpret_cast<ushort4*>(outb + (size_t)i * HID + c0);
    op[0] = p0; op[1] = p1;

    // fused BN stats (from fp32 values)
#pragma unroll
    for (int t = 0; t < 8; ++t) psum[wave][c0 + t] = o[t];
    __syncthreads();
    int c = threadIdx.x; // 512 == HID
    float s = 0.f, q = 0.f;
#pragma unroll
    for (int w = 0; w < 8; ++w) {
        float v = psum[w][c];
        s += v; q += v * v;
    }
    int bin = blockIdx.x & (NBINS - 1);
    atomicAdd(&ps[bin * HID + c], s);
    atomicAdd(&pq[bin * HID + c], q);
}

// ---------------- BN prep: fold bins (wave per channel) --------------------
__global__ void bn_prep_kernel(const float* __restrict__ ps, const float* __restrict__ pq,
                               const float* __restrict__ gamma, const float* __restrict__ beta,
                               float* __restrict__ sc, float* __restrict__ sh, int n) {
    int wave = threadIdx.x >> 6, lane = threadIdx.x & 63;
    int c = blockIdx.x * 8 + wave;
    float s = ps[lane * HID + c] + ps[(lane + 64) * HID + c];
    float q = pq[lane * HID + c] + pq[(lane + 64) * HID + c];
#pragma unroll
    for (int off = 32; off > 0; off >>= 1) {
        s += __shfl_xor(s, off);
        q += __shfl_xor(q, off);
    }
    if (lane == 0) {
        float inv_n = 1.f / (float)n;
        float mu = s * inv_n;
        float var = q * inv_n - mu * mu;
        float g = rsqrtf(var + 1e-5f) * gamma[c];
        sc[c] = g;
        sh[c] = beta[c] - mu * g;
    }
}

// ---------------- pooling: wave per graph, no atomics ----------------------
__launch_bounds__(256)
__global__ void pool_bn_kernel(const __hip_bfloat16* __restrict__ xb,
                               const int* __restrict__ goff,
                               const float* __restrict__ sc, const float* __restrict__ sh,
                               float* __restrict__ pooled) {
    const int wave = threadIdx.x >> 6, lane = threadIdx.x & 63;
    const int g = blockIdx.x * 4 + wave;
    if (g >= N_GRAPHS) return;
    const int beg = goff[g], end = goff[g + 1];
    const int c0 = lane << 3;
    const float4* scp = reinterpret_cast<const float4*>(sc + c0);
    const float4* shp = reinterpret_cast<const float4*>(sh + c0);
    float4 s0 = scp[0], s1 = scp[1], h0 = shp[0], h1 = shp[1];
    float scv[8] = {s0.x, s0.y, s0.z, s0.w, s1.x, s1.y, s1.z, s1.w};
    float shv[8] = {h0.x, h0.y, h0.z, h0.w, h1.x, h1.y, h1.z, h1.w};
    float acc[8] = {};
    for (int i = beg; i < end; ++i) {
        bf16x8 v = *reinterpret_cast<const bf16x8*>(xb + (size_t)i * HID + c0);
#pragma unroll
        for (int t = 0; t < 8; ++t) {
            float val = fmaf(bf2f((unsigned short)v[t]), scv[t], shv[t]);
            acc[t] += val > 0.f ? val : 0.f;
        }
    }
    int cnt = end - beg;
    float inv = 1.f / (float)(cnt > 0 ? cnt : 1);
    float4 o0 = make_float4(acc[0] * inv, acc[1] * inv, acc[2] * inv, acc[3] * inv);
    float4 o1 = make_float4(acc[4] * inv, acc[5] * inv, acc[6] * inv, acc[7] * inv);
    float4* op = reinterpret_cast<float4*>(pooled + (size_t)g * HID + c0);
    op[0] = o0; op[1] = o1;
}

__global__ void mlp1_kernel(const float* __restrict__ pooled,
                            const float* __restrict__ w1, const float* __restrict__ b1,
                            float* __restrict__ h1) {
    __shared__ float row[HID];
    int g = blockIdx.x;
    int tid = threadIdx.x; // 256
    row[tid] = pooled[(size_t)g * HID + tid];
    row[tid + 256] = pooled[(size_t)g * HID + tid + 256];
    __syncthreads();
    float acc = 0.f;
    for (int c = 0; c < HID; ++c) acc += row[c] * w1[c * 256 + tid];
    float v = acc + b1[tid];
    h1[g * 256 + tid] = v > 0.f ? v : 0.f;
}

__global__ void mlp2_kernel(const float* __restrict__ h1, const float* __restrict__ w2,
                            const float* __restrict__ b2, float* __restrict__ out) {
    __shared__ float row[256];
    int g = blockIdx.x;
    int tid = threadIdx.x; // 64
    for (int j = tid; j < 256; j += 64) row[j] = h1[g * 256 + j];
    __syncthreads();
    if (tid < TARGETS) {
        float acc = 0.f;
        for (int j = 0; j < 256; ++j) acc += row[j] * w2[j * TARGETS + tid];
        out[g * TARGETS + tid] = acc + b2[tid];
    }
}

// ---------------------------------------------------------------------------
extern "C" void kernel_launch(void* const* d_in, const int* in_sizes, int n_in,
                              void* d_out, int out_size, void* d_ws, size_t ws_size,
                              hipStream_t stream) {
    const float* atom   = (const float*)d_in[0];
    const int*   ei     = (const int*)d_in[2];   // [2, N_EDGES]
    const int*   batch  = (const int*)d_in[3];
    const float* atom_w = (const float*)d_in[4];
    const float* atom_b = (const float*)d_in[5];
    const float* gat_w  = (const float*)d_in[6];
    const float* att_s  = (const float*)d_in[7];
    const float* att_d  = (const float*)d_in[8];
    const float* gat_b  = (const float*)d_in[9];
    const float* bn_g   = (const float*)d_in[10];
    const float* bn_b   = (const float*)d_in[11];
    const float* w1     = (const float*)d_in[12];
    const float* b1     = (const float*)d_in[13];
    const float* w2     = (const float*)d_in[14];
    const float* b2     = (const float*)d_in[15];
    float* out = (float*)d_out;

    const int ETOT = N_EDGES + N_NODES;

    char* ws = (char*)d_ws;
    size_t off = 0;
    auto alloc = [&](size_t bytes) {
        void* p = ws + off;
        off += (bytes + 255) & ~(size_t)255;
        return p;
    };
    __hip_bfloat16* xn  = (__hip_bfloat16*)alloc((size_t)N_NODES * HID * 2); // 51.2 MB (atom out)
    __hip_bfloat16* xb  = (__hip_bfloat16*)alloc((size_t)N_NODES * HID * 2); // 51.2 MB (agg out, pre-BN)
    __hip_bfloat16* hb  = (__hip_bfloat16*)alloc((size_t)N_NODES * HID * 2); // 51.2 MB
    __hip_bfloat16* Wt  = (__hip_bfloat16*)alloc((size_t)LAYERS * HID * HID * 2); // 3.1 MB
    __hip_bfloat16* Wt0 = (__hip_bfloat16*)alloc((size_t)HID * 128 * 2);          // 131 KB
    float* as_    = (float*)alloc((size_t)N_NODES * HEADS * 4);
    float* ad_    = (float*)alloc((size_t)N_NODES * HEADS * 4);
    int* counts   = (int*)alloc(N_NODES * 4);
    int* offsets  = (int*)alloc((N_NODES + 1) * 4);
    int* wp       = (int*)alloc(N_NODES * 4);
    int* csrc     = (int*)alloc(ETOT * 4);
    int* bsums    = (int*)alloc(64 * 4);
    int* gcounts  = (int*)alloc(N_GRAPHS * 4);
    int* goff     = (int*)alloc((N_GRAPHS + 1) * 4);
    float* part_s = (float*)alloc((size_t)NBINS * HID * 4);     // 256 KB (contiguous with part_q)
    float* part_q = (float*)alloc((size_t)NBINS * HID * 4);     // 256 KB
    float* bn_sc  = (float*)alloc(HID * 4);
    float* bn_sh  = (float*)alloc(HID * 4);
    float* pooled = (float*)alloc((size_t)N_GRAPHS * HID * 4);
    float* h1     = (float*)alloc((size_t)N_GRAPHS * 256 * 4);

    // ---- edge CSR build (by dst; self-loops appended; stores src/slot) ----
    hipMemsetAsync(counts, 0, N_NODES * 4, stream);
    count_kernel<<<(ETOT + 255) / 256, 256, 0, stream>>>(ei, counts);
    int nb = (N_NODES + 1023) / 1024;
    scan1_kernel<<<nb, 1024, 0, stream>>>(counts, offsets, bsums, N_NODES);
    scan2_kernel<<<1, 64, 0, stream>>>(bsums, nb);
    scan3_kernel<<<nb, 1024, 0, stream>>>(counts, offsets, bsums, wp, N_NODES);
    scatter_kernel<<<(ETOT + 255) / 256, 256, 0, stream>>>(ei, wp, csrc);

    // ---- graph offsets from sorted batch (count + scan, n=2000) ----
    hipMemsetAsync(gcounts, 0, N_GRAPHS * 4, stream);
    gcount_kernel<<<(N_NODES + 255) / 256, 256, 0, stream>>>(batch, gcounts);
    int nbg = (N_GRAPHS + 1023) / 1024;
    scan1_kernel<<<nbg, 1024, 0, stream>>>(gcounts, goff, bsums, N_GRAPHS);
    scan2_kernel<<<1, 64, 0, stream>>>(bsums, nbg);
    scan3_kernel<<<nbg, 1024, 0, stream>>>(gcounts, goff, bsums, wp, N_GRAPHS);

    // ---- weights: transpose + bf16 convert ----
    wtrans_kernel<<<dim3(HID / 32, HID / 32, LAYERS), dim3(32, 8), 0, stream>>>(gat_w, Wt);
    atomwt_kernel<<<(HID * 128 + 255) / 256, 256, 0, stream>>>(atom_w, Wt0);

    // ---- atom projection -> xn (bf16) via MFMA (K padded to 128) ----
    gemm_atom_kernel<<<dim3((N_NODES + 127) / 128, HID / 128), 256, 0, stream>>>(
        atom, Wt0, atom_b, xn, N_NODES);

    // ---- 6 GAT layers ----
    dim3 ggrid((N_NODES + 127) / 128, HID / 256);
    for (int l = 0; l < LAYERS; ++l) {
        if (l == 0)
            gemm_mfma_kernel<0><<<ggrid, 512, 0, stream>>>(
                xn, Wt, hb, nullptr, nullptr,
                att_s, att_d, as_, ad_, N_NODES);
        else
            gemm_mfma_kernel<1><<<ggrid, 512, 0, stream>>>(
                xb, Wt + (size_t)l * HID * HID, hb, bn_sc, bn_sh,
                att_s + l * HID, att_d + l * HID, as_, ad_, N_NODES);
        hipMemsetAsync(part_s, 0, (size_t)2 * NBINS * HID * 4, stream); // part_s+part_q contiguous
        agg_kernel<<<N_NODES / 8, 512, 0, stream>>>(hb, as_, ad_, offsets, csrc,
                                                    gat_b + l * HID, xb, part_s, part_q);
        bn_prep_kernel<<<64, 512, 0, stream>>>(part_s, part_q, bn_g + l * HID, bn_b + l * HID,
                                               bn_sc, bn_sh, N_NODES);
    }

    // ---- pool (wave/graph, BN+ReLU fused, atomic-free) + MLP head ----
    pool_bn_kernel<<<(N_GRAPHS + 3) / 4, 256, 0, stream>>>(xb, goff, bn_sc, bn_sh, pooled);
    mlp1_kernel<<<N_GRAPHS, 256, 0, stream>>>(pooled, w1, b1, h1);
    mlp2_kernel<<<N_GRAPHS, 64, 0, stream>>>(h1, w2, b2, out);
}

// Round 12
// 904.715 us; speedup vs baseline: 5.3270x; 1.0461x over previous
//
#include <hip/hip_runtime.h>
#include <hip/hip_bf16.h>

// ---------------------------------------------------------------------------
// MolecularGNN: atom proj -> 6x (GATConv + BN + ReLU) -> mean pool -> MLP
// Round 12: consolidation. (a) agg processes 16 nodes/block (2/wave) ->
// halves BN-stat atomic write-through (R11: 25.6MB of WRITE was atomics);
// (b) bn_prep zeroes bins after folding -> kills 6 per-layer memsets;
// (c) one contiguous setup memset; count_kernel also bins graph counts.
// ---------------------------------------------------------------------------

#define N_NODES 50000
#define N_EDGES 150000
#define N_GRAPHS 2000
#define ATOM_DIM 100
#define HID 512
#define HEADS 8
#define HEAD_DIM 64
#define LAYERS 6
#define TARGETS 13
#define NBINS 128
#define BK 64

typedef __attribute__((ext_vector_type(8))) short bf16x8;
typedef __attribute__((ext_vector_type(4))) float f32x4;

__device__ __forceinline__ float lrelu(float v) { return v > 0.f ? v : 0.2f * v; }

__device__ __forceinline__ unsigned short f2bf(float v) {
    __hip_bfloat16 b = __float2bfloat16(v);
    return *reinterpret_cast<unsigned short*>(&b);
}
__device__ __forceinline__ float bf2f(unsigned short u) {
    unsigned int x = ((unsigned int)u) << 16;
    return __uint_as_float(x);
}

typedef __attribute__((address_space(3))) unsigned int lds_uint;
typedef __attribute__((address_space(1))) const unsigned int glob_uint;

__device__ __forceinline__ void gload_lds16(const void* g, void* l) {
    __builtin_amdgcn_global_load_lds((glob_uint*)g, (lds_uint*)l, 16, 0, 0);
}

// ---------------- weight transpose + bf16 convert (layer weights) ----------
__global__ void wtrans_kernel(const float* __restrict__ W, __hip_bfloat16* __restrict__ Wt) {
    __shared__ float t[32][33];
    int l = blockIdx.z;
    int k0 = blockIdx.x * 32, m0 = blockIdx.y * 32;
    const float* Wl = W + (size_t)l * HID * HID;
    __hip_bfloat16* Wtl = Wt + (size_t)l * HID * HID;
#pragma unroll
    for (int i = 0; i < 32; i += 8)
        t[threadIdx.y + i][threadIdx.x] = Wl[(size_t)(k0 + threadIdx.y + i) * HID + m0 + threadIdx.x];
    __syncthreads();
#pragma unroll
    for (int i = 0; i < 32; i += 8)
        Wtl[(size_t)(m0 + threadIdx.y + i) * HID + k0 + threadIdx.x] =
            __float2bfloat16(t[threadIdx.x][threadIdx.y + i]);
}

// ---------------- atom_w transpose: Wt0[m][k] = bf16(atom_w[k][m]), k pad 128
__global__ void atomwt_kernel(const float* __restrict__ aw, __hip_bfloat16* __restrict__ Wt0) {
    int idx = blockIdx.x * 256 + threadIdx.x; // 512*128 total
    if (idx >= HID * 128) return;
    int k = idx >> 9, m = idx & (HID - 1);
    float v = (k < ATOM_DIM) ? aw[(size_t)k * HID + m] : 0.f;
    Wt0[(size_t)m * 128 + k] = __float2bfloat16(v);
}

// ---------------- atom projection MFMA: xn[N,512] = bf16(atom) @ Wt0^T + b -
__launch_bounds__(256)
__global__ void gemm_atom_kernel(const float* __restrict__ A,
                                 const __hip_bfloat16* __restrict__ Bt,
                                 const float* __restrict__ bias,
                                 __hip_bfloat16* __restrict__ Cb, int N) {
    constexpr int KP = 128;
    constexpr int LDA = 40;
    __shared__ __align__(16) short As[128 * LDA];
    __shared__ __align__(16) short Bs[128 * LDA];
    const int tid = threadIdx.x;
    const int wave = tid >> 6, lane = tid & 63;
    const int row0 = blockIdx.x * 128, col0 = blockIdx.y * 128;
    const int wr = (wave >> 1) * 64, wc = (wave & 1) * 64;
    const int q = lane >> 4, r16 = lane & 15;
    f32x4 acc[4][4] = {};

    for (int k0 = 0; k0 < KP; k0 += 32) {
#pragma unroll
        for (int c = tid; c < 512; c += 256) {
            int rrow = c >> 2, koff = (c & 3) << 3;
            int grow = row0 + rrow;
            int kb = k0 + koff;
            float vv[8];
            if (grow < N && kb + 8 <= ATOM_DIM) {
                const float* ap = A + (size_t)grow * ATOM_DIM + kb;
                float4 v0 = *reinterpret_cast<const float4*>(ap);
                float4 v1 = *reinterpret_cast<const float4*>(ap + 4);
                vv[0] = v0.x; vv[1] = v0.y; vv[2] = v0.z; vv[3] = v0.w;
                vv[4] = v1.x; vv[5] = v1.y; vv[6] = v1.z; vv[7] = v1.w;
            } else {
#pragma unroll
                for (int t = 0; t < 8; ++t)
                    vv[t] = (grow < N && kb + t < ATOM_DIM) ? A[(size_t)grow * ATOM_DIM + kb + t] : 0.f;
            }
            ushort4 p0, p1;
            p0.x = f2bf(vv[0]); p0.y = f2bf(vv[1]); p0.z = f2bf(vv[2]); p0.w = f2bf(vv[3]);
            p1.x = f2bf(vv[4]); p1.y = f2bf(vv[5]); p1.z = f2bf(vv[6]); p1.w = f2bf(vv[7]);
            *reinterpret_cast<ushort4*>(&As[rrow * LDA + koff]) = p0;
            *reinterpret_cast<ushort4*>(&As[rrow * LDA + koff + 4]) = p1;
            float4 w = *reinterpret_cast<const float4*>(Bt + (size_t)(col0 + rrow) * KP + kb);
            *reinterpret_cast<float4*>(&Bs[rrow * LDA + koff]) = w;
        }
        __syncthreads();
        bf16x8 a[4], b[4];
#pragma unroll
        for (int i = 0; i < 4; ++i)
            a[i] = *reinterpret_cast<const bf16x8*>(&As[(wr + i * 16 + r16) * LDA + q * 8]);
#pragma unroll
        for (int j = 0; j < 4; ++j)
            b[j] = *reinterpret_cast<const bf16x8*>(&Bs[(wc + j * 16 + r16) * LDA + q * 8]);
#pragma unroll
        for (int i = 0; i < 4; ++i)
#pragma unroll
            for (int j = 0; j < 4; ++j)
                acc[i][j] = __builtin_amdgcn_mfma_f32_16x16x32_bf16(a[i], b[j], acc[i][j], 0, 0, 0);
        __syncthreads();
    }

#pragma unroll
    for (int i = 0; i < 4; ++i) {
#pragma unroll
        for (int rr = 0; rr < 4; ++rr) {
            int grow = row0 + wr + i * 16 + q * 4 + rr;
            if (grow >= N) continue;
#pragma unroll
            for (int j = 0; j < 4; ++j) {
                int col = col0 + wc + j * 16 + r16;
                Cb[(size_t)grow * HID + col] =
                    __float2bfloat16(acc[i][j][rr] + bias[col]);
            }
        }
    }
}

// ---------------- bf16 MFMA GEMM (m97 structure) + alpha epilogue ----------
// 128x256 tile, 512 threads = 8 waves, BK=64, XOR-swizzled LDS.
// HAS_BN=0: A via global_load_lds. HAS_BN=1: A via VGPR ds_write with fused
// fp32 relu(x*sc+sh). B always global_load_lds.
template <int HAS_BN>
__launch_bounds__(512)
__global__ void gemm_mfma_kernel(const __hip_bfloat16* __restrict__ A,
                                 const __hip_bfloat16* __restrict__ Bt,
                                 __hip_bfloat16* __restrict__ Cb,
                                 const float* __restrict__ bn_sc,
                                 const float* __restrict__ bn_sh,
                                 const float* __restrict__ att_s,
                                 const float* __restrict__ att_d,
                                 float* __restrict__ as_out,
                                 float* __restrict__ ad_out,
                                 int N) {
    constexpr int K = HID;
    __shared__ __align__(16) short As[128 * BK];   // 16 KB
    __shared__ __align__(16) short Bs[256 * BK];   // 32 KB
    __shared__ float scs[HID], shs[HID];
    const int tid = threadIdx.x;
    const int wave = tid >> 6, lane = tid & 63;
    const int row0 = blockIdx.x * 128, col0 = blockIdx.y * 256;
    const int wr = (wave >> 2) * 64, wc = (wave & 3) * 64;
    const int q = lane >> 4, r16 = lane & 15;
    f32x4 acc[4][4] = {};

    if (HAS_BN) {
        if (tid < HID) { scs[tid] = bn_sc[tid]; shs[tid] = bn_sh[tid]; }
        __syncthreads();
    }

    int arows[2], agchs[2];
#pragma unroll
    for (int is = 0; is < 2; ++is) {
        int fc = (wave * 2 + is) * 64 + lane;
        int row = fc >> 3;
        arows[is] = row;
        agchs[is] = (fc & 7) ^ (row & 7);
    }
    int brows[4], bgchs[4];
#pragma unroll
    for (int is = 0; is < 4; ++is) {
        int fc = (wave * 4 + is) * 64 + lane;
        int row = fc >> 3;
        brows[is] = row;
        bgchs[is] = (fc & 7) ^ (row & 7);
    }

    for (int k0 = 0; k0 < K; k0 += BK) {
        if (!HAS_BN) {
#pragma unroll
            for (int is = 0; is < 2; ++is) {
                int gra = row0 + arows[is]; if (gra > N - 1) gra = N - 1;
                gload_lds16(A + (size_t)gra * K + k0 + agchs[is] * 8, &As[(wave * 2 + is) * 512]);
            }
        } else {
#pragma unroll
            for (int is = 0; is < 2; ++is) {
                int gra = row0 + arows[is]; if (gra > N - 1) gra = N - 1;
                int cc = k0 + agchs[is] * 8;
                bf16x8 v = *reinterpret_cast<const bf16x8*>(A + (size_t)gra * K + cc);
                bf16x8 o;
#pragma unroll
                for (int t = 0; t < 8; ++t) {
                    float val = fmaf(bf2f((unsigned short)v[t]), scs[cc + t], shs[cc + t]);
                    o[t] = (short)f2bf(val > 0.f ? val : 0.f);
                }
                *reinterpret_cast<bf16x8*>(&As[((wave * 2 + is) * 64 + lane) * 8]) = o;
            }
        }
#pragma unroll
        for (int is = 0; is < 4; ++is) {
            gload_lds16(Bt + (size_t)(col0 + brows[is]) * K + k0 + bgchs[is] * 8,
                        &Bs[(wave * 4 + is) * 512]);
        }
        __syncthreads();
#pragma unroll
        for (int kk = 0; kk < 2; ++kk) {
            bf16x8 a[4], b[4];
#pragma unroll
            for (int i = 0; i < 4; ++i) {
                int row = wr + i * 16 + r16;
                int sw = (kk * 4 + q) ^ (row & 7);
                a[i] = *reinterpret_cast<const bf16x8*>(&As[row * BK + sw * 8]);
            }
#pragma unroll
            for (int j = 0; j < 4; ++j) {
                int row = wc + j * 16 + r16;
                int sw = (kk * 4 + q) ^ (row & 7);
                b[j] = *reinterpret_cast<const bf16x8*>(&Bs[row * BK + sw * 8]);
            }
#pragma unroll
            for (int i = 0; i < 4; ++i)
#pragma unroll
                for (int j = 0; j < 4; ++j)
                    acc[i][j] = __builtin_amdgcn_mfma_f32_16x16x32_bf16(a[i], b[j], acc[i][j], 0, 0, 0);
        }
        __syncthreads();
    }

    // C write (bf16). C/D layout: col = lane&15, row = (lane>>4)*4 + reg
#pragma unroll
    for (int i = 0; i < 4; ++i) {
#pragma unroll
        for (int rr = 0; rr < 4; ++rr) {
            int grow = row0 + wr + i * 16 + q * 4 + rr;
            if (grow >= N) continue;
#pragma unroll
            for (int j = 0; j < 4; ++j)
                Cb[(size_t)grow * HID + col0 + wc + j * 16 + r16] =
                    __float2bfloat16(acc[i][j][rr]);
        }
    }

    // Fused alpha: wave's 64 cols == one head
    const int head = (col0 + wc) >> 6;
    float avs[4], avd[4];
#pragma unroll
    for (int j = 0; j < 4; ++j) {
        avs[j] = att_s[col0 + wc + j * 16 + r16];
        avd[j] = att_d[col0 + wc + j * 16 + r16];
    }
#pragma unroll
    for (int i = 0; i < 4; ++i) {
#pragma unroll
        for (int rr = 0; rr < 4; ++rr) {
            float ss = 0.f, dd = 0.f;
#pragma unroll
            for (int j = 0; j < 4; ++j) {
                float v = acc[i][j][rr];
                ss += v * avs[j];
                dd += v * avd[j];
            }
#pragma unroll
            for (int off = 8; off > 0; off >>= 1) {
                ss += __shfl_xor(ss, off);
                dd += __shfl_xor(dd, off);
            }
            int grow = row0 + wr + i * 16 + q * 4 + rr;
            if (r16 == 0 && grow < N) {
                as_out[(size_t)grow * HEADS + head] = ss;
                ad_out[(size_t)grow * HEADS + head] = dd;
            }
        }
    }
}

// ---------------- count: edge dst bins + graph bins in one pass ------------
__global__ void count_kernel(const int* __restrict__ ei, const int* __restrict__ batch,
                             int* __restrict__ counts, int* __restrict__ gc) {
    int e = blockIdx.x * blockDim.x + threadIdx.x;
    int tot = N_EDGES + N_NODES;
    if (e < tot) {
        int dst = e < N_EDGES ? ei[N_EDGES + e] : e - N_EDGES;
        atomicAdd(&counts[dst], 1);
    }
    if (e < N_NODES) atomicAdd(&gc[batch[e]], 1);
}

__global__ void scan1_kernel(const int* __restrict__ counts, int* __restrict__ offsets,
                             int* __restrict__ bsums, int n) {
    __shared__ int tmp[1024];
    int tid = threadIdx.x;
    int gid = blockIdx.x * 1024 + tid;
    tmp[tid] = gid < n ? counts[gid] : 0;
    __syncthreads();
    for (int off = 1; off < 1024; off <<= 1) {
        int t = tid >= off ? tmp[tid - off] : 0;
        __syncthreads();
        tmp[tid] += t;
        __syncthreads();
    }
    if (gid < n) offsets[gid + 1] = tmp[tid];
    if (tid == 1023) bsums[blockIdx.x] = tmp[1023];
}

__global__ void scan2_kernel(int* bsums, int nb) {
    if (threadIdx.x == 0) {
        int s = 0;
        for (int i = 0; i < nb; ++i) { s += bsums[i]; bsums[i] = s; }
    }
}

__global__ void scan3_kernel(const int* __restrict__ counts, int* __restrict__ offsets,
                             const int* __restrict__ bsums, int* __restrict__ wp, int n) {
    int tid = threadIdx.x;
    int gid = blockIdx.x * 1024 + tid;
    if (gid == 0) offsets[0] = 0;
    if (gid >= n) return;
    int add = blockIdx.x > 0 ? bsums[blockIdx.x - 1] : 0;
    int v = offsets[gid + 1] + add;
    offsets[gid + 1] = v;
    wp[gid] = v - counts[gid];
}

__global__ void scatter_kernel(const int* __restrict__ ei, int* __restrict__ wp,
                               int* __restrict__ csrc) {
    int e = blockIdx.x * blockDim.x + threadIdx.x;
    int tot = N_EDGES + N_NODES;
    if (e >= tot) return;
    int src = e < N_EDGES ? ei[e] : e - N_EDGES;
    int dst = e < N_EDGES ? ei[N_EDGES + e] : e - N_EDGES;
    int pos = atomicAdd(&wp[dst], 1);
    csrc[pos] = src;
}

// ---------------- softmax-attention aggregation + fused BN stats -----------
// 16 dst nodes / block (2 per wave, sequential). Lane owns 8 channels.
__launch_bounds__(512)
__global__ void agg_kernel(const __hip_bfloat16* __restrict__ hb, const float* __restrict__ as,
                           const float* __restrict__ ad, const int* __restrict__ offsets,
                           const int* __restrict__ csrc, const float* __restrict__ bias,
                           __hip_bfloat16* __restrict__ outb,
                           float* __restrict__ ps, float* __restrict__ pq) {
    __shared__ float psum[16][HID];
    const int wave = threadIdx.x >> 6, lane = threadIdx.x & 63;
    const int head = lane >> 3;
    const int c0 = lane << 3;
    const float4* bp = reinterpret_cast<const float4*>(bias + c0);
    float4 b0 = bp[0], b1 = bp[1];
    float bb[8] = {b0.x, b0.y, b0.z, b0.w, b1.x, b1.y, b1.z, b1.w};

#pragma unroll
    for (int sub = 0; sub < 2; ++sub) {
        const int i = blockIdx.x * 16 + wave * 2 + sub;
        const int beg = offsets[i];
        const int deg = offsets[i + 1] - beg;
        const float adv = ad[(size_t)i * HEADS + head];

        float a[8] = {};
        float den = 0.f;
        for (int e0 = 0; e0 < deg; e0 += 4) {
            int m = deg - e0; if (m > 4) m = 4;
            int s[4];
#pragma unroll
            for (int k = 0; k < 4; ++k) {
                int kk = k < m ? k : m - 1;
                s[k] = csrc[beg + e0 + kk];
            }
            float w[4];
#pragma unroll
            for (int k = 0; k < 4; ++k)
                w[k] = (k < m) ? __expf(lrelu(as[(size_t)s[k] * HEADS + head] + adv)) : 0.f;
#pragma unroll
            for (int k = 0; k < 4; ++k) {
                bf16x8 hv = *reinterpret_cast<const bf16x8*>(hb + (size_t)s[k] * HID + c0);
#pragma unroll
                for (int t = 0; t < 8; ++t)
                    a[t] += w[k] * bf2f((unsigned short)hv[t]);
                den += w[k];
            }
        }
        float inv = 1.f / den;
        float o[8];
        ushort4 p0, p1;
#pragma unroll
        for (int t = 0; t < 8; ++t) o[t] = a[t] * inv + bb[t];
        p0.x = f2bf(o[0]); p0.y = f2bf(o[1]); p0.z = f2bf(o[2]); p0.w = f2bf(o[3]);
        p1.x = f2bf(o[4]); p1.y = f2bf(o[5]); p1.z = f2bf(o[6]); p1.w = f2bf(o[7]);
        ushort4* op = reinterpret_cast<ushort4*>(outb + (size_t)i * HID + c0);
        op[0] = p0; op[1] = p1;
#pragma unroll
        for (int t = 0; t < 8; ++t) psum[wave * 2 + sub][c0 + t] = o[t];
    }
    __syncthreads();
    int c = threadIdx.x; // 512 == HID
    float s = 0.f, q = 0.f;
#pragma unroll
    for (int w = 0; w < 16; ++w) {
        float v = psum[w][c];
        s += v; q += v * v;
    }
    int bin = blockIdx.x & (NBINS - 1);
    atomicAdd(&ps[bin * HID + c], s);
    atomicAdd(&pq[bin * HID + c], q);
}

// ---------------- BN prep: fold bins (wave per channel) + zero bins --------
__global__ void bn_prep_kernel(float* __restrict__ ps, float* __restrict__ pq,
                               const float* __restrict__ gamma, const float* __restrict__ beta,
                               float* __restrict__ sc, float* __restrict__ sh, int n) {
    int wave = threadIdx.x >> 6, lane = threadIdx.x & 63;
    int c = blockIdx.x * 8 + wave;
    float s = ps[lane * HID + c] + ps[(lane + 64) * HID + c];
    float q = pq[lane * HID + c] + pq[(lane + 64) * HID + c];
    // zero bins for the next layer's agg (separate dispatch -> safe)
    ps[lane * HID + c] = 0.f; ps[(lane + 64) * HID + c] = 0.f;
    pq[lane * HID + c] = 0.f; pq[(lane + 64) * HID + c] = 0.f;
#pragma unroll
    for (int off = 32; off > 0; off >>= 1) {
        s += __shfl_xor(s, off);
        q += __shfl_xor(q, off);
    }
    if (lane == 0) {
        float inv_n = 1.f / (float)n;
        float mu = s * inv_n;
        float var = q * inv_n - mu * mu;
        float g = rsqrtf(var + 1e-5f) * gamma[c];
        sc[c] = g;
        sh[c] = beta[c] - mu * g;
    }
}

// ---------------- pooling: wave per graph, no atomics ----------------------
__launch_bounds__(256)
__global__ void pool_bn_kernel(const __hip_bfloat16* __restrict__ xb,
                               const int* __restrict__ goff,
                               const float* __restrict__ sc, const float* __restrict__ sh,
                               float* __restrict__ pooled) {
    const int wave = threadIdx.x >> 6, lane = threadIdx.x & 63;
    const int g = blockIdx.x * 4 + wave;
    if (g >= N_GRAPHS) return;
    const int beg = goff[g], end = goff[g + 1];
    const int c0 = lane << 3;
    const float4* scp = reinterpret_cast<const float4*>(sc + c0);
    const float4* shp = reinterpret_cast<const float4*>(sh + c0);
    float4 s0 = scp[0], s1 = scp[1], h0 = shp[0], h1 = shp[1];
    float scv[8] = {s0.x, s0.y, s0.z, s0.w, s1.x, s1.y, s1.z, s1.w};
    float shv[8] = {h0.x, h0.y, h0.z, h0.w, h1.x, h1.y, h1.z, h1.w};
    float acc[8] = {};
    for (int i = beg; i < end; ++i) {
        bf16x8 v = *reinterpret_cast<const bf16x8*>(xb + (size_t)i * HID + c0);
#pragma unroll
        for (int t = 0; t < 8; ++t) {
            float val = fmaf(bf2f((unsigned short)v[t]), scv[t], shv[t]);
            acc[t] += val > 0.f ? val : 0.f;
        }
    }
    int cnt = end - beg;
    float inv = 1.f / (float)(cnt > 0 ? cnt : 1);
    float4 o0 = make_float4(acc[0] * inv, acc[1] * inv, acc[2] * inv, acc[3] * inv);
    float4 o1 = make_float4(acc[4] * inv, acc[5] * inv, acc[6] * inv, acc[7] * inv);
    float4* op = reinterpret_cast<float4*>(pooled + (size_t)g * HID + c0);
    op[0] = o0; op[1] = o1;
}

__global__ void mlp1_kernel(const float* __restrict__ pooled,
                            const float* __restrict__ w1, const float* __restrict__ b1,
                            float* __restrict__ h1) {
    __shared__ float row[HID];
    int g = blockIdx.x;
    int tid = threadIdx.x; // 256
    row[tid] = pooled[(size_t)g * HID + tid];
    row[tid + 256] = pooled[(size_t)g * HID + tid + 256];
    __syncthreads();
    float acc = 0.f;
    for (int c = 0; c < HID; ++c) acc += row[c] * w1[c * 256 + tid];
    float v = acc + b1[tid];
    h1[g * 256 + tid] = v > 0.f ? v : 0.f;
}

__global__ void mlp2_kernel(const float* __restrict__ h1, const float* __restrict__ w2,
                            const float* __restrict__ b2, float* __restrict__ out) {
    __shared__ float row[256];
    int g = blockIdx.x;
    int tid = threadIdx.x; // 64
    for (int j = tid; j < 256; j += 64) row[j] = h1[g * 256 + j];
    __syncthreads();
    if (tid < TARGETS) {
        float acc = 0.f;
        for (int j = 0; j < 256; ++j) acc += row[j] * w2[j * TARGETS + tid];
        out[g * TARGETS + tid] = acc + b2[tid];
    }
}

// ---------------------------------------------------------------------------
extern "C" void kernel_launch(void* const* d_in, const int* in_sizes, int n_in,
                              void* d_out, int out_size, void* d_ws, size_t ws_size,
                              hipStream_t stream) {
    const float* atom   = (const float*)d_in[0];
    const int*   ei     = (const int*)d_in[2];   // [2, N_EDGES]
    const int*   batch  = (const int*)d_in[3];
    const float* atom_w = (const float*)d_in[4];
    const float* atom_b = (const float*)d_in[5];
    const float* gat_w  = (const float*)d_in[6];
    const float* att_s  = (const float*)d_in[7];
    const float* att_d  = (const float*)d_in[8];
    const float* gat_b  = (const float*)d_in[9];
    const float* bn_g   = (const float*)d_in[10];
    const float* bn_b   = (const float*)d_in[11];
    const float* w1     = (const float*)d_in[12];
    const float* b1     = (const float*)d_in[13];
    const float* w2     = (const float*)d_in[14];
    const float* b2     = (const float*)d_in[15];
    float* out = (float*)d_out;

    const int ETOT = N_EDGES + N_NODES;

    char* ws = (char*)d_ws;
    size_t off = 0;
    auto alloc = [&](size_t bytes) {
        void* p = ws + off;
        off += (bytes + 255) & ~(size_t)255;
        return p;
    };
    __hip_bfloat16* xn  = (__hip_bfloat16*)alloc((size_t)N_NODES * HID * 2); // 51.2 MB (atom out)
    __hip_bfloat16* xb  = (__hip_bfloat16*)alloc((size_t)N_NODES * HID * 2); // 51.2 MB (agg out, pre-BN)
    __hip_bfloat16* hb  = (__hip_bfloat16*)alloc((size_t)N_NODES * HID * 2); // 51.2 MB
    __hip_bfloat16* Wt  = (__hip_bfloat16*)alloc((size_t)LAYERS * HID * HID * 2); // 3.1 MB
    __hip_bfloat16* Wt0 = (__hip_bfloat16*)alloc((size_t)HID * 128 * 2);          // 131 KB
    float* as_    = (float*)alloc((size_t)N_NODES * HEADS * 4);
    float* ad_    = (float*)alloc((size_t)N_NODES * HEADS * 4);
    // --- contiguous zero-init region: counts, gcounts, part_s, part_q ---
    size_t zbase = off;
    int* counts   = (int*)alloc(N_NODES * 4);
    int* gcounts  = (int*)alloc(N_GRAPHS * 4);
    float* part_s = (float*)alloc((size_t)NBINS * HID * 4);     // 256 KB
    float* part_q = (float*)alloc((size_t)NBINS * HID * 4);     // 256 KB
    size_t zlen = off - zbase;
    int* offsets  = (int*)alloc((N_NODES + 1) * 4);
    int* wp       = (int*)alloc(N_NODES * 4);
    int* csrc     = (int*)alloc(ETOT * 4);
    int* bsums    = (int*)alloc(64 * 4);
    int* goff     = (int*)alloc((N_GRAPHS + 1) * 4);
    float* bn_sc  = (float*)alloc(HID * 4);
    float* bn_sh  = (float*)alloc(HID * 4);
    float* pooled = (float*)alloc((size_t)N_GRAPHS * HID * 4);
    float* h1     = (float*)alloc((size_t)N_GRAPHS * 256 * 4);

    // ---- single setup memset ----
    hipMemsetAsync(ws + zbase, 0, zlen, stream);

    // ---- edge CSR + graph counting in one pass ----
    count_kernel<<<(ETOT + 255) / 256, 256, 0, stream>>>(ei, batch, counts, gcounts);
    int nb = (N_NODES + 1023) / 1024;
    scan1_kernel<<<nb, 1024, 0, stream>>>(counts, offsets, bsums, N_NODES);
    scan2_kernel<<<1, 64, 0, stream>>>(bsums, nb);
    scan3_kernel<<<nb, 1024, 0, stream>>>(counts, offsets, bsums, wp, N_NODES);
    scatter_kernel<<<(ETOT + 255) / 256, 256, 0, stream>>>(ei, wp, csrc);

    // ---- graph offsets from sorted batch (scan, n=2000) ----
    int nbg = (N_GRAPHS + 1023) / 1024;
    scan1_kernel<<<nbg, 1024, 0, stream>>>(gcounts, goff, bsums, N_GRAPHS);
    scan2_kernel<<<1, 64, 0, stream>>>(bsums, nbg);
    scan3_kernel<<<nbg, 1024, 0, stream>>>(gcounts, goff, bsums, wp, N_GRAPHS);

    // ---- weights: transpose + bf16 convert ----
    wtrans_kernel<<<dim3(HID / 32, HID / 32, LAYERS), dim3(32, 8), 0, stream>>>(gat_w, Wt);
    atomwt_kernel<<<(HID * 128 + 255) / 256, 256, 0, stream>>>(atom_w, Wt0);

    // ---- atom projection -> xn (bf16) via MFMA (K padded to 128) ----
    gemm_atom_kernel<<<dim3((N_NODES + 127) / 128, HID / 128), 256, 0, stream>>>(
        atom, Wt0, atom_b, xn, N_NODES);

    // ---- 6 GAT layers ----
    dim3 ggrid((N_NODES + 127) / 128, HID / 256);
    for (int l = 0; l < LAYERS; ++l) {
        if (l == 0)
            gemm_mfma_kernel<0><<<ggrid, 512, 0, stream>>>(
                xn, Wt, hb, nullptr, nullptr,
                att_s, att_d, as_, ad_, N_NODES);
        else
            gemm_mfma_kernel<1><<<ggrid, 512, 0, stream>>>(
                xb, Wt + (size_t)l * HID * HID, hb, bn_sc, bn_sh,
                att_s + l * HID, att_d + l * HID, as_, ad_, N_NODES);
        agg_kernel<<<N_NODES / 16, 512, 0, stream>>>(hb, as_, ad_, offsets, csrc,
                                                     gat_b + l * HID, xb, part_s, part_q);
        bn_prep_kernel<<<64, 512, 0, stream>>>(part_s, part_q, bn_g + l * HID, bn_b + l * HID,
                                               bn_sc, bn_sh, N_NODES);
    }

    // ---- pool (wave/graph, BN+ReLU fused, atomic-free) + MLP head ----
    pool_bn_kernel<<<(N_GRAPHS + 3) / 4, 256, 0, stream>>>(xb, goff, bn_sc, bn_sh, pooled);
    mlp1_kernel<<<N_GRAPHS, 256, 0, stream>>>(pooled, w1, b1, h1);
    mlp2_kernel<<<N_GRAPHS, 64, 0, stream>>>(h1, w2, b2, out);
}